// Round 1
// baseline (21235.432 us; speedup 1.0000x reference)
//
#include <hip/hip_runtime.h>
#include <math.h>

// RNN: T=512, B=64, IC=HC=1024, L=2, fp32 in/out.
// out = seq2 [T,B,HC] ++ hs [2,B,HC]  (fp32)
//
// Wavefront schedule: stage s (0..512):
//   blocks 0..127   : layer-1 step t1=s      (if s<512)
//   blocks 128..255 : layer-2 step t2=s-1    (if s>=1)
// Layer-1 writes seq1[t] directly into d_out's seq region.
// Layer-2 reads seq1[t2] from d_out and delayed-writes seq2[t2-1] into
// d_out[t2-1] (that slot's seq1 value was consumed at the previous stage).
// Tail kernel writes seq2[T-1] and hs.

#define T_STEPS 512
#define BATCH   64
#define HCC     1024
#define BH      (BATCH * HCC)   // 65536 elements per [B,HC] slab

__global__ __launch_bounds__(256) void rnn_zero_kernel(float* p, int n) {
    int i = blockIdx.x * blockDim.x + threadIdx.x;
    if (i < n) p[i] = 0.0f;
}

// One wavefront stage. Each block computes a [64 rows x 8 cols] tile of
// h_new = tanh(A1 . Wi_l^T + h_prev . Wh_l^T + bi_l + bh_l)
// where A1 is x[t] (layer 1) or seq1[t] (layer 2); both have row stride 1024.
__global__ __launch_bounds__(256) void rnn_stage(
    int t1, int t2,
    const float* __restrict__ x,
    const float* __restrict__ Wi, const float* __restrict__ bi,
    const float* __restrict__ Wh, const float* __restrict__ bh,
    const float* __restrict__ h1p, float* __restrict__ h1n,
    const float* __restrict__ h2p, float* __restrict__ h2n,
    float* seqO)
{
    __shared__ float As[64][68];
    __shared__ float Ws[8][68];

    const int part = blockIdx.x >> 7;   // 0: layer 1, 1: layer 2
    const int blk  = blockIdx.x & 127;
    const int t    = part ? t2 : t1;
    if (t < 0) return;

    const float* A1;
    const float* hp;
    float* hn;
    const float* wi;
    const float* wh;
    const float* bip;
    const float* bhp;
    float* seq_out;
    float* prev_out;

    if (part == 0) {
        A1 = x + (size_t)t1 * BH;            // x[t1]: [64,1024]
        hp = h1p; hn = h1n;
        wi = Wi;  wh = Wh;  bip = bi;  bhp = bh;
        seq_out  = seqO + (size_t)t1 * BH;   // seq1[t1]
        prev_out = nullptr;
    } else {
        A1 = seqO + (size_t)t2 * BH;         // seq1[t2]
        hp = h2p; hn = h2n;
        wi = Wi + HCC * HCC;  wh = Wh + HCC * HCC;
        bip = bi + HCC;       bhp = bh + HCC;
        seq_out  = nullptr;
        prev_out = (t2 > 0) ? (seqO + (size_t)(t2 - 1) * BH) : nullptr;
    }

    const int tid = threadIdx.x;
    const int col = tid & 7;            // 0..7
    const int r0  = (tid >> 3) << 1;    // 0,2,...,62
    const int c0  = blk * 8;            // block's first output column

    float acc0 = 0.0f, acc1 = 0.0f;

    #pragma unroll
    for (int pass = 0; pass < 2; ++pass) {
        const float* Asrc = pass ? hp : A1;   // [64,1024]
        const float* Wsrc = pass ? wh : wi;   // [1024,1024] row-major (out,in)
        for (int k0 = 0; k0 < 1024; k0 += 64) {
            // stage A tile: 64x64 floats = 1024 float4, 4 per thread
            #pragma unroll
            for (int i = 0; i < 4; ++i) {
                int flat = i * 256 + tid;          // 0..1023
                int r  = flat >> 4;
                int k4 = (flat & 15) << 2;
                *(float4*)&As[r][k4] =
                    *(const float4*)&Asrc[(size_t)r * 1024 + k0 + k4];
            }
            // stage W tile: 8x64 floats = 128 float4
            if (tid < 128) {
                int r  = tid >> 4;
                int k4 = (tid & 15) << 2;
                *(float4*)&Ws[r][k4] =
                    *(const float4*)&Wsrc[(size_t)(c0 + r) * 1024 + k0 + k4];
            }
            __syncthreads();
            #pragma unroll
            for (int kk = 0; kk < 64; kk += 4) {
                float4 a0 = *(const float4*)&As[r0][kk];
                float4 a1 = *(const float4*)&As[r0 + 1][kk];
                float4 w  = *(const float4*)&Ws[col][kk];
                acc0 += a0.x * w.x + a0.y * w.y + a0.z * w.z + a0.w * w.w;
                acc1 += a1.x * w.x + a1.y * w.y + a1.z * w.z + a1.w * w.w;
            }
            __syncthreads();
        }
    }

    const int c  = c0 + col;
    const float b  = bip[c] + bhp[c];
    const float v0 = tanhf(acc0 + b);
    const float v1 = tanhf(acc1 + b);
    const int o0 = r0 * HCC + c;
    const int o1 = o0 + HCC;
    hn[o0] = v0;
    hn[o1] = v1;
    if (seq_out)  { seq_out[o0] = v0;       seq_out[o1] = v1; }
    if (prev_out) { prev_out[o0] = hp[o0];  prev_out[o1] = hp[o1]; }
}

__global__ __launch_bounds__(256) void rnn_tail(
    const float* __restrict__ h1f, const float* __restrict__ h2f,
    float* __restrict__ seq_last, float* __restrict__ hs)
{
    int i = blockIdx.x * blockDim.x + threadIdx.x;
    if (i < BH) {
        float v2 = h2f[i];
        seq_last[i]  = v2;      // seq2[T-1]
        hs[i]        = h1f[i];  // hs[0] = layer-1 final h
        hs[BH + i]   = v2;      // hs[1] = layer-2 final h
    }
}

extern "C" void kernel_launch(void* const* d_in, const int* in_sizes, int n_in,
                              void* d_out, int out_size, void* d_ws, size_t ws_size,
                              hipStream_t stream) {
    const float* x  = (const float*)d_in[0];  // [512,64,1024]
    const float* Wi = (const float*)d_in[1];  // [2,1024,1024]
    const float* bi = (const float*)d_in[2];  // [2,1024]
    const float* Wh = (const float*)d_in[3];  // [2,1024,1024]
    const float* bh = (const float*)d_in[4];  // [2,1024]

    float* out  = (float*)d_out;
    float* seqO = out;                        // [512,64,1024]
    float* hsO  = out + (size_t)T_STEPS * BH; // [2,64,1024]

    // workspace: 4 ping-pong h buffers (1 MB total)
    float* h1a = (float*)d_ws;
    float* h1b = h1a + BH;
    float* h2a = h1b + BH;
    float* h2b = h2a + BH;

    rnn_zero_kernel<<<(4 * BH + 255) / 256, 256, 0, stream>>>(h1a, 4 * BH);

    float* h1p = h1a; float* h1n = h1b;
    float* h2p = h2a; float* h2n = h2b;

    for (int s = 0; s <= T_STEPS; ++s) {
        int t1 = (s < T_STEPS) ? s : -1;
        int t2 = (s >= 1) ? (s - 1) : -1;
        rnn_stage<<<256, 256, 0, stream>>>(t1, t2, x, Wi, bi, Wh, bh,
                                           h1p, h1n, h2p, h2n, seqO);
        if (t1 >= 0) { float* tmp = h1p; h1p = h1n; h1n = tmp; }
        if (t2 >= 0) { float* tmp = h2p; h2p = h2n; h2n = tmp; }
    }

    rnn_tail<<<(BH + 255) / 256, 256, 0, stream>>>(
        h1p, h2p, seqO + (size_t)(T_STEPS - 1) * BH, hsO);
}

// Round 2
// 13515.117 us; speedup vs baseline: 1.5712x; 1.5712x over previous
//
#include <hip/hip_runtime.h>

// 2-layer tanh RNN, T=512, B=64, IC=HC=1024, fp32 in/out.
// Persistent wavefront kernel: stage s computes layer-1 step s and layer-2
// step s-1 concurrently; custom device-scope grid barrier between stages.
// All GEMMs: split-bf16 (hi+lo) MFMA 16x16x32, fp32 accumulate.
//
// ws layout:
//   WF  : 16 MiB  fragment-major split weights (bf16)  [layer][mat][prec][c16][ks][lane][8]
//   xF  : 2 x 256 KiB  fragment-major split x[t] (double-buffered by stage parity)
//   h1F : 2 x 256 KiB  layer-1 hidden state ring (= seq1 ring for layer-2 input)
//   h2F : 2 x 256 KiB  layer-2 hidden state ring
//   cnt : barrier counter

#define T_STEPS 512
#define HCC     1024
#define BH      (64*1024)

typedef __attribute__((ext_vector_type(8))) short  bf16x8;
typedef __attribute__((ext_vector_type(4))) float  f32x4;

#define WF_SHORTS  (8u*64u*32u*512u)     /* 8,388,608 shorts = 16 MiB  */
#define AF_SHORTS  (2u*4u*32u*512u)      /* 131072 shorts = 256 KiB    */
#define OFF_XF     WF_SHORTS
#define OFF_H1F    (OFF_XF  + 2u*AF_SHORTS)
#define OFF_H2F    (OFF_H1F + 2u*AF_SHORTS)
#define CNT_BYTE_OFF ((size_t)(OFF_H2F + 2u*AF_SHORTS) * 2u)   /* 18,350,080 */

__device__ __forceinline__ unsigned short bf16_rne_bits(float f) {
    unsigned u = __builtin_bit_cast(unsigned, f);
    unsigned r = u + 0x7fffu + ((u >> 16) & 1u);
    return (unsigned short)(r >> 16);
}
__device__ __forceinline__ float bf16_to_f(unsigned short h) {
    unsigned u = ((unsigned)h) << 16;
    return __builtin_bit_cast(float, u);
}
__device__ __forceinline__ void split1(float f, unsigned short& hi, unsigned short& lo) {
    unsigned u = __builtin_bit_cast(unsigned, f);
    unsigned r = (u + 0x7fffu + ((u >> 16) & 1u)) & 0xffff0000u;
    hi = (unsigned short)(r >> 16);
    float res = f - __builtin_bit_cast(float, r);
    lo = bf16_rne_bits(res);
}
__device__ __forceinline__ float tanh_fast(float v) {
    float e = __expf(2.0f * v);
    return 1.0f - 2.0f * __builtin_amdgcn_rcpf(e + 1.0f);
}

// ---------------- barrier counter zero ----------------
__global__ void zero_cnt_kernel(unsigned* cnt) {
    if (threadIdx.x == 0) cnt[0] = 0u;
}

// ---------------- weight split / fragment re-layout ----------------
// WF[layer][mat(0=Wi,1=Wh)][prec(0=hi,1=lo)][c16][ks][lane*8+e]
//   element = W[row = c16*16 + (lane&15)][k = ks*32 + (lane>>4)*8 + e]
__global__ __launch_bounds__(256) void wsplit_kernel(
    const float* __restrict__ Wi, const float* __restrict__ Wh,
    unsigned short* __restrict__ WF)
{
    unsigned id  = blockIdx.x * 256u + threadIdx.x;   // < 524288
    unsigned kc  = id & 127u;          // 8-element k chunk
    unsigned row = (id >> 7) & 1023u;
    unsigned ml  = id >> 17;           // 0..3
    unsigned mat = ml & 1u, layer = ml >> 1;

    const float* src = (mat ? Wh : Wi) + (size_t)layer * HCC * HCC
                     + (size_t)row * HCC + kc * 8u;
    float f[8];
    *(f32x4*)&f[0] = *(const f32x4*)&src[0];
    *(f32x4*)&f[4] = *(const f32x4*)&src[4];

    bf16x8 H, L;
#pragma unroll
    for (int e = 0; e < 8; ++e) {
        unsigned short hi, lo; split1(f[e], hi, lo);
        H[e] = (short)hi; L[e] = (short)lo;
    }
    unsigned c16 = row >> 4, ks = kc >> 2;
    unsigned lane = (row & 15u) + 16u * (kc & 3u);
    size_t basehi = (((size_t)((layer * 2u + mat) * 2u + 0u) * 64u + c16) * 32u + ks) * 512u + lane * 8u;
    size_t baselo = (((size_t)((layer * 2u + mat) * 2u + 1u) * 64u + c16) * 32u + ks) * 512u + lane * 8u;
    *(bf16x8*)&WF[basehi] = H;
    *(bf16x8*)&WF[baselo] = L;
}

// ---------------- persistent wavefront kernel ----------------
__global__ __launch_bounds__(256, 1) void rnn_persist(
    const float* __restrict__ x,
    const float* __restrict__ bi, const float* __restrict__ bh,
    const unsigned short* __restrict__ WF,
    unsigned short* __restrict__ xF,
    unsigned short* __restrict__ h1F,
    unsigned short* __restrict__ h2F,
    unsigned* __restrict__ cnt,
    float* __restrict__ seqO, float* __restrict__ hsO)
{
    __shared__ short WlS[4 * 16384];        // 128 KiB: [mat*2+prec][ks*512+lane*8]
    __shared__ float redS[4 * 4 * 64 * 4];  // 16 KiB: [srcwave][rt][lane][reg]

    const unsigned wg    = blockIdx.x;      // 128 WGs
    const unsigned layer = wg >> 6;         // 0..1
    const unsigned c16   = wg & 63u;        // col tile (16 cols)
    const unsigned tid   = threadIdx.x;
    const unsigned w     = tid >> 6;        // wave = K-quarter
    const unsigned lane  = tid & 63u;
    const unsigned koff  = lane * 8u;

    // persistent W LDS load (once)
#pragma unroll
    for (unsigned m = 0; m < 4; ++m) {
        const unsigned short* sp = WF + (((size_t)(layer * 4u + m) * 64u + c16) * 16384u);
        short* dp = &WlS[m * 16384u];
        for (unsigned t = tid * 8u; t < 16384u; t += 2048u)
            *(bf16x8*)&dp[t] = *(const bf16x8*)&sp[t];
    }

    const unsigned colj  = c16 * 16u + (lane & 15u);
    const float    bv    = bi[layer * HCC + colj] + bh[layer * HCC + colj];
    const unsigned ksj   = colj >> 5;
    const unsigned lfadd = 16u * ((colj >> 3) & 3u);
    const unsigned ej    = colj & 7u;

    unsigned gen = 0u;

    // prologue: prestage x[0] into xF[parity 0]
    if (wg >= 96u) {
        unsigned gid = (wg - 96u) * 256u + tid;          // 0..8191
        unsigned row = gid >> 7, kc = gid & 127u;
        const float* sp = x + (size_t)row * HCC + kc * 8u;
        float f[8];
        *(f32x4*)&f[0] = *(const f32x4*)&sp[0];
        *(f32x4*)&f[4] = *(const f32x4*)&sp[4];
        bf16x8 H, L;
#pragma unroll
        for (int e = 0; e < 8; ++e) { unsigned short hi2, lo2; split1(f[e], hi2, lo2); H[e] = (short)hi2; L[e] = (short)lo2; }
        unsigned ks = kc >> 2, lg = (row & 15u) + 16u * (kc & 3u), rt = row >> 4;
        *(bf16x8*)&xF[((0u * 4u + rt) * 32u + ks) * 512u + lg * 8u] = H;
        *(bf16x8*)&xF[((1u * 4u + rt) * 32u + ks) * 512u + lg * 8u] = L;
    }
    // barrier helper (inline)
#define GBAR()                                                                        \
    do {                                                                              \
        __syncthreads();                                                              \
        if (tid == 0) {                                                               \
            __threadfence();                                                          \
            __hip_atomic_fetch_add(cnt, 1u, __ATOMIC_RELEASE, __HIP_MEMORY_SCOPE_AGENT); \
            unsigned tgt = gen * 128u;                                                \
            while (__hip_atomic_load(cnt, __ATOMIC_ACQUIRE, __HIP_MEMORY_SCOPE_AGENT) < tgt) \
                __builtin_amdgcn_s_sleep(1);                                          \
        }                                                                             \
        __syncthreads();                                                              \
    } while (0)

    ++gen; GBAR();   // WF (prev kernel) + xF[0] visible

    for (int s = 0; s <= T_STEPS; ++s) {
        const unsigned par = (unsigned)s & 1u;
        bool active, use_h;
        const unsigned short *a1b, *hbb;
        unsigned short* hdst;
        float *fd0 = nullptr, *fd1 = nullptr;

        if (layer == 0) {
            active = (s < T_STEPS);
            a1b  = xF  + par * AF_SHORTS;
            hbb  = h1F + (par ^ 1u) * AF_SHORTS;
            hdst = h1F + par * AF_SHORTS;
            use_h = (s > 0);
            if (s == T_STEPS - 1) fd0 = hsO;             // hs[0] = final h1
        } else {
            active = (s >= 1);
            a1b  = h1F + (par ^ 1u) * AF_SHORTS;          // seq1[s-1]
            hbb  = h2F + (par ^ 1u) * AF_SHORTS;
            hdst = h2F + par * AF_SHORTS;
            use_h = (s >= 2);
            fd0 = seqO + (size_t)(s - 1) * BH;            // seq2[s-1]
            if (s == T_STEPS) fd1 = hsO + BH;             // hs[1] = final h2
        }

        if (active) {
            f32x4 acc[4];
#pragma unroll
            for (unsigned rt = 0; rt < 4; ++rt) acc[rt] = (f32x4){0.f, 0.f, 0.f, 0.f};

            for (unsigned i = 0; i < 8; ++i) {
                const unsigned ks = w * 8u + i;
                const unsigned wo = ks * 512u + koff;
                bf16x8 b_ih = *(const bf16x8*)&WlS[0u * 16384u + wo];
                bf16x8 b_il = *(const bf16x8*)&WlS[1u * 16384u + wo];
                bf16x8 b_hh = *(const bf16x8*)&WlS[2u * 16384u + wo];
                bf16x8 b_hl = *(const bf16x8*)&WlS[3u * 16384u + wo];
                bf16x8 ah[4], al[4];
#pragma unroll
                for (unsigned rt = 0; rt < 4; ++rt) {
                    ah[rt] = *(const bf16x8*)&a1b[((0u * 4u + rt) * 32u + ks) * 512u + koff];
                    al[rt] = *(const bf16x8*)&a1b[((1u * 4u + rt) * 32u + ks) * 512u + koff];
                }
#pragma unroll
                for (unsigned rt = 0; rt < 4; ++rt)
                    acc[rt] = __builtin_amdgcn_mfma_f32_16x16x32_bf16(ah[rt], b_ih, acc[rt], 0, 0, 0);
#pragma unroll
                for (unsigned rt = 0; rt < 4; ++rt)
                    acc[rt] = __builtin_amdgcn_mfma_f32_16x16x32_bf16(al[rt], b_ih, acc[rt], 0, 0, 0);
#pragma unroll
                for (unsigned rt = 0; rt < 4; ++rt)
                    acc[rt] = __builtin_amdgcn_mfma_f32_16x16x32_bf16(ah[rt], b_il, acc[rt], 0, 0, 0);
                if (use_h) {
                    bf16x8 gh[4], gl[4];
#pragma unroll
                    for (unsigned rt = 0; rt < 4; ++rt) {
                        gh[rt] = *(const bf16x8*)&hbb[((0u * 4u + rt) * 32u + ks) * 512u + koff];
                        gl[rt] = *(const bf16x8*)&hbb[((1u * 4u + rt) * 32u + ks) * 512u + koff];
                    }
#pragma unroll
                    for (unsigned rt = 0; rt < 4; ++rt)
                        acc[rt] = __builtin_amdgcn_mfma_f32_16x16x32_bf16(gh[rt], b_hh, acc[rt], 0, 0, 0);
#pragma unroll
                    for (unsigned rt = 0; rt < 4; ++rt)
                        acc[rt] = __builtin_amdgcn_mfma_f32_16x16x32_bf16(gl[rt], b_hh, acc[rt], 0, 0, 0);
#pragma unroll
                    for (unsigned rt = 0; rt < 4; ++rt)
                        acc[rt] = __builtin_amdgcn_mfma_f32_16x16x32_bf16(gh[rt], b_hl, acc[rt], 0, 0, 0);
                }
            }
            // cross-wave K reduction through LDS
#pragma unroll
            for (unsigned rt = 0; rt < 4; ++rt)
                *(f32x4*)&redS[((w * 4u + rt) * 64u + lane) * 4u] = acc[rt];
            __syncthreads();
            f32x4 tot = *(const f32x4*)&redS[((0u * 4u + w) * 64u + lane) * 4u];
            {
                f32x4 t1 = *(const f32x4*)&redS[((1u * 4u + w) * 64u + lane) * 4u];
                f32x4 t2 = *(const f32x4*)&redS[((2u * 4u + w) * 64u + lane) * 4u];
                f32x4 t3 = *(const f32x4*)&redS[((3u * 4u + w) * 64u + lane) * 4u];
                tot = tot + t1 + t2 + t3;
            }
            const unsigned base_hi = ((0u * 4u + w) * 32u + ksj) * 512u;
            const unsigned base_lo = ((1u * 4u + w) * 32u + ksj) * 512u;
#pragma unroll
            for (unsigned r = 0; r < 4; ++r) {
                float v = tanh_fast(tot[r] + bv);
                unsigned rowf = (lane >> 4) * 4u + r;
                unsigned short hi2, lo2; split1(v, hi2, lo2);
                hdst[base_hi + (rowf + lfadd) * 8u + ej] = hi2;
                hdst[base_lo + (rowf + lfadd) * 8u + ej] = lo2;
                unsigned grow = w * 16u + rowf;
                if (fd0) fd0[(size_t)grow * HCC + colj] = v;
                if (fd1) fd1[(size_t)grow * HCC + colj] = v;
            }
        }

        // prestage x[s+1] into xF[par^1]
        if (wg >= 96u && s < T_STEPS - 1) {
            unsigned gid = (wg - 96u) * 256u + tid;
            unsigned row = gid >> 7, kc = gid & 127u;
            const float* sp = x + (size_t)(s + 1) * BH + (size_t)row * HCC + kc * 8u;
            float f[8];
            *(f32x4*)&f[0] = *(const f32x4*)&sp[0];
            *(f32x4*)&f[4] = *(const f32x4*)&sp[4];
            bf16x8 H, L;
#pragma unroll
            for (int e = 0; e < 8; ++e) { unsigned short hi2, lo2; split1(f[e], hi2, lo2); H[e] = (short)hi2; L[e] = (short)lo2; }
            unsigned ks = kc >> 2, lg = (row & 15u) + 16u * (kc & 3u), rt = row >> 4;
            unsigned short* xdst = xF + (par ^ 1u) * AF_SHORTS;
            *(bf16x8*)&xdst[((0u * 4u + rt) * 32u + ks) * 512u + lg * 8u] = H;
            *(bf16x8*)&xdst[((1u * 4u + rt) * 32u + ks) * 512u + lg * 8u] = L;
        }

        if (s < T_STEPS) { ++gen; GBAR(); }
    }
#undef GBAR
}

extern "C" void kernel_launch(void* const* d_in, const int* in_sizes, int n_in,
                              void* d_out, int out_size, void* d_ws, size_t ws_size,
                              hipStream_t stream) {
    const float* x  = (const float*)d_in[0];
    const float* Wi = (const float*)d_in[1];
    const float* bi = (const float*)d_in[2];
    const float* Wh = (const float*)d_in[3];
    const float* bh = (const float*)d_in[4];

    float* seqO = (float*)d_out;
    float* hsO  = seqO + (size_t)T_STEPS * BH;

    unsigned short* wsS = (unsigned short*)d_ws;
    unsigned short* WF  = wsS;
    unsigned short* xF  = wsS + OFF_XF;
    unsigned short* h1F = wsS + OFF_H1F;
    unsigned short* h2F = wsS + OFF_H2F;
    unsigned* cnt = (unsigned*)((char*)d_ws + CNT_BYTE_OFF);

    zero_cnt_kernel<<<1, 64, 0, stream>>>(cnt);
    wsplit_kernel<<<2048, 256, 0, stream>>>(Wi, Wh, WF);
    rnn_persist<<<128, 256, 0, stream>>>(x, bi, bh, WF, xF, h1F, h2F, cnt, seqO, hsO);
}

// Round 3
// 11649.549 us; speedup vs baseline: 1.8229x; 1.1601x over previous
//
#include <hip/hip_runtime.h>

// 2-layer tanh RNN, T=512, B=64, IC=HC=1024, fp32 in/out.
// Pipeline: pre1 = x*Wi1+b precomputed (parallel GEMM, frag-major into d_out);
// persistent kernel runs 3-group wavefront:
//   G0 (wg 0..63):    h1[s]   = tanh(pre1[s] + h1[s-1]*Wh1^T)
//   G1 (wg 64..127):  pre2[s-1] = h1[s-1]*Wi2^T + b2
//   G2 (wg 128..191): h2[s-2] = tanh(pre2[s-2] + h2[s-3]*Wh2^T) -> seq2[s-2]
// All GEMMs split-bf16 (hi+lo, drop lo*lo) MFMA 16x16x32, fp32 accumulate.

#define T_STEPS 512
#define HCC     1024
#define BH      65536
#define NWG     192
#define NSTAGE  514

typedef __attribute__((ext_vector_type(8))) short  bf16x8;
typedef __attribute__((ext_vector_type(4))) float  f32x4;

// ws layout (shorts unless noted)
#define WF_SHORTS   8388608u                 /* 4 mats x 2 prec x 64 c16 x 32 ks x 512 = 16 MiB */
#define SLAB_SHORTS 131072u                  /* h ring slab: 2 rh x 2 prec x 2 r16 x 32 ks x 512 = 256 KiB */
#define OFF_H1F     WF_SHORTS
#define OFF_H2F     (OFF_H1F + 2u*SLAB_SHORTS)
#define OFF_PRE2_BYTES ((size_t)(OFF_H2F + 2u*SLAB_SHORTS) * 2u)   /* 17,825,792 */
#define PRE2_FLOATS 65536u                   /* per parity: 2 rh x 32 ct x 4 fi x 64 lane x 4 reg */
#define CNT_BYTE_OFF (OFF_PRE2_BYTES + 2u*(size_t)PRE2_FLOATS*4u)  /* 18,350,080 */

__device__ __forceinline__ unsigned short bf16_rne_bits(float f) {
    unsigned u = __builtin_bit_cast(unsigned, f);
    unsigned r = u + 0x7fffu + ((u >> 16) & 1u);
    return (unsigned short)(r >> 16);
}
__device__ __forceinline__ void split1(float f, unsigned short& hi, unsigned short& lo) {
    unsigned u = __builtin_bit_cast(unsigned, f);
    unsigned r = (u + 0x7fffu + ((u >> 16) & 1u)) & 0xffff0000u;
    hi = (unsigned short)(r >> 16);
    float res = f - __builtin_bit_cast(float, r);
    lo = bf16_rne_bits(res);
}
__device__ __forceinline__ void split8(const float* f, bf16x8& H, bf16x8& L) {
#pragma unroll
    for (int e = 0; e < 8; ++e) {
        unsigned short hi, lo; split1(f[e], hi, lo);
        H[e] = (short)hi; L[e] = (short)lo;
    }
}
__device__ __forceinline__ float tanh_fast(float v) {
    float e = __expf(2.0f * v);
    return 1.0f - 2.0f * __builtin_amdgcn_rcpf(e + 1.0f);
}

__global__ void zero_cnt_kernel(unsigned* cnt) {
    if (threadIdx.x == 0) cnt[0] = 0u;
}

// ---------------- weight split to fragment-major ----------------
// WF[mat][prec][c16][ks][lane*8+e]; mat: 0=Wi1 1=Wh1 2=Wi2 3=Wh2
// element = W[row = c16*16 + (lane&15)][k = ks*32 + (lane>>4)*8 + e]
__global__ __launch_bounds__(256) void wsplit_kernel(
    const float* __restrict__ Wi, const float* __restrict__ Wh,
    unsigned short* __restrict__ WF)
{
    unsigned id  = blockIdx.x * 256u + threadIdx.x;   // < 524288
    unsigned kc  = id & 127u;
    unsigned row = (id >> 7) & 1023u;
    unsigned m   = id >> 17;                           // 0..3

    const float* src = ((m & 1u) ? Wh : Wi) + (size_t)(m >> 1) * HCC * HCC
                     + (size_t)row * HCC + kc * 8u;
    float f[8];
    *(f32x4*)&f[0] = *(const f32x4*)&src[0];
    *(f32x4*)&f[4] = *(const f32x4*)&src[4];
    bf16x8 H, L; split8(f, H, L);

    unsigned c16 = row >> 4, ks = kc >> 2;
    unsigned lane = (row & 15u) + 16u * (kc & 3u);
    size_t bh_ = (((size_t)(m * 2u + 0u) * 64u + c16) * 32u + ks) * 512u + lane * 8u;
    size_t bl_ = (((size_t)(m * 2u + 1u) * 64u + c16) * 32u + ks) * 512u + lane * 8u;
    *(bf16x8*)&WF[bh_] = H;
    *(bf16x8*)&WF[bl_] = L;
}

// ---------------- pre1 = x*Wi1^T + (bi1+bh1), frag-major into d_out ----------------
// grid: (t, cg): 512*8 WGs, 256 thr; wave w owns ct32 = cg*4+w (32 cols), all 64 rows.
// out slot t: [rh][ct32][fi][lane][reg] fp32, 65536 floats.
__global__ __launch_bounds__(256) void pre1_gemm(
    const float* __restrict__ x, const float* __restrict__ bi, const float* __restrict__ bh,
    const unsigned short* __restrict__ WF, float* __restrict__ preO)
{
    __shared__ float xs[64 * 36];
    const unsigned t = blockIdx.x >> 3, cg = blockIdx.x & 7u;
    const unsigned tid = threadIdx.x, w = tid >> 6, lane = tid & 63u;
    const unsigned ct32 = cg * 4u + w;

    float b0 = bi[ct32 * 32u + (lane & 15u)]        + bh[ct32 * 32u + (lane & 15u)];
    float b1 = bi[ct32 * 32u + 16u + (lane & 15u)]  + bh[ct32 * 32u + 16u + (lane & 15u)];
    f32x4 acc[4][2];
#pragma unroll
    for (unsigned rt = 0; rt < 4; ++rt) {
        acc[rt][0] = (f32x4){b0, b0, b0, b0};
        acc[rt][1] = (f32x4){b1, b1, b1, b1};
    }
    const float* xt = x + (size_t)t * BH;

    for (unsigned ks = 0; ks < 32; ++ks) {
        {   // stage x chunk [64 rows x 32 k] into LDS
            unsigned row = tid >> 2, c8 = (tid & 3u) * 8u;
            const float* sp = xt + (size_t)row * HCC + ks * 32u + c8;
            *(f32x4*)&xs[row * 36u + c8]      = *(const f32x4*)&sp[0];
            *(f32x4*)&xs[row * 36u + c8 + 4u] = *(const f32x4*)&sp[4];
        }
        __syncthreads();
        bf16x8 bhv[2], blv[2];
#pragma unroll
        for (unsigned c16 = 0; c16 < 2; ++c16) {
            size_t base = (((size_t)(0u) * 64u + (ct32 * 2u + c16)) * 32u + ks) * 512u + lane * 8u;
            bhv[c16] = *(const bf16x8*)&WF[base];
            blv[c16] = *(const bf16x8*)&WF[base + (size_t)64u * 32u * 512u];
        }
#pragma unroll
        for (unsigned rt = 0; rt < 4; ++rt) {
            unsigned row = rt * 16u + (lane & 15u);
            unsigned k0 = (lane >> 4) * 8u;
            float f[8];
            *(f32x4*)&f[0] = *(const f32x4*)&xs[row * 36u + k0];
            *(f32x4*)&f[4] = *(const f32x4*)&xs[row * 36u + k0 + 4u];
            bf16x8 ah, al; split8(f, ah, al);
#pragma unroll
            for (unsigned c16 = 0; c16 < 2; ++c16) {
                acc[rt][c16] = __builtin_amdgcn_mfma_f32_16x16x32_bf16(ah, bhv[c16], acc[rt][c16], 0, 0, 0);
                acc[rt][c16] = __builtin_amdgcn_mfma_f32_16x16x32_bf16(al, bhv[c16], acc[rt][c16], 0, 0, 0);
                acc[rt][c16] = __builtin_amdgcn_mfma_f32_16x16x32_bf16(ah, blv[c16], acc[rt][c16], 0, 0, 0);
            }
        }
        __syncthreads();
    }
#pragma unroll
    for (unsigned rt = 0; rt < 4; ++rt)
#pragma unroll
        for (unsigned c16 = 0; c16 < 2; ++c16) {
            unsigned rh = rt >> 1, fi = (rt & 1u) * 2u + c16;
            size_t off = ((((size_t)t * 2u + rh) * 32u + ct32) * 4u + fi) * 256u + lane * 4u;
            *(f32x4*)&preO[off] = acc[rt][c16];
        }
}

// ---------------- persistent 3-group wavefront ----------------
__global__ __launch_bounds__(512, 1) void rnn_persist(
    const float* __restrict__ bi, const float* __restrict__ bh,
    const unsigned short* __restrict__ WF,
    unsigned short* __restrict__ h1F, unsigned short* __restrict__ h2F,
    float* __restrict__ pre2F, unsigned* __restrict__ cnt,
    float* __restrict__ seqO, float* __restrict__ hsO)
{
    __shared__ short WlS[65536];                 // 128 KiB [(prec*2+c16l)][ks][lane*8]
    __shared__ float redS[2 * 2 * 2 * 64 * 4];   // 8 KiB [cw][buf][r16][lane][reg]

    const unsigned wg  = blockIdx.x;
    const unsigned grp = wg >> 6;                // 0,1,2
    const unsigned sub = wg & 63u;
    const unsigned rh  = sub >> 5, ct = sub & 31u;
    const unsigned tid = threadIdx.x;
    const unsigned w   = tid >> 6, lane = tid & 63u;
    const unsigned kw  = w >> 1, cw = w & 1u;

    const unsigned mat = grp + 1u;               // G0:Wh1, G1:Wi2, G2:Wh2
#pragma unroll
    for (unsigned prec = 0; prec < 2; ++prec)
#pragma unroll
        for (unsigned c16l = 0; c16l < 2; ++c16l) {
            const unsigned short* sp = WF + (((size_t)(mat * 2u + prec) * 64u + (ct * 2u + c16l)) * 32u) * 512u;
            short* dp = &WlS[(prec * 2u + c16l) * 16384u];
            for (unsigned o = tid * 8u; o < 16384u; o += 4096u)
                *(bf16x8*)&dp[o] = *(const bf16x8*)&sp[o];
        }

    float binit = 0.f;
    if (grp == 1u) {
        unsigned c = HCC + ct * 32u + cw * 16u + (lane & 15u);
        binit = bi[c] + bh[c];
    }

    for (int s = 0; s < NSTAGE; ++s) {
        const bool active = (grp == 0u) ? (s <= 511) : (grp == 1u) ? (s >= 1 && s <= 512) : (s >= 2);
        if (active) {
            f32x4 acc0 = (f32x4){0.f, 0.f, 0.f, 0.f};
            f32x4 acc1 = (f32x4){0.f, 0.f, 0.f, 0.f};
            if (kw == 0u) {
                if (grp == 0u) {
                    const float* pp = seqO + (((size_t)s * 2u + rh) * 32u + ct) * 1024u;
                    acc0 = *(const f32x4*)&pp[(0u * 2u + cw) * 256u + lane * 4u];
                    acc1 = *(const f32x4*)&pp[(1u * 2u + cw) * 256u + lane * 4u];
                } else if (grp == 1u) {
                    acc0 = (f32x4){binit, binit, binit, binit};
                    acc1 = acc0;
                } else {
                    const float* pp = pre2F + (size_t)((s - 2) & 1) * PRE2_FLOATS
                                    + ((size_t)rh * 32u + ct) * 1024u;
                    acc0 = *(const f32x4*)&pp[(0u * 2u + cw) * 256u + lane * 4u];
                    acc1 = *(const f32x4*)&pp[(1u * 2u + cw) * 256u + lane * 4u];
                }
            }
            const bool do_h = (grp == 0u) ? (s > 0) : (grp == 1u) ? true : (s > 2);
            if (do_h) {
                const unsigned short* Aslab = (grp <= 1u ? h1F : h2F) + (size_t)((s - 1) & 1) * SLAB_SHORTS;
                const unsigned a00 = ((rh * 2u + 0u) * 2u + 0u) * 16384u;  // prec0 r16_0
                const unsigned a01 = ((rh * 2u + 0u) * 2u + 1u) * 16384u;  // prec0 r16_1
                const unsigned a10 = ((rh * 2u + 1u) * 2u + 0u) * 16384u;  // prec1 r16_0
                const unsigned a11 = ((rh * 2u + 1u) * 2u + 1u) * 16384u;  // prec1 r16_1
                const unsigned bh_ = (0u * 2u + cw) * 16384u;
                const unsigned bl_ = (1u * 2u + cw) * 16384u;
#pragma unroll
                for (unsigned i = 0; i < 8; ++i) {
                    const unsigned ao = (kw * 8u + i) * 512u + lane * 8u;
                    bf16x8 ah0 = *(const bf16x8*)&Aslab[a00 + ao];
                    bf16x8 ah1 = *(const bf16x8*)&Aslab[a01 + ao];
                    bf16x8 al0 = *(const bf16x8*)&Aslab[a10 + ao];
                    bf16x8 al1 = *(const bf16x8*)&Aslab[a11 + ao];
                    bf16x8 bbh = *(const bf16x8*)&WlS[bh_ + ao];
                    bf16x8 bbl = *(const bf16x8*)&WlS[bl_ + ao];
                    acc0 = __builtin_amdgcn_mfma_f32_16x16x32_bf16(ah0, bbh, acc0, 0, 0, 0);
                    acc1 = __builtin_amdgcn_mfma_f32_16x16x32_bf16(ah1, bbh, acc1, 0, 0, 0);
                    acc0 = __builtin_amdgcn_mfma_f32_16x16x32_bf16(al0, bbh, acc0, 0, 0, 0);
                    acc1 = __builtin_amdgcn_mfma_f32_16x16x32_bf16(al1, bbh, acc1, 0, 0, 0);
                    acc0 = __builtin_amdgcn_mfma_f32_16x16x32_bf16(ah0, bbl, acc0, 0, 0, 0);
                    acc1 = __builtin_amdgcn_mfma_f32_16x16x32_bf16(ah1, bbl, acc1, 0, 0, 0);
                }
            }
            // reduce over kw (4-way) per cw
#define REDP(buf, r16) (&redS[(((cw * 2u + (buf)) * 2u + (r16)) * 64u + lane) * 4u])
            if (kw >= 2u) { *(f32x4*)REDP(kw - 2u, 0u) = acc0; *(f32x4*)REDP(kw - 2u, 1u) = acc1; }
            __syncthreads();
            if (kw < 2u) { acc0 += *(const f32x4*)REDP(kw, 0u); acc1 += *(const f32x4*)REDP(kw, 1u); }
            __syncthreads();
            if (kw == 1u) { *(f32x4*)REDP(0u, 0u) = acc0; *(f32x4*)REDP(0u, 1u) = acc1; }
            __syncthreads();
            if (kw == 0u) {
                acc0 += *(const f32x4*)REDP(0u, 0u);
                acc1 += *(const f32x4*)REDP(0u, 1u);
                if (grp == 1u) {
                    float* pp = pre2F + (size_t)((s - 1) & 1) * PRE2_FLOATS
                              + ((size_t)rh * 32u + ct) * 1024u;
                    *(f32x4*)&pp[(0u * 2u + cw) * 256u + lane * 4u] = acc0;
                    *(f32x4*)&pp[(1u * 2u + cw) * 256u + lane * 4u] = acc1;
                } else {
                    unsigned short* hdst = (grp == 0u ? h1F : h2F)
                        + (size_t)((grp == 0u ? s : s - 2) & 1) * SLAB_SHORTS;
                    const int t2 = s - 2;
#pragma unroll
                    for (unsigned r16 = 0; r16 < 2; ++r16) {
                        f32x4 a = r16 ? acc1 : acc0;
#pragma unroll
                        for (unsigned rr = 0; rr < 4; ++rr) {
                            float v = tanh_fast(a[rr]);
                            unsigned short hi2, lo2; split1(v, hi2, lo2);
                            unsigned lane_c = (lane >> 4) * 4u + rr + 16u * (cw * 2u + ((lane >> 3) & 1u));
                            unsigned so = ((rh * 2u + 0u) * 2u + r16) * 16384u + ct * 512u + lane_c * 8u + (lane & 7u);
                            hdst[so] = hi2;
                            hdst[so + 32768u] = lo2;
                            unsigned R = rh * 32u + r16 * 16u + (lane >> 4) * 4u + rr;
                            unsigned C = ct * 32u + cw * 16u + (lane & 15u);
                            if (grp == 0u) {
                                if (s == 511) hsO[(size_t)R * HCC + C] = v;
                            } else {
                                seqO[((size_t)t2 * 64u + R) * HCC + C] = v;
                                if (s == 513) hsO[BH + (size_t)R * HCC + C] = v;
                            }
                        }
                    }
                }
            }
#undef REDP
        }
        if (s < NSTAGE - 1) {
            __syncthreads();
            if (tid == 0u) {
                __hip_atomic_fetch_add(cnt, 1u, __ATOMIC_RELEASE, __HIP_MEMORY_SCOPE_AGENT);
                const unsigned tgt = (unsigned)(s + 1) * NWG;
                while (__hip_atomic_load(cnt, __ATOMIC_ACQUIRE, __HIP_MEMORY_SCOPE_AGENT) < tgt)
                    __builtin_amdgcn_s_sleep(1);
            }
            __syncthreads();
        }
    }
}

extern "C" void kernel_launch(void* const* d_in, const int* in_sizes, int n_in,
                              void* d_out, int out_size, void* d_ws, size_t ws_size,
                              hipStream_t stream) {
    const float* x  = (const float*)d_in[0];
    const float* Wi = (const float*)d_in[1];
    const float* bi = (const float*)d_in[2];
    const float* Wh = (const float*)d_in[3];
    const float* bh = (const float*)d_in[4];

    float* seqO = (float*)d_out;
    float* hsO  = seqO + (size_t)T_STEPS * BH;

    unsigned short* wsS = (unsigned short*)d_ws;
    unsigned short* WF  = wsS;
    unsigned short* h1F = wsS + OFF_H1F;
    unsigned short* h2F = wsS + OFF_H2F;
    float* pre2F = (float*)((char*)d_ws + OFF_PRE2_BYTES);
    unsigned* cnt = (unsigned*)((char*)d_ws + CNT_BYTE_OFF);

    zero_cnt_kernel<<<1, 64, 0, stream>>>(cnt);
    wsplit_kernel<<<2048, 256, 0, stream>>>(Wi, Wh, WF);
    pre1_gemm<<<4096, 256, 0, stream>>>(x, bi, bh, WF, seqO);
    rnn_persist<<<NWG, 512, 0, stream>>>(bi, bh, WF, h1F, h2F, pre2F, cnt, seqO, hsO);
}

// Round 5
// 7724.008 us; speedup vs baseline: 2.7493x; 1.5082x over previous
//
#include <hip/hip_runtime.h>

// 2-layer tanh RNN, T=512, B=64, IC=HC=1024, fp32 in/out.
// pre1 = x*Wi1+b precomputed (parallel MFMA GEMM, frag-major into d_out).
// Persistent kernel, 3 groups of 64 WGs, per-group dependency counters
// (monotonic, one per stage*group), relaxed polling + single acquire:
//   G0 (wg 0..63):    h1[s]   = tanh(pre1[s] + h1[s-1]*Wh1^T)        s=0..511
//   G1 (wg 64..127):  pre2[s-1] = h1[s-1]*Wi2^T + b2                 s=1..512
//   G2 (wg 128..191): h2[s-2] = tanh(pre2[s-2] + h2[s-3]*Wh2^T)      s=2..513
// All GEMMs split-bf16 (hi+lo, drop lo*lo) MFMA 16x16x32, fp32 accumulate.
// Rings 4-deep. NOTE (round-4 bugfix): G2 reads h2[s-3] -> slot (s-3)&3.

#define T_STEPS 512
#define HCC     1024
#define BH      65536
#define NWG     192

typedef __attribute__((ext_vector_type(8))) short  bf16x8;
typedef __attribute__((ext_vector_type(4))) float  f32x4;

// ws layout
#define WF_SHORTS   8388608u                 /* 16 MiB frag-major split weights */
#define SLAB_SHORTS 131072u                  /* one h slab: 256 KiB */
#define OFF_H1F     WF_SHORTS
#define OFF_H2F     (OFF_H1F + 4u*SLAB_SHORTS)
#define OFF_PRE2_BYTES ((size_t)(OFF_H2F + 4u*SLAB_SHORTS) * 2u)   /* 18,874,368 */
#define PRE2_FLOATS 65536u                   /* one pre2 slot: 256 KiB */
#define CNT_BYTE_OFF (OFF_PRE2_BYTES + 4u*(size_t)PRE2_FLOATS*4u)  /* 19,922,944 */
#define CNT_UINTS   (516u*3u*32u)            /* 128B-strided counters */

__device__ __forceinline__ unsigned cidx(int s, unsigned g) {
    return ((unsigned)s * 3u + g) * 32u;
}

__device__ __forceinline__ unsigned short bf16_rne_bits(float f) {
    unsigned u = __builtin_bit_cast(unsigned, f);
    unsigned r = u + 0x7fffu + ((u >> 16) & 1u);
    return (unsigned short)(r >> 16);
}
__device__ __forceinline__ void split1(float f, unsigned short& hi, unsigned short& lo) {
    unsigned u = __builtin_bit_cast(unsigned, f);
    unsigned r = (u + 0x7fffu + ((u >> 16) & 1u)) & 0xffff0000u;
    hi = (unsigned short)(r >> 16);
    float res = f - __builtin_bit_cast(float, r);
    lo = bf16_rne_bits(res);
}
__device__ __forceinline__ void split8(const float* f, bf16x8& H, bf16x8& L) {
#pragma unroll
    for (int e = 0; e < 8; ++e) {
        unsigned short hi, lo; split1(f[e], hi, lo);
        H[e] = (short)hi; L[e] = (short)lo;
    }
}
__device__ __forceinline__ float tanh_fast(float v) {
    float e = __expf(2.0f * v);
    return 1.0f - 2.0f * __builtin_amdgcn_rcpf(e + 1.0f);
}

__global__ __launch_bounds__(256) void zero_cnt_kernel(unsigned* cnt, unsigned n) {
    unsigned i = blockIdx.x * 256u + threadIdx.x;
    if (i < n) cnt[i] = 0u;
}

// ---------------- weight split to fragment-major ----------------
// WF[mat][prec][c16][ks][lane*8+e]; mat: 0=Wi1 1=Wh1 2=Wi2 3=Wh2
__global__ __launch_bounds__(256) void wsplit_kernel(
    const float* __restrict__ Wi, const float* __restrict__ Wh,
    unsigned short* __restrict__ WF)
{
    unsigned id  = blockIdx.x * 256u + threadIdx.x;   // < 524288
    unsigned kc  = id & 127u;
    unsigned row = (id >> 7) & 1023u;
    unsigned m   = id >> 17;                           // 0..3

    const float* src = ((m & 1u) ? Wh : Wi) + (size_t)(m >> 1) * HCC * HCC
                     + (size_t)row * HCC + kc * 8u;
    float f[8];
    *(f32x4*)&f[0] = *(const f32x4*)&src[0];
    *(f32x4*)&f[4] = *(const f32x4*)&src[4];
    bf16x8 H, L; split8(f, H, L);

    unsigned c16 = row >> 4, ks = kc >> 2;
    unsigned lane = (row & 15u) + 16u * (kc & 3u);
    size_t bh_ = (((size_t)(m * 2u + 0u) * 64u + c16) * 32u + ks) * 512u + lane * 8u;
    size_t bl_ = (((size_t)(m * 2u + 1u) * 64u + c16) * 32u + ks) * 512u + lane * 8u;
    *(bf16x8*)&WF[bh_] = H;
    *(bf16x8*)&WF[bl_] = L;
}

// ---------------- pre1 = x*Wi1^T + (bi1+bh1), frag-major into d_out ----------------
__global__ __launch_bounds__(256) void pre1_gemm(
    const float* __restrict__ x, const float* __restrict__ bi, const float* __restrict__ bh,
    const unsigned short* __restrict__ WF, float* __restrict__ preO)
{
    __shared__ float xs[64 * 36];
    const unsigned t = blockIdx.x >> 3, cg = blockIdx.x & 7u;
    const unsigned tid = threadIdx.x, w = tid >> 6, lane = tid & 63u;
    const unsigned ct32 = cg * 4u + w;

    float b0 = bi[ct32 * 32u + (lane & 15u)]        + bh[ct32 * 32u + (lane & 15u)];
    float b1 = bi[ct32 * 32u + 16u + (lane & 15u)]  + bh[ct32 * 32u + 16u + (lane & 15u)];
    f32x4 acc[4][2];
#pragma unroll
    for (unsigned rt = 0; rt < 4; ++rt) {
        acc[rt][0] = (f32x4){b0, b0, b0, b0};
        acc[rt][1] = (f32x4){b1, b1, b1, b1};
    }
    const float* xt = x + (size_t)t * BH;

    for (unsigned ks = 0; ks < 32; ++ks) {
        {
            unsigned row = tid >> 2, c8 = (tid & 3u) * 8u;
            const float* sp = xt + (size_t)row * HCC + ks * 32u + c8;
            *(f32x4*)&xs[row * 36u + c8]      = *(const f32x4*)&sp[0];
            *(f32x4*)&xs[row * 36u + c8 + 4u] = *(const f32x4*)&sp[4];
        }
        __syncthreads();
        bf16x8 bhv[2], blv[2];
#pragma unroll
        for (unsigned c16 = 0; c16 < 2; ++c16) {
            size_t base = (((size_t)(0u) * 64u + (ct32 * 2u + c16)) * 32u + ks) * 512u + lane * 8u;
            bhv[c16] = *(const bf16x8*)&WF[base];
            blv[c16] = *(const bf16x8*)&WF[base + (size_t)64u * 32u * 512u];
        }
#pragma unroll
        for (unsigned rt = 0; rt < 4; ++rt) {
            unsigned row = rt * 16u + (lane & 15u);
            unsigned k0 = (lane >> 4) * 8u;
            float f[8];
            *(f32x4*)&f[0] = *(const f32x4*)&xs[row * 36u + k0];
            *(f32x4*)&f[4] = *(const f32x4*)&xs[row * 36u + k0 + 4u];
            bf16x8 ah, al; split8(f, ah, al);
#pragma unroll
            for (unsigned c16 = 0; c16 < 2; ++c16) {
                acc[rt][c16] = __builtin_amdgcn_mfma_f32_16x16x32_bf16(ah, bhv[c16], acc[rt][c16], 0, 0, 0);
                acc[rt][c16] = __builtin_amdgcn_mfma_f32_16x16x32_bf16(al, bhv[c16], acc[rt][c16], 0, 0, 0);
                acc[rt][c16] = __builtin_amdgcn_mfma_f32_16x16x32_bf16(ah, blv[c16], acc[rt][c16], 0, 0, 0);
            }
        }
        __syncthreads();
    }
#pragma unroll
    for (unsigned rt = 0; rt < 4; ++rt)
#pragma unroll
        for (unsigned c16 = 0; c16 < 2; ++c16) {
            unsigned rh = rt >> 1, fi = (rt & 1u) * 2u + c16;
            size_t off = ((((size_t)t * 2u + rh) * 32u + ct32) * 4u + fi) * 256u + lane * 4u;
            *(f32x4*)&preO[off] = acc[rt][c16];
        }
}

// ---------------- persistent 3-group pipeline ----------------
__global__ __launch_bounds__(512, 1) void rnn_persist(
    const float* __restrict__ bi, const float* __restrict__ bh,
    const unsigned short* __restrict__ WF,
    unsigned short* __restrict__ h1F, unsigned short* __restrict__ h2F,
    float* __restrict__ pre2F, unsigned* __restrict__ cnt,
    float* __restrict__ seqO, float* __restrict__ hsO)
{
    __shared__ short WlS[65536];                 // 128 KiB weights (hi+lo, 32 cols)
    __shared__ float redS[2 * 2 * 2 * 64 * 4];   // 8 KiB reduction

    const unsigned wg  = blockIdx.x;
    const unsigned grp = wg >> 6;                // 0,1,2
    const unsigned sub = wg & 63u;
    const unsigned rh  = sub >> 5, ct = sub & 31u;
    const unsigned tid = threadIdx.x;
    const unsigned w   = tid >> 6, lane = tid & 63u;
    const unsigned kw  = w >> 1, cw = w & 1u;

    const unsigned mat = grp + 1u;               // G0:Wh1, G1:Wi2, G2:Wh2
#pragma unroll
    for (unsigned prec = 0; prec < 2; ++prec)
#pragma unroll
        for (unsigned c16l = 0; c16l < 2; ++c16l) {
            const unsigned short* sp = WF + (((size_t)(mat * 2u + prec) * 64u + (ct * 2u + c16l)) * 32u) * 512u;
            short* dp = &WlS[(prec * 2u + c16l) * 16384u];
            for (unsigned o = tid * 8u; o < 16384u; o += 4096u)
                *(bf16x8*)&dp[o] = *(const bf16x8*)&sp[o];
        }

    float binit = 0.f;
    if (grp == 1u) {
        unsigned c = HCC + ct * 32u + cw * 16u + (lane & 15u);
        binit = bi[c] + bh[c];
    }

    const int s0 = (grp == 0u) ? 0 : (grp == 1u) ? 1 : 2;
    const int s1 = s0 + 511;

    for (int s = s0; s <= s1; ++s) {
        // ---- dependency waits (relaxed poll, one acquire) ----
        if (tid == 0u) {
            const unsigned* pa = nullptr;   // anti-dep (3 back, usually clear)
            const unsigned* pm = nullptr;   // main dep (1 back)
            if (grp == 0u) {
                if (s >= 4) pa = cnt + cidx(s - 3, 1u);
                if (s >= 1) pm = cnt + cidx(s - 1, 0u);
            } else if (grp == 1u) {
                if (s >= 5) pa = cnt + cidx(s - 3, 2u);
                pm = cnt + cidx(s - 1, 0u);
            } else {
                if (s >= 3) pa = cnt + cidx(s - 1, 2u);
                pm = cnt + cidx(s - 1, 1u);
            }
            if (pa)
                while (__hip_atomic_load(pa, __ATOMIC_RELAXED, __HIP_MEMORY_SCOPE_AGENT) < 64u)
                    __builtin_amdgcn_s_sleep(1);
            if (pm) {
                while (__hip_atomic_load(pm, __ATOMIC_RELAXED, __HIP_MEMORY_SCOPE_AGENT) < 64u)
                    __builtin_amdgcn_s_sleep(1);
                (void)__hip_atomic_load(pm, __ATOMIC_ACQUIRE, __HIP_MEMORY_SCOPE_AGENT);
            }
        }
        __syncthreads();

        // ---- compute ----
        f32x4 acc0 = (f32x4){0.f, 0.f, 0.f, 0.f};
        f32x4 acc1 = (f32x4){0.f, 0.f, 0.f, 0.f};
        if (kw == 0u) {
            if (grp == 0u) {
                const float* pp = seqO + (((size_t)s * 2u + rh) * 32u + ct) * 1024u;
                acc0 = *(const f32x4*)&pp[(0u * 2u + cw) * 256u + lane * 4u];
                acc1 = *(const f32x4*)&pp[(1u * 2u + cw) * 256u + lane * 4u];
            } else if (grp == 1u) {
                acc0 = (f32x4){binit, binit, binit, binit};
                acc1 = acc0;
            } else {
                const float* pp = pre2F + (size_t)((s - 2) & 3) * PRE2_FLOATS
                                + ((size_t)rh * 32u + ct) * 1024u;
                acc0 = *(const f32x4*)&pp[(0u * 2u + cw) * 256u + lane * 4u];
                acc1 = *(const f32x4*)&pp[(1u * 2u + cw) * 256u + lane * 4u];
            }
        }
        const bool do_h = (grp == 0u) ? (s > 0) : (grp == 1u) ? true : (s > 2);
        if (do_h) {
            // G0/G1 read h1[s-1] (written at stage s-1, slot (s-1)&3).
            // G2 reads h2[s-3] (written at stage s-1, slot (s-3)&3).  [bugfix]
            const unsigned aslot = (grp == 2u) ? ((unsigned)(s - 3) & 3u)
                                               : ((unsigned)(s - 1) & 3u);
            const unsigned short* Aslab = (grp <= 1u ? h1F : h2F)
                                        + (size_t)aslot * SLAB_SHORTS;
            const unsigned a00 = ((rh * 2u + 0u) * 2u + 0u) * 16384u;
            const unsigned a01 = ((rh * 2u + 0u) * 2u + 1u) * 16384u;
            const unsigned a10 = ((rh * 2u + 1u) * 2u + 0u) * 16384u;
            const unsigned a11 = ((rh * 2u + 1u) * 2u + 1u) * 16384u;
            const unsigned bh_ = (0u * 2u + cw) * 16384u;
            const unsigned bl_ = (1u * 2u + cw) * 16384u;
#pragma unroll
            for (unsigned i = 0; i < 8; ++i) {
                const unsigned ao = (kw * 8u + i) * 512u + lane * 8u;
                bf16x8 ah0 = *(const bf16x8*)&Aslab[a00 + ao];
                bf16x8 ah1 = *(const bf16x8*)&Aslab[a01 + ao];
                bf16x8 al0 = *(const bf16x8*)&Aslab[a10 + ao];
                bf16x8 al1 = *(const bf16x8*)&Aslab[a11 + ao];
                bf16x8 bbh = *(const bf16x8*)&WlS[bh_ + ao];
                bf16x8 bbl = *(const bf16x8*)&WlS[bl_ + ao];
                acc0 = __builtin_amdgcn_mfma_f32_16x16x32_bf16(ah0, bbh, acc0, 0, 0, 0);
                acc1 = __builtin_amdgcn_mfma_f32_16x16x32_bf16(ah1, bbh, acc1, 0, 0, 0);
                acc0 = __builtin_amdgcn_mfma_f32_16x16x32_bf16(al0, bbh, acc0, 0, 0, 0);
                acc1 = __builtin_amdgcn_mfma_f32_16x16x32_bf16(al1, bbh, acc1, 0, 0, 0);
                acc0 = __builtin_amdgcn_mfma_f32_16x16x32_bf16(ah0, bbl, acc0, 0, 0, 0);
                acc1 = __builtin_amdgcn_mfma_f32_16x16x32_bf16(ah1, bbl, acc1, 0, 0, 0);
            }
        }
        // ---- reduce over kw (4-way) per cw ----
#define REDP(buf, r16) (&redS[(((cw * 2u + (buf)) * 2u + (r16)) * 64u + lane) * 4u])
        if (kw >= 2u) { *(f32x4*)REDP(kw - 2u, 0u) = acc0; *(f32x4*)REDP(kw - 2u, 1u) = acc1; }
        __syncthreads();
        if (kw < 2u) { acc0 += *(const f32x4*)REDP(kw, 0u); acc1 += *(const f32x4*)REDP(kw, 1u); }
        __syncthreads();
        if (kw == 1u) { *(f32x4*)REDP(0u, 0u) = acc0; *(f32x4*)REDP(0u, 1u) = acc1; }
        __syncthreads();
        if (kw == 0u) {
            acc0 += *(const f32x4*)REDP(0u, 0u);
            acc1 += *(const f32x4*)REDP(0u, 1u);
            if (grp == 1u) {
                float* pp = pre2F + (size_t)((s - 1) & 3) * PRE2_FLOATS
                          + ((size_t)rh * 32u + ct) * 1024u;
                *(f32x4*)&pp[(0u * 2u + cw) * 256u + lane * 4u] = acc0;
                *(f32x4*)&pp[(1u * 2u + cw) * 256u + lane * 4u] = acc1;
            } else {
                unsigned short* hdst = (grp == 0u ? h1F : h2F)
                    + (size_t)((grp == 0u ? s : s - 2) & 3) * SLAB_SHORTS;
                const int t2 = s - 2;
#pragma unroll
                for (unsigned r16 = 0; r16 < 2; ++r16) {
                    f32x4 a = r16 ? acc1 : acc0;
#pragma unroll
                    for (unsigned rr = 0; rr < 4; ++rr) {
                        float v = tanh_fast(a[rr]);
                        unsigned short hi2, lo2; split1(v, hi2, lo2);
                        unsigned lane_c = (lane >> 4) * 4u + rr + 16u * (cw * 2u + ((lane >> 3) & 1u));
                        unsigned so = ((rh * 2u + 0u) * 2u + r16) * 16384u + ct * 512u + lane_c * 8u + (lane & 7u);
                        hdst[so] = hi2;
                        hdst[so + 32768u] = lo2;
                        unsigned R = rh * 32u + r16 * 16u + (lane >> 4) * 4u + rr;
                        unsigned C = ct * 32u + cw * 16u + (lane & 15u);
                        if (grp == 0u) {
                            if (s == 511) hsO[(size_t)R * HCC + C] = v;
                        } else {
                            seqO[((size_t)t2 * 64u + R) * HCC + C] = v;
                            if (s == 513) hsO[BH + (size_t)R * HCC + C] = v;
                        }
                    }
                }
            }
        }
#undef REDP
        // ---- signal (release) ----
        __syncthreads();
        if (tid == 0u)
            __hip_atomic_fetch_add(cnt + cidx(s, grp), 1u,
                                   __ATOMIC_RELEASE, __HIP_MEMORY_SCOPE_AGENT);
    }
}

extern "C" void kernel_launch(void* const* d_in, const int* in_sizes, int n_in,
                              void* d_out, int out_size, void* d_ws, size_t ws_size,
                              hipStream_t stream) {
    const float* x  = (const float*)d_in[0];
    const float* Wi = (const float*)d_in[1];
    const float* bi = (const float*)d_in[2];
    const float* Wh = (const float*)d_in[3];
    const float* bh = (const float*)d_in[4];

    float* seqO = (float*)d_out;
    float* hsO  = seqO + (size_t)T_STEPS * BH;

    unsigned short* wsS = (unsigned short*)d_ws;
    unsigned short* WF  = wsS;
    unsigned short* h1F = wsS + OFF_H1F;
    unsigned short* h2F = wsS + OFF_H2F;
    float* pre2F = (float*)((char*)d_ws + OFF_PRE2_BYTES);
    unsigned* cnt = (unsigned*)((char*)d_ws + CNT_BYTE_OFF);

    zero_cnt_kernel<<<(CNT_UINTS + 255u) / 256u, 256, 0, stream>>>(cnt, CNT_UINTS);
    wsplit_kernel<<<2048, 256, 0, stream>>>(Wi, Wh, WF);
    pre1_gemm<<<4096, 256, 0, stream>>>(x, bi, bh, WF, seqO);
    rnn_persist<<<NWG, 512, 0, stream>>>(bi, bh, WF, h1F, h2F, pre2F, cnt, seqO, hsO);
}

// Round 6
// 4610.880 us; speedup vs baseline: 4.6055x; 1.6752x over previous
//
#include <hip/hip_runtime.h>

// 2-layer tanh RNN, T=512, B=64, IC=HC=1024, fp32 in/out.
// pre1 = x*Wi1+b precomputed (parallel MFMA GEMM, frag-major into d_out).
// Persistent kernel, 3 groups of 64 WGs, per-group monotonic dependency
// counters. Cross-WG data moves via sc0/sc1 write-through stores + sc0/sc1
// coherent loads (no acquire-invalidate / release-writeback cache ops):
//   G0 (wg 0..63):    h1[s]   = tanh(pre1[s] + h1[s-1]*Wh1^T)        s=0..511
//   G1 (wg 64..127):  pre2[s-1] = h1[s-1]*Wi2^T + b2                 s=1..512
//   G2 (wg 128..191): h2[s-2] = tanh(pre2[s-2] + h2[s-3]*Wh2^T)      s=2..513
// All GEMMs split-bf16 (hi+lo, drop lo*lo) MFMA 16x16x32, fp32 accumulate.
// Rings 4-deep; G2 reads h2[s-3] -> slot (s-3)&3.

#define T_STEPS 512
#define HCC     1024
#define BH      65536
#define NWG     192

typedef __attribute__((ext_vector_type(8))) short  bf16x8;
typedef __attribute__((ext_vector_type(4))) float  f32x4;

// ws layout
#define WF_SHORTS   8388608u                 /* 16 MiB frag-major split weights */
#define SLAB_SHORTS 131072u                  /* one h slab: 256 KiB */
#define OFF_H1F     WF_SHORTS
#define OFF_H2F     (OFF_H1F + 4u*SLAB_SHORTS)
#define OFF_PRE2_BYTES ((size_t)(OFF_H2F + 4u*SLAB_SHORTS) * 2u)   /* 18,874,368 */
#define PRE2_FLOATS 65536u                   /* one pre2 slot: 256 KiB */
#define CNT_BYTE_OFF (OFF_PRE2_BYTES + 4u*(size_t)PRE2_FLOATS*4u)  /* 19,922,944 */
#define CNT_UINTS   (516u*3u*32u)            /* 128B-strided counters */

__device__ __forceinline__ unsigned cidx(int s, unsigned g) {
    return ((unsigned)s * 3u + g) * 32u;
}

// ---- coherent (device-scope) 16B load/store, bypassing L1/L2 ----
__device__ __forceinline__ void gload_b128_cc(bf16x8& d, const unsigned short* p) {
    asm volatile("global_load_dwordx4 %0, %1, off sc0 sc1" : "=v"(d) : "v"(p));
}
__device__ __forceinline__ void gload_f128_cc(f32x4& d, const float* p) {
    asm volatile("global_load_dwordx4 %0, %1, off sc0 sc1" : "=v"(d) : "v"(p));
}
__device__ __forceinline__ void gstore_b128_cc(bf16x8 v, unsigned short* p) {
    asm volatile("global_store_dwordx4 %0, %1, off sc0 sc1" :: "v"(p), "v"(v) : "memory");
}
__device__ __forceinline__ void gstore_f128_cc(f32x4 v, float* p) {
    asm volatile("global_store_dwordx4 %0, %1, off sc0 sc1" :: "v"(p), "v"(v) : "memory");
}
__device__ __forceinline__ void vm_drain() {
    asm volatile("s_waitcnt vmcnt(0)" ::: "memory");
}

__device__ __forceinline__ unsigned short bf16_rne_bits(float f) {
    unsigned u = __builtin_bit_cast(unsigned, f);
    unsigned r = u + 0x7fffu + ((u >> 16) & 1u);
    return (unsigned short)(r >> 16);
}
__device__ __forceinline__ void split1(float f, unsigned short& hi, unsigned short& lo) {
    unsigned u = __builtin_bit_cast(unsigned, f);
    unsigned r = (u + 0x7fffu + ((u >> 16) & 1u)) & 0xffff0000u;
    hi = (unsigned short)(r >> 16);
    float res = f - __builtin_bit_cast(float, r);
    lo = bf16_rne_bits(res);
}
__device__ __forceinline__ void split8(const float* f, bf16x8& H, bf16x8& L) {
#pragma unroll
    for (int e = 0; e < 8; ++e) {
        unsigned short hi, lo; split1(f[e], hi, lo);
        H[e] = (short)hi; L[e] = (short)lo;
    }
}
__device__ __forceinline__ float tanh_fast(float v) {
    float e = __expf(2.0f * v);
    return 1.0f - 2.0f * __builtin_amdgcn_rcpf(e + 1.0f);
}

__global__ __launch_bounds__(256) void zero_cnt_kernel(unsigned* cnt, unsigned n) {
    unsigned i = blockIdx.x * 256u + threadIdx.x;
    if (i < n) cnt[i] = 0u;
}

// ---------------- weight split to fragment-major ----------------
// WF[mat][prec][c16][ks][lane*8+e]; mat: 0=Wi1 1=Wh1 2=Wi2 3=Wh2
__global__ __launch_bounds__(256) void wsplit_kernel(
    const float* __restrict__ Wi, const float* __restrict__ Wh,
    unsigned short* __restrict__ WF)
{
    unsigned id  = blockIdx.x * 256u + threadIdx.x;   // < 524288
    unsigned kc  = id & 127u;
    unsigned row = (id >> 7) & 1023u;
    unsigned m   = id >> 17;                           // 0..3

    const float* src = ((m & 1u) ? Wh : Wi) + (size_t)(m >> 1) * HCC * HCC
                     + (size_t)row * HCC + kc * 8u;
    float f[8];
    *(f32x4*)&f[0] = *(const f32x4*)&src[0];
    *(f32x4*)&f[4] = *(const f32x4*)&src[4];
    bf16x8 H, L; split8(f, H, L);

    unsigned c16 = row >> 4, ks = kc >> 2;
    unsigned lane = (row & 15u) + 16u * (kc & 3u);
    size_t bh_ = (((size_t)(m * 2u + 0u) * 64u + c16) * 32u + ks) * 512u + lane * 8u;
    size_t bl_ = (((size_t)(m * 2u + 1u) * 64u + c16) * 32u + ks) * 512u + lane * 8u;
    *(bf16x8*)&WF[bh_] = H;
    *(bf16x8*)&WF[bl_] = L;
}

// ---------------- pre1 = x*Wi1^T + (bi1+bh1), frag-major into d_out ----------------
__global__ __launch_bounds__(256) void pre1_gemm(
    const float* __restrict__ x, const float* __restrict__ bi, const float* __restrict__ bh,
    const unsigned short* __restrict__ WF, float* __restrict__ preO)
{
    __shared__ float xs[64 * 36];
    const unsigned t = blockIdx.x >> 3, cg = blockIdx.x & 7u;
    const unsigned tid = threadIdx.x, w = tid >> 6, lane = tid & 63u;
    const unsigned ct32 = cg * 4u + w;

    float b0 = bi[ct32 * 32u + (lane & 15u)]        + bh[ct32 * 32u + (lane & 15u)];
    float b1 = bi[ct32 * 32u + 16u + (lane & 15u)]  + bh[ct32 * 32u + 16u + (lane & 15u)];
    f32x4 acc[4][2];
#pragma unroll
    for (unsigned rt = 0; rt < 4; ++rt) {
        acc[rt][0] = (f32x4){b0, b0, b0, b0};
        acc[rt][1] = (f32x4){b1, b1, b1, b1};
    }
    const float* xt = x + (size_t)t * BH;

    for (unsigned ks = 0; ks < 32; ++ks) {
        {
            unsigned row = tid >> 2, c8 = (tid & 3u) * 8u;
            const float* sp = xt + (size_t)row * HCC + ks * 32u + c8;
            *(f32x4*)&xs[row * 36u + c8]      = *(const f32x4*)&sp[0];
            *(f32x4*)&xs[row * 36u + c8 + 4u] = *(const f32x4*)&sp[4];
        }
        __syncthreads();
        bf16x8 bhv[2], blv[2];
#pragma unroll
        for (unsigned c16 = 0; c16 < 2; ++c16) {
            size_t base = (((size_t)(0u) * 64u + (ct32 * 2u + c16)) * 32u + ks) * 512u + lane * 8u;
            bhv[c16] = *(const bf16x8*)&WF[base];
            blv[c16] = *(const bf16x8*)&WF[base + (size_t)64u * 32u * 512u];
        }
#pragma unroll
        for (unsigned rt = 0; rt < 4; ++rt) {
            unsigned row = rt * 16u + (lane & 15u);
            unsigned k0 = (lane >> 4) * 8u;
            float f[8];
            *(f32x4*)&f[0] = *(const f32x4*)&xs[row * 36u + k0];
            *(f32x4*)&f[4] = *(const f32x4*)&xs[row * 36u + k0 + 4u];
            bf16x8 ah, al; split8(f, ah, al);
#pragma unroll
            for (unsigned c16 = 0; c16 < 2; ++c16) {
                acc[rt][c16] = __builtin_amdgcn_mfma_f32_16x16x32_bf16(ah, bhv[c16], acc[rt][c16], 0, 0, 0);
                acc[rt][c16] = __builtin_amdgcn_mfma_f32_16x16x32_bf16(al, bhv[c16], acc[rt][c16], 0, 0, 0);
                acc[rt][c16] = __builtin_amdgcn_mfma_f32_16x16x32_bf16(ah, blv[c16], acc[rt][c16], 0, 0, 0);
            }
        }
        __syncthreads();
    }
#pragma unroll
    for (unsigned rt = 0; rt < 4; ++rt)
#pragma unroll
        for (unsigned c16 = 0; c16 < 2; ++c16) {
            unsigned rh = rt >> 1, fi = (rt & 1u) * 2u + c16;
            size_t off = ((((size_t)t * 2u + rh) * 32u + ct32) * 4u + fi) * 256u + lane * 4u;
            *(f32x4*)&preO[off] = acc[rt][c16];
        }
}

// ---------------- persistent 3-group pipeline ----------------
__global__ __launch_bounds__(512, 1) void rnn_persist(
    const float* __restrict__ bi, const float* __restrict__ bh,
    const unsigned short* __restrict__ WF,
    unsigned short* __restrict__ h1F, unsigned short* __restrict__ h2F,
    float* __restrict__ pre2F, unsigned* __restrict__ cnt,
    float* __restrict__ seqO, float* __restrict__ hsO)
{
    __shared__ short WlS[65536];                 // 128 KiB weights (hi+lo, 32 cols)
    __shared__ float redS[2 * 2 * 2 * 64 * 4];   // 8 KiB reduction
    __shared__ float epS[32 * 36];               // 4.5 KiB epilogue transpose

    const unsigned wg  = blockIdx.x;
    const unsigned grp = wg >> 6;                // 0,1,2
    const unsigned sub = wg & 63u;
    const unsigned rh  = sub >> 5, ct = sub & 31u;
    const unsigned tid = threadIdx.x;
    const unsigned w   = tid >> 6, lane = tid & 63u;
    const unsigned kw  = w >> 1, cw = w & 1u;

    const unsigned mat = grp + 1u;               // G0:Wh1, G1:Wi2, G2:Wh2
#pragma unroll
    for (unsigned prec = 0; prec < 2; ++prec)
#pragma unroll
        for (unsigned c16l = 0; c16l < 2; ++c16l) {
            const unsigned short* sp = WF + (((size_t)(mat * 2u + prec) * 64u + (ct * 2u + c16l)) * 32u) * 512u;
            short* dp = &WlS[(prec * 2u + c16l) * 16384u];
            for (unsigned o = tid * 8u; o < 16384u; o += 4096u)
                *(bf16x8*)&dp[o] = *(const bf16x8*)&sp[o];
        }

    float binit = 0.f;
    if (grp == 1u) {
        unsigned c = HCC + ct * 32u + cw * 16u + (lane & 15u);
        binit = bi[c] + bh[c];
    }

    const int s0 = (grp == 0u) ? 0 : (grp == 1u) ? 1 : 2;
    const int s1 = s0 + 511;

    for (int s = s0; s <= s1; ++s) {
        // ---- dependency waits (relaxed polls only; data uses coherent loads) ----
        if (tid == 0u) {
            const unsigned* pa = nullptr;   // anti-dep / secondary
            const unsigned* pm = nullptr;   // main dep
            if (grp == 0u) {
                if (s >= 4) pa = cnt + cidx(s - 3, 1u);
                if (s >= 1) pm = cnt + cidx(s - 1, 0u);
            } else if (grp == 1u) {
                if (s >= 5) pa = cnt + cidx(s - 3, 2u);
                pm = cnt + cidx(s - 1, 0u);
            } else {
                if (s >= 3) pa = cnt + cidx(s - 1, 2u);
                pm = cnt + cidx(s - 1, 1u);
            }
            if (pa)
                while (__hip_atomic_load(pa, __ATOMIC_RELAXED, __HIP_MEMORY_SCOPE_AGENT) < 64u)
                    __builtin_amdgcn_s_sleep(1);
            if (pm)
                while (__hip_atomic_load(pm, __ATOMIC_RELAXED, __HIP_MEMORY_SCOPE_AGENT) < 64u)
                    __builtin_amdgcn_s_sleep(1);
        }
        __syncthreads();

        // ---- acc init ----
        f32x4 acc0 = (f32x4){0.f, 0.f, 0.f, 0.f};
        f32x4 acc1 = (f32x4){0.f, 0.f, 0.f, 0.f};
        if (kw == 0u) {
            if (grp == 0u) {
                const float* pp = seqO + (((size_t)s * 2u + rh) * 32u + ct) * 1024u;
                acc0 = *(const f32x4*)&pp[(0u * 2u + cw) * 256u + lane * 4u];
                acc1 = *(const f32x4*)&pp[(1u * 2u + cw) * 256u + lane * 4u];
            } else if (grp == 1u) {
                acc0 = (f32x4){binit, binit, binit, binit};
                acc1 = acc0;
            } else {
                const float* pp = pre2F + (size_t)((s - 2) & 3) * PRE2_FLOATS
                                + ((size_t)rh * 32u + ct) * 1024u;
                gload_f128_cc(acc0, &pp[(0u * 2u + cw) * 256u + lane * 4u]);
                gload_f128_cc(acc1, &pp[(1u * 2u + cw) * 256u + lane * 4u]);
            }
        }
        const bool do_h = (grp == 0u) ? (s > 0) : (grp == 1u) ? true : (s > 2);
        bf16x8 Ah0[8], Ah1[8], Al0[8], Al1[8];
        if (do_h) {
            const unsigned aslot = (grp == 2u) ? ((unsigned)(s - 3) & 3u)
                                               : ((unsigned)(s - 1) & 3u);
            const unsigned short* Aslab = (grp <= 1u ? h1F : h2F)
                                        + (size_t)aslot * SLAB_SHORTS;
            const unsigned a00 = ((rh * 2u + 0u) * 2u + 0u) * 16384u;
            const unsigned a01 = ((rh * 2u + 0u) * 2u + 1u) * 16384u;
            const unsigned a10 = ((rh * 2u + 1u) * 2u + 0u) * 16384u;
            const unsigned a11 = ((rh * 2u + 1u) * 2u + 1u) * 16384u;
#pragma unroll
            for (unsigned i = 0; i < 8; ++i) {
                const unsigned ao = (kw * 8u + i) * 512u + lane * 8u;
                gload_b128_cc(Ah0[i], Aslab + a00 + ao);
                gload_b128_cc(Ah1[i], Aslab + a01 + ao);
                gload_b128_cc(Al0[i], Aslab + a10 + ao);
                gload_b128_cc(Al1[i], Aslab + a11 + ao);
            }
        }
        vm_drain();
        __builtin_amdgcn_sched_barrier(0);
        if (do_h) {
            const unsigned bh_ = (0u * 2u + cw) * 16384u;
            const unsigned bl_ = (1u * 2u + cw) * 16384u;
#pragma unroll
            for (unsigned i = 0; i < 8; ++i) {
                const unsigned ao = (kw * 8u + i) * 512u + lane * 8u;
                bf16x8 bbh = *(const bf16x8*)&WlS[bh_ + ao];
                bf16x8 bbl = *(const bf16x8*)&WlS[bl_ + ao];
                acc0 = __builtin_amdgcn_mfma_f32_16x16x32_bf16(Ah0[i], bbh, acc0, 0, 0, 0);
                acc1 = __builtin_amdgcn_mfma_f32_16x16x32_bf16(Ah1[i], bbh, acc1, 0, 0, 0);
                acc0 = __builtin_amdgcn_mfma_f32_16x16x32_bf16(Al0[i], bbh, acc0, 0, 0, 0);
                acc1 = __builtin_amdgcn_mfma_f32_16x16x32_bf16(Al1[i], bbh, acc1, 0, 0, 0);
                acc0 = __builtin_amdgcn_mfma_f32_16x16x32_bf16(Ah0[i], bbl, acc0, 0, 0, 0);
                acc1 = __builtin_amdgcn_mfma_f32_16x16x32_bf16(Ah1[i], bbl, acc1, 0, 0, 0);
            }
        }
        // ---- reduce over kw (4-way) per cw ----
#define REDP(buf, r16) (&redS[(((cw * 2u + (buf)) * 2u + (r16)) * 64u + lane) * 4u])
        if (kw >= 2u) { *(f32x4*)REDP(kw - 2u, 0u) = acc0; *(f32x4*)REDP(kw - 2u, 1u) = acc1; }
        __syncthreads();
        if (kw < 2u) { acc0 += *(const f32x4*)REDP(kw, 0u); acc1 += *(const f32x4*)REDP(kw, 1u); }
        __syncthreads();
        if (kw == 1u) { *(f32x4*)REDP(0u, 0u) = acc0; *(f32x4*)REDP(0u, 1u) = acc1; }
        __syncthreads();
        if (kw == 0u) {
            acc0 += *(const f32x4*)REDP(0u, 0u);
            acc1 += *(const f32x4*)REDP(0u, 1u);
            if (grp == 1u) {
                float* pp = pre2F + (size_t)((s - 1) & 3) * PRE2_FLOATS
                          + ((size_t)rh * 32u + ct) * 1024u;
                gstore_f128_cc(acc0, &pp[(0u * 2u + cw) * 256u + lane * 4u]);
                gstore_f128_cc(acc1, &pp[(1u * 2u + cw) * 256u + lane * 4u]);
            } else {
#pragma unroll
                for (unsigned r16 = 0; r16 < 2; ++r16) {
                    f32x4 a = r16 ? acc1 : acc0;
#pragma unroll
                    for (unsigned rr = 0; rr < 4; ++rr) {
                        float v = tanh_fast(a[rr]);
                        epS[(r16 * 16u + (lane >> 4) * 4u + rr) * 36u + cw * 16u + (lane & 15u)] = v;
                    }
                }
            }
        }
#undef REDP
        if (grp != 1u) {
            __syncthreads();   // epS ready
            // coalesced coherent h-slab store (hi+lo), waves 0..3
            if (w < 4u) {
                const unsigned r16l = w >> 1, prec = w & 1u;
                const unsigned row = r16l * 16u + (lane & 15u);
                const unsigned c0 = (lane >> 4) * 8u;
                float f[8];
                *(f32x4*)&f[0] = *(const f32x4*)&epS[row * 36u + c0];
                *(f32x4*)&f[4] = *(const f32x4*)&epS[row * 36u + c0 + 4u];
                bf16x8 H, L; split8(f, H, L);
                unsigned short* hdst = (grp == 0u ? h1F : h2F)
                    + (size_t)((grp == 0u ? s : s - 2) & 3) * SLAB_SHORTS;
                gstore_b128_cc(prec ? L : H,
                    hdst + ((rh * 2u + prec) * 2u + r16l) * 16384u + ct * 512u + lane * 8u);
            }
            // coalesced fp32 outputs from epS
            if (grp == 2u) {
                const int t2 = s - 2;
#pragma unroll
                for (unsigned pass = 0; pass < 2; ++pass) {
                    const unsigned r = w * 4u + pass * 2u + (lane >> 5);
                    const unsigned c = lane & 31u;
                    const float v = epS[r * 36u + c];
                    seqO[((size_t)t2 * 64u + rh * 32u + r) * 1024u + ct * 32u + c] = v;
                    if (s == 513) hsO[BH + (size_t)(rh * 32u + r) * 1024u + ct * 32u + c] = v;
                }
            }
            if (grp == 0u && s == 511) {
#pragma unroll
                for (unsigned pass = 0; pass < 2; ++pass) {
                    const unsigned r = w * 4u + pass * 2u + (lane >> 5);
                    const unsigned c = lane & 31u;
                    hsO[(size_t)(rh * 32u + r) * 1024u + ct * 32u + c] = epS[r * 36u + c];
                }
            }
        }
        // ---- drain write-through stores, then relaxed signal ----
        vm_drain();
        __syncthreads();
        if (tid == 0u)
            __hip_atomic_fetch_add(cnt + cidx(s, grp), 1u,
                                   __ATOMIC_RELAXED, __HIP_MEMORY_SCOPE_AGENT);
    }
}

extern "C" void kernel_launch(void* const* d_in, const int* in_sizes, int n_in,
                              void* d_out, int out_size, void* d_ws, size_t ws_size,
                              hipStream_t stream) {
    const float* x  = (const float*)d_in[0];
    const float* Wi = (const float*)d_in[1];
    const float* bi = (const float*)d_in[2];
    const float* Wh = (const float*)d_in[3];
    const float* bh = (const float*)d_in[4];

    float* seqO = (float*)d_out;
    float* hsO  = seqO + (size_t)T_STEPS * BH;

    unsigned short* wsS = (unsigned short*)d_ws;
    unsigned short* WF  = wsS;
    unsigned short* h1F = wsS + OFF_H1F;
    unsigned short* h2F = wsS + OFF_H2F;
    float* pre2F = (float*)((char*)d_ws + OFF_PRE2_BYTES);
    unsigned* cnt = (unsigned*)((char*)d_ws + CNT_BYTE_OFF);

    zero_cnt_kernel<<<(CNT_UINTS + 255u) / 256u, 256, 0, stream>>>(cnt, CNT_UINTS);
    wsplit_kernel<<<2048, 256, 0, stream>>>(Wi, Wh, WF);
    pre1_gemm<<<4096, 256, 0, stream>>>(x, bi, bh, WF, seqO);
    rnn_persist<<<NWG, 512, 0, stream>>>(bi, bh, WF, h1F, h2F, pre2F, cnt, seqO, hsO);
}

// Round 7
// 3215.728 us; speedup vs baseline: 6.6036x; 1.4339x over previous
//
#include <hip/hip_runtime.h>

// 2-layer tanh RNN, T=512, B=64, IC=HC=1024, fp32 in/out.
// pre1 = x*Wi1+b precomputed (parallel MFMA GEMM, frag-major into d_out).
// Persistent kernel, 3 groups of 64 WGs. Cross-WG data: sc0/sc1 write-through
// stores + sc0/sc1 coherent loads. Sync: per-WG monotonic flag (plain relaxed
// store of s+1), consumers poll lane-parallel (lane i watches producer i).
//   G0 (wg 0..63):    h1[s]   = tanh(pre1[s] + h1[s-1]*Wh1^T)        s=0..511
//   G1 (wg 64..127):  pre2[s-1] = h1[s-1]*Wi2^T + b2                 s=1..512
//   G2 (wg 128..191): h2[s-2] = tanh(pre2[s-2] + h2[s-3]*Wh2^T)      s=2..513
// Split-bf16 (hi+lo, drop lo*lo) MFMA 16x16x32, fp32 accumulate.
// Rings 4-deep; G2 reads h2[s-3] -> slot (s-3)&3.

#define T_STEPS 512
#define HCC     1024
#define BH      65536
#define NWG     192

typedef __attribute__((ext_vector_type(8))) short  bf16x8;
typedef __attribute__((ext_vector_type(4))) float  f32x4;

// ws layout
#define WF_SHORTS   8388608u                 /* 16 MiB frag-major split weights */
#define SLAB_SHORTS 131072u                  /* one h slab: 256 KiB */
#define OFF_H1F     WF_SHORTS
#define OFF_H2F     (OFF_H1F + 4u*SLAB_SHORTS)
#define OFF_PRE2_BYTES ((size_t)(OFF_H2F + 4u*SLAB_SHORTS) * 2u)   /* 18,874,368 */
#define PRE2_FLOATS 65536u                   /* one pre2 slot: 256 KiB */
#define FLG_BYTE_OFF (OFF_PRE2_BYTES + 4u*(size_t)PRE2_FLOATS*4u)  /* 19,922,944 */
#define FLG_UINTS   (3u*64u*4u)              /* 16B-strided flags */

__device__ __forceinline__ unsigned fidx(unsigned g, unsigned i) {
    return (g * 64u + i) * 4u;
}

// ---- raw 16B loads/stores (all VMEM ordering handled manually) ----
__device__ __forceinline__ void gload_b128_cc(bf16x8& d, const unsigned short* p) {
    asm volatile("global_load_dwordx4 %0, %1, off sc0 sc1" : "=v"(d) : "v"(p));
}
__device__ __forceinline__ void gload_f128_cc(f32x4& d, const float* p) {
    asm volatile("global_load_dwordx4 %0, %1, off sc0 sc1" : "=v"(d) : "v"(p));
}
__device__ __forceinline__ void gload_f128_nc(f32x4& d, const float* p) {
    asm volatile("global_load_dwordx4 %0, %1, off" : "=v"(d) : "v"(p));
}
__device__ __forceinline__ void gstore_b128_cc(bf16x8 v, unsigned short* p) {
    asm volatile("global_store_dwordx4 %0, %1, off sc0 sc1" :: "v"(p), "v"(v) : "memory");
}
__device__ __forceinline__ void gstore_f128_cc(f32x4 v, float* p) {
    asm volatile("global_store_dwordx4 %0, %1, off sc0 sc1" :: "v"(p), "v"(v) : "memory");
}
__device__ __forceinline__ void vm_drain() {
    asm volatile("s_waitcnt vmcnt(0)" ::: "memory");
}
__device__ __forceinline__ void vm_wait16() {
    asm volatile("s_waitcnt vmcnt(16)" ::: "memory");
}

__device__ __forceinline__ unsigned short bf16_rne_bits(float f) {
    unsigned u = __builtin_bit_cast(unsigned, f);
    unsigned r = u + 0x7fffu + ((u >> 16) & 1u);
    return (unsigned short)(r >> 16);
}
__device__ __forceinline__ void split1(float f, unsigned short& hi, unsigned short& lo) {
    unsigned u = __builtin_bit_cast(unsigned, f);
    unsigned r = (u + 0x7fffu + ((u >> 16) & 1u)) & 0xffff0000u;
    hi = (unsigned short)(r >> 16);
    float res = f - __builtin_bit_cast(float, r);
    lo = bf16_rne_bits(res);
}
__device__ __forceinline__ void split8(const float* f, bf16x8& H, bf16x8& L) {
#pragma unroll
    for (int e = 0; e < 8; ++e) {
        unsigned short hi, lo; split1(f[e], hi, lo);
        H[e] = (short)hi; L[e] = (short)lo;
    }
}
__device__ __forceinline__ float tanh_fast(float v) {
    float e = __expf(2.0f * v);
    return 1.0f - 2.0f * __builtin_amdgcn_rcpf(e + 1.0f);
}

__global__ __launch_bounds__(256) void zero_cnt_kernel(unsigned* cnt, unsigned n) {
    unsigned i = blockIdx.x * 256u + threadIdx.x;
    if (i < n) cnt[i] = 0u;
}

// ---------------- weight split to fragment-major ----------------
// WF[mat][prec][c16][ks][lane*8+e]; mat: 0=Wi1 1=Wh1 2=Wi2 3=Wh2
__global__ __launch_bounds__(256) void wsplit_kernel(
    const float* __restrict__ Wi, const float* __restrict__ Wh,
    unsigned short* __restrict__ WF)
{
    unsigned id  = blockIdx.x * 256u + threadIdx.x;   // < 524288
    unsigned kc  = id & 127u;
    unsigned row = (id >> 7) & 1023u;
    unsigned m   = id >> 17;                           // 0..3

    const float* src = ((m & 1u) ? Wh : Wi) + (size_t)(m >> 1) * HCC * HCC
                     + (size_t)row * HCC + kc * 8u;
    float f[8];
    *(f32x4*)&f[0] = *(const f32x4*)&src[0];
    *(f32x4*)&f[4] = *(const f32x4*)&src[4];
    bf16x8 H, L; split8(f, H, L);

    unsigned c16 = row >> 4, ks = kc >> 2;
    unsigned lane = (row & 15u) + 16u * (kc & 3u);
    size_t bh_ = (((size_t)(m * 2u + 0u) * 64u + c16) * 32u + ks) * 512u + lane * 8u;
    size_t bl_ = (((size_t)(m * 2u + 1u) * 64u + c16) * 32u + ks) * 512u + lane * 8u;
    *(bf16x8*)&WF[bh_] = H;
    *(bf16x8*)&WF[bl_] = L;
}

// ---------------- pre1 = x*Wi1^T + (bi1+bh1), frag-major into d_out ----------------
__global__ __launch_bounds__(256) void pre1_gemm(
    const float* __restrict__ x, const float* __restrict__ bi, const float* __restrict__ bh,
    const unsigned short* __restrict__ WF, float* __restrict__ preO)
{
    __shared__ float xs[64 * 36];
    const unsigned t = blockIdx.x >> 3, cg = blockIdx.x & 7u;
    const unsigned tid = threadIdx.x, w = tid >> 6, lane = tid & 63u;
    const unsigned ct32 = cg * 4u + w;

    float b0 = bi[ct32 * 32u + (lane & 15u)]        + bh[ct32 * 32u + (lane & 15u)];
    float b1 = bi[ct32 * 32u + 16u + (lane & 15u)]  + bh[ct32 * 32u + 16u + (lane & 15u)];
    f32x4 acc[4][2];
#pragma unroll
    for (unsigned rt = 0; rt < 4; ++rt) {
        acc[rt][0] = (f32x4){b0, b0, b0, b0};
        acc[rt][1] = (f32x4){b1, b1, b1, b1};
    }
    const float* xt = x + (size_t)t * BH;

    for (unsigned ks = 0; ks < 32; ++ks) {
        {
            unsigned row = tid >> 2, c8 = (tid & 3u) * 8u;
            const float* sp = xt + (size_t)row * HCC + ks * 32u + c8;
            *(f32x4*)&xs[row * 36u + c8]      = *(const f32x4*)&sp[0];
            *(f32x4*)&xs[row * 36u + c8 + 4u] = *(const f32x4*)&sp[4];
        }
        __syncthreads();
        bf16x8 bhv[2], blv[2];
#pragma unroll
        for (unsigned c16 = 0; c16 < 2; ++c16) {
            size_t base = (((size_t)(0u) * 64u + (ct32 * 2u + c16)) * 32u + ks) * 512u + lane * 8u;
            bhv[c16] = *(const bf16x8*)&WF[base];
            blv[c16] = *(const bf16x8*)&WF[base + (size_t)64u * 32u * 512u];
        }
#pragma unroll
        for (unsigned rt = 0; rt < 4; ++rt) {
            unsigned row = rt * 16u + (lane & 15u);
            unsigned k0 = (lane >> 4) * 8u;
            float f[8];
            *(f32x4*)&f[0] = *(const f32x4*)&xs[row * 36u + k0];
            *(f32x4*)&f[4] = *(const f32x4*)&xs[row * 36u + k0 + 4u];
            bf16x8 ah, al; split8(f, ah, al);
#pragma unroll
            for (unsigned c16 = 0; c16 < 2; ++c16) {
                acc[rt][c16] = __builtin_amdgcn_mfma_f32_16x16x32_bf16(ah, bhv[c16], acc[rt][c16], 0, 0, 0);
                acc[rt][c16] = __builtin_amdgcn_mfma_f32_16x16x32_bf16(al, bhv[c16], acc[rt][c16], 0, 0, 0);
                acc[rt][c16] = __builtin_amdgcn_mfma_f32_16x16x32_bf16(ah, blv[c16], acc[rt][c16], 0, 0, 0);
            }
        }
        __syncthreads();
    }
#pragma unroll
    for (unsigned rt = 0; rt < 4; ++rt)
#pragma unroll
        for (unsigned c16 = 0; c16 < 2; ++c16) {
            unsigned rh = rt >> 1, fi = (rt & 1u) * 2u + c16;
            size_t off = ((((size_t)t * 2u + rh) * 32u + ct32) * 4u + fi) * 256u + lane * 4u;
            *(f32x4*)&preO[off] = acc[rt][c16];
        }
}

// ---------------- persistent 3-group pipeline ----------------
__global__ __launch_bounds__(512, 1) void rnn_persist(
    const float* __restrict__ bi, const float* __restrict__ bh,
    const unsigned short* __restrict__ WF,
    unsigned short* __restrict__ h1F, unsigned short* __restrict__ h2F,
    float* __restrict__ pre2F, unsigned* __restrict__ flg,
    float* __restrict__ seqO, float* __restrict__ hsO)
{
    __shared__ short WlS[65536];                 // 128 KiB weights (hi+lo, 32 cols)
    __shared__ float redS[3 * 2 * 2 * 64 * 4];   // 12 KiB single-phase reduction
    __shared__ float epS[32 * 36];               // 4.5 KiB epilogue transpose

    const unsigned wg  = blockIdx.x;
    const unsigned grp = wg >> 6;                // 0,1,2
    const unsigned sub = wg & 63u;
    const unsigned rh  = sub >> 5, ct = sub & 31u;
    const unsigned tid = threadIdx.x;
    const unsigned w   = tid >> 6, lane = tid & 63u;
    const unsigned kw  = w >> 1, cw = w & 1u;

    const unsigned mat = grp + 1u;               // G0:Wh1, G1:Wi2, G2:Wh2
#pragma unroll
    for (unsigned prec = 0; prec < 2; ++prec)
#pragma unroll
        for (unsigned c16l = 0; c16l < 2; ++c16l) {
            const unsigned short* sp = WF + (((size_t)(mat * 2u + prec) * 64u + (ct * 2u + c16l)) * 32u) * 512u;
            short* dp = &WlS[(prec * 2u + c16l) * 16384u];
            for (unsigned o = tid * 8u; o < 16384u; o += 4096u)
                *(bf16x8*)&dp[o] = *(const bf16x8*)&sp[o];
        }

    float binit = 0.f;
    if (grp == 1u) {
        unsigned c = HCC + ct * 32u + cw * 16u + (lane & 15u);
        binit = bi[c] + bh[c];
    }

    const int s0 = (grp == 0u) ? 0 : (grp == 1u) ? 1 : 2;
    const int s1 = s0 + 511;

    for (int s = s0; s <= s1; ++s) {
        // ---- dependency waits: lane-parallel flag polls ----
        bool needA, needB; unsigned srcA = 0u, srcB = 0u, tA = 0u, tB = 0u;
        if (grp == 0u) {
            needA = (s >= 1); srcA = 0u; tA = (unsigned)s;
            needB = (s >= 4); srcB = 1u; tB = (unsigned)(s - 2);
        } else if (grp == 1u) {
            needA = true;     srcA = 0u; tA = (unsigned)s;
            needB = (s >= 5); srcB = 2u; tB = (unsigned)(s - 2);
        } else {
            needA = true;     srcA = 1u; tA = (unsigned)s;
            needB = (s >= 3); srcB = 2u; tB = (unsigned)s;
        }
        if (w == 0u && needA) {
            const unsigned* fp = flg + fidx(srcA, lane);
            while (!__all((int)(__hip_atomic_load(fp, __ATOMIC_RELAXED, __HIP_MEMORY_SCOPE_AGENT) >= tA)))
                __builtin_amdgcn_s_sleep(1);
        }
        if (w == 1u && needB) {
            const unsigned* fp = flg + fidx(srcB, lane);
            while (!__all((int)(__hip_atomic_load(fp, __ATOMIC_RELAXED, __HIP_MEMORY_SCOPE_AGENT) >= tB)))
                __builtin_amdgcn_s_sleep(1);
        }
        __syncthreads();

        // ---- acc init (all loads via inline asm; ordering manual) ----
        f32x4 acc0 = (f32x4){0.f, 0.f, 0.f, 0.f};
        f32x4 acc1 = (f32x4){0.f, 0.f, 0.f, 0.f};
        if (kw == 0u) {
            if (grp == 0u) {
                const float* pp = seqO + (((size_t)s * 2u + rh) * 32u + ct) * 1024u;
                gload_f128_nc(acc0, &pp[(0u * 2u + cw) * 256u + lane * 4u]);
                gload_f128_nc(acc1, &pp[(1u * 2u + cw) * 256u + lane * 4u]);
            } else if (grp == 1u) {
                acc0 = (f32x4){binit, binit, binit, binit};
                acc1 = acc0;
            } else {
                const float* pp = pre2F + (size_t)((s - 2) & 3) * PRE2_FLOATS
                                + ((size_t)rh * 32u + ct) * 1024u;
                gload_f128_cc(acc0, &pp[(0u * 2u + cw) * 256u + lane * 4u]);
                gload_f128_cc(acc1, &pp[(1u * 2u + cw) * 256u + lane * 4u]);
            }
        }
        const bool do_h = (grp == 0u) ? (s > 0) : (grp == 1u) ? true : (s > 2);
        if (do_h) {
            const unsigned aslot = (grp == 2u) ? ((unsigned)(s - 3) & 3u)
                                               : ((unsigned)(s - 1) & 3u);
            const unsigned short* Aslab = (grp <= 1u ? h1F : h2F)
                                        + (size_t)aslot * SLAB_SHORTS;
            const unsigned a00 = ((rh * 2u + 0u) * 2u + 0u) * 16384u;
            const unsigned a01 = ((rh * 2u + 0u) * 2u + 1u) * 16384u;
            const unsigned a10 = ((rh * 2u + 1u) * 2u + 0u) * 16384u;
            const unsigned a11 = ((rh * 2u + 1u) * 2u + 1u) * 16384u;
            bf16x8 Ah0[8], Ah1[8], Al0[8], Al1[8];
            // issue order: hi rows first, lo rows second
#pragma unroll
            for (unsigned i = 0; i < 8; ++i) {
                const unsigned ao = (kw * 8u + i) * 512u + lane * 8u;
                gload_b128_cc(Ah0[i], Aslab + a00 + ao);
                gload_b128_cc(Ah1[i], Aslab + a01 + ao);
            }
#pragma unroll
            for (unsigned i = 0; i < 8; ++i) {
                const unsigned ao = (kw * 8u + i) * 512u + lane * 8u;
                gload_b128_cc(Al0[i], Aslab + a10 + ao);
                gload_b128_cc(Al1[i], Aslab + a11 + ao);
            }
            const unsigned bh_ = (0u * 2u + cw) * 16384u;
            const unsigned bl_ = (1u * 2u + cw) * 16384u;
            // phase 1: Ah terms while Al block still streams (16 outstanding)
            vm_wait16();
            __builtin_amdgcn_sched_barrier(0);
#pragma unroll
            for (unsigned i = 0; i < 8; ++i) {
                const unsigned ao = (kw * 8u + i) * 512u + lane * 8u;
                bf16x8 bbh = *(const bf16x8*)&WlS[bh_ + ao];
                bf16x8 bbl = *(const bf16x8*)&WlS[bl_ + ao];
                acc0 = __builtin_amdgcn_mfma_f32_16x16x32_bf16(Ah0[i], bbh, acc0, 0, 0, 0);
                acc1 = __builtin_amdgcn_mfma_f32_16x16x32_bf16(Ah1[i], bbh, acc1, 0, 0, 0);
                acc0 = __builtin_amdgcn_mfma_f32_16x16x32_bf16(Ah0[i], bbl, acc0, 0, 0, 0);
                acc1 = __builtin_amdgcn_mfma_f32_16x16x32_bf16(Ah1[i], bbl, acc1, 0, 0, 0);
            }
            // phase 2: Al terms after full drain
            vm_drain();
            __builtin_amdgcn_sched_barrier(0);
#pragma unroll
            for (unsigned i = 0; i < 8; ++i) {
                const unsigned ao = (kw * 8u + i) * 512u + lane * 8u;
                bf16x8 bbh = *(const bf16x8*)&WlS[bh_ + ao];
                acc0 = __builtin_amdgcn_mfma_f32_16x16x32_bf16(Al0[i], bbh, acc0, 0, 0, 0);
                acc1 = __builtin_amdgcn_mfma_f32_16x16x32_bf16(Al1[i], bbh, acc1, 0, 0, 0);
            }
        } else {
            vm_drain();
            __builtin_amdgcn_sched_barrier(0);
        }
        // ---- single-barrier 4-way kw reduction ----
#define REDQ(buf, r16) (&redS[((((buf) * 2u + (r16)) * 2u + cw) * 64u + lane) * 4u])
        if (kw >= 1u) { *(f32x4*)REDQ(kw - 1u, 0u) = acc0; *(f32x4*)REDQ(kw - 1u, 1u) = acc1; }
        __syncthreads();
        if (kw == 0u) {
            acc0 += *(const f32x4*)REDQ(0u, 0u); acc1 += *(const f32x4*)REDQ(0u, 1u);
            acc0 += *(const f32x4*)REDQ(1u, 0u); acc1 += *(const f32x4*)REDQ(1u, 1u);
            acc0 += *(const f32x4*)REDQ(2u, 0u); acc1 += *(const f32x4*)REDQ(2u, 1u);
            if (grp == 1u) {
                float* pp = pre2F + (size_t)((s - 1) & 3) * PRE2_FLOATS
                          + ((size_t)rh * 32u + ct) * 1024u;
                gstore_f128_cc(acc0, &pp[(0u * 2u + cw) * 256u + lane * 4u]);
                gstore_f128_cc(acc1, &pp[(1u * 2u + cw) * 256u + lane * 4u]);
            } else {
#pragma unroll
                for (unsigned r16 = 0; r16 < 2; ++r16) {
                    f32x4 a = r16 ? acc1 : acc0;
#pragma unroll
                    for (unsigned rr = 0; rr < 4; ++rr) {
                        float v = tanh_fast(a[rr]);
                        epS[(r16 * 16u + (lane >> 4) * 4u + rr) * 36u + cw * 16u + (lane & 15u)] = v;
                    }
                }
            }
        }
#undef REDQ
        if (grp != 1u) {
            __syncthreads();   // epS ready
            // coalesced coherent h-slab store (hi+lo), waves 0..3
            if (w < 4u) {
                const unsigned r16l = w >> 1, prec = w & 1u;
                const unsigned row = r16l * 16u + (lane & 15u);
                const unsigned c0 = (lane >> 4) * 8u;
                float f[8];
                *(f32x4*)&f[0] = *(const f32x4*)&epS[row * 36u + c0];
                *(f32x4*)&f[4] = *(const f32x4*)&epS[row * 36u + c0 + 4u];
                bf16x8 H, L; split8(f, H, L);
                unsigned short* hdst = (grp == 0u ? h1F : h2F)
                    + (size_t)((grp == 0u ? s : s - 2) & 3) * SLAB_SHORTS;
                gstore_b128_cc(prec ? L : H,
                    hdst + ((rh * 2u + prec) * 2u + r16l) * 16384u + ct * 512u + lane * 8u);
            }
            // coalesced fp32 outputs from epS (normal cacheable stores)
            if (grp == 2u) {
                const int t2 = s - 2;
#pragma unroll
                for (unsigned pass = 0; pass < 2; ++pass) {
                    const unsigned r = w * 4u + pass * 2u + (lane >> 5);
                    const unsigned c = lane & 31u;
                    const float v = epS[r * 36u + c];
                    seqO[((size_t)t2 * 64u + rh * 32u + r) * 1024u + ct * 32u + c] = v;
                    if (s == 513) hsO[BH + (size_t)(rh * 32u + r) * 1024u + ct * 32u + c] = v;
                }
            }
            if (grp == 0u && s == 511) {
#pragma unroll
                for (unsigned pass = 0; pass < 2; ++pass) {
                    const unsigned r = w * 4u + pass * 2u + (lane >> 5);
                    const unsigned c = lane & 31u;
                    hsO[(size_t)(rh * 32u + r) * 1024u + ct * 32u + c] = epS[r * 36u + c];
                }
            }
        }
        // ---- drain stores, then plain flag store (no RMW) ----
        vm_drain();
        __syncthreads();
        if (tid == 0u)
            __hip_atomic_store(flg + fidx(grp, sub), (unsigned)s + 1u,
                               __ATOMIC_RELAXED, __HIP_MEMORY_SCOPE_AGENT);
    }
}

extern "C" void kernel_launch(void* const* d_in, const int* in_sizes, int n_in,
                              void* d_out, int out_size, void* d_ws, size_t ws_size,
                              hipStream_t stream) {
    const float* x  = (const float*)d_in[0];
    const float* Wi = (const float*)d_in[1];
    const float* bi = (const float*)d_in[2];
    const float* Wh = (const float*)d_in[3];
    const float* bh = (const float*)d_in[4];

    float* seqO = (float*)d_out;
    float* hsO  = seqO + (size_t)T_STEPS * BH;

    unsigned short* wsS = (unsigned short*)d_ws;
    unsigned short* WF  = wsS;
    unsigned short* h1F = wsS + OFF_H1F;
    unsigned short* h2F = wsS + OFF_H2F;
    float* pre2F = (float*)((char*)d_ws + OFF_PRE2_BYTES);
    unsigned* flg = (unsigned*)((char*)d_ws + FLG_BYTE_OFF);

    zero_cnt_kernel<<<(FLG_UINTS + 255u) / 256u, 256, 0, stream>>>(flg, FLG_UINTS);
    wsplit_kernel<<<2048, 256, 0, stream>>>(Wi, Wh, WF);
    pre1_gemm<<<4096, 256, 0, stream>>>(x, bi, bh, WF, seqO);
    rnn_persist<<<NWG, 512, 0, stream>>>(bi, bh, WF, h1F, h2F, pre2F, flg, seqO, hsO);
}

// Round 11
// 3144.952 us; speedup vs baseline: 6.7522x; 1.0225x over previous
//
#include <hip/hip_runtime.h>

// 2-layer tanh RNN, T=512, B=64, IC=HC=1024, fp32 in/out.
// pre1 = x*Wi1+b precomputed (parallel MFMA GEMM, frag-major into d_out).
// Persistent kernel, 3 groups of 64 WGs x 512 threads. ROUND-7 SYNC SKELETON
// (known good): w0/w1 lane-parallel polls + post-poll barrier; stage-end
// vm_drain + barrier + tid0 flag store. Rings 4-deep; G2 reads h2[s-3]
// at slot (s-3)&3. Cross-WG data via sc0/sc1 stores + sc0/sc1 loads.
// NEW vs round 7 (WG-local only):
//  - 8-way K-split (waves = K-eighths, no cw duplication): A pull 256->128 KB
//  - single-barrier 7-buffer reduction (redS 28 KB; epS aliases bufs 4-6)
//  - acc-init loads issued after A loads, consumed post-reduce (vmcnt 12/8/4)
//   G0 (wg 0..63):    h1[s]   = tanh(pre1[s] + h1[s-1]*Wh1^T)        s=0..511
//   G1 (wg 64..127):  pre2[s-1] = h1[s-1]*Wi2^T + b2                 s=1..512
//   G2 (wg 128..191): h2[s-2] = tanh(pre2[s-2] + h2[s-3]*Wh2^T)      s=2..513
// Split-bf16 (hi+lo, drop lo*lo) MFMA 16x16x32, fp32 accumulate.

#define T_STEPS 512
#define HCC     1024
#define BH      65536
#define NWG     192

typedef __attribute__((ext_vector_type(8))) short  bf16x8;
typedef __attribute__((ext_vector_type(4))) float  f32x4;

// ws layout (round 7): WF 16 MiB | h1F 4 slabs | h2F 4 slabs | pre2 4 slots | flags
#define WF_SHORTS   8388608u
#define SLAB_SHORTS 131072u
#define OFF_H1F     WF_SHORTS
#define OFF_H2F     (OFF_H1F + 4u*SLAB_SHORTS)
#define OFF_PRE2_BYTES ((size_t)(OFF_H2F + 4u*SLAB_SHORTS) * 2u)   /* 18,874,368 */
#define PRE2_FLOATS 65536u
#define FLG_BYTE_OFF (OFF_PRE2_BYTES + 4u*(size_t)PRE2_FLOATS*4u)  /* 19,922,944 */
#define FLG_UINTS   (3u*64u*4u)

__device__ __forceinline__ unsigned fidx(unsigned g, unsigned i) {
    return (g * 64u + i) * 4u;
}

// ---- raw 16B loads/stores; VMEM ordering handled manually ----
__device__ __forceinline__ void gload_b128_cc(bf16x8& d, const unsigned short* p) {
    asm volatile("global_load_dwordx4 %0, %1, off sc0 sc1" : "=v"(d) : "v"(p));
}
__device__ __forceinline__ void gload_f128_cc(f32x4& d, const float* p) {
    asm volatile("global_load_dwordx4 %0, %1, off sc0 sc1" : "=v"(d) : "v"(p));
}
__device__ __forceinline__ void gload_f128_nc(f32x4& d, const float* p) {
    asm volatile("global_load_dwordx4 %0, %1, off" : "=v"(d) : "v"(p));
}
__device__ __forceinline__ void gstore_b128_cc(bf16x8 v, unsigned short* p) {
    asm volatile("global_store_dwordx4 %0, %1, off sc0 sc1" :: "v"(p), "v"(v) : "memory");
}
__device__ __forceinline__ void gstore_f128_cc(f32x4 v, float* p) {
    asm volatile("global_store_dwordx4 %0, %1, off sc0 sc1" :: "v"(p), "v"(v) : "memory");
}
__device__ __forceinline__ void vm_drain()  { asm volatile("s_waitcnt vmcnt(0)"  ::: "memory"); }
__device__ __forceinline__ void vm_wait4()  { asm volatile("s_waitcnt vmcnt(4)"  ::: "memory"); }
__device__ __forceinline__ void vm_wait8()  { asm volatile("s_waitcnt vmcnt(8)"  ::: "memory"); }
__device__ __forceinline__ void vm_wait12() { asm volatile("s_waitcnt vmcnt(12)" ::: "memory"); }
#define SBAR() __builtin_amdgcn_sched_barrier(0)

__device__ __forceinline__ unsigned short bf16_rne_bits(float f) {
    unsigned u = __builtin_bit_cast(unsigned, f);
    unsigned r = u + 0x7fffu + ((u >> 16) & 1u);
    return (unsigned short)(r >> 16);
}
__device__ __forceinline__ void split1(float f, unsigned short& hi, unsigned short& lo) {
    unsigned u = __builtin_bit_cast(unsigned, f);
    unsigned r = (u + 0x7fffu + ((u >> 16) & 1u)) & 0xffff0000u;
    hi = (unsigned short)(r >> 16);
    float res = f - __builtin_bit_cast(float, r);
    lo = bf16_rne_bits(res);
}
__device__ __forceinline__ void split8(const float* f, bf16x8& H, bf16x8& L) {
#pragma unroll
    for (int e = 0; e < 8; ++e) {
        unsigned short hi, lo; split1(f[e], hi, lo);
        H[e] = (short)hi; L[e] = (short)lo;
    }
}
__device__ __forceinline__ float tanh_fast(float v) {
    float e = __expf(2.0f * v);
    return 1.0f - 2.0f * __builtin_amdgcn_rcpf(e + 1.0f);
}

__global__ __launch_bounds__(256) void zero_cnt_kernel(unsigned* cnt, unsigned n) {
    unsigned i = blockIdx.x * 256u + threadIdx.x;
    if (i < n) cnt[i] = 0u;
}

// ---------------- weight split to fragment-major (round 7 verbatim) ----------------
// WF[mat][prec][c16][ks][lane*8+e]; mat: 0=Wi1 1=Wh1 2=Wi2 3=Wh2
__global__ __launch_bounds__(256) void wsplit_kernel(
    const float* __restrict__ Wi, const float* __restrict__ Wh,
    unsigned short* __restrict__ WF)
{
    unsigned id  = blockIdx.x * 256u + threadIdx.x;   // < 524288
    unsigned kc  = id & 127u;
    unsigned row = (id >> 7) & 1023u;
    unsigned m   = id >> 17;                           // 0..3

    const float* src = ((m & 1u) ? Wh : Wi) + (size_t)(m >> 1) * HCC * HCC
                     + (size_t)row * HCC + kc * 8u;
    float f[8];
    *(f32x4*)&f[0] = *(const f32x4*)&src[0];
    *(f32x4*)&f[4] = *(const f32x4*)&src[4];
    bf16x8 H, L; split8(f, H, L);

    unsigned c16 = row >> 4, ks = kc >> 2;
    unsigned lane = (row & 15u) + 16u * (kc & 3u);
    size_t bh_ = (((size_t)(m * 2u + 0u) * 64u + c16) * 32u + ks) * 512u + lane * 8u;
    size_t bl_ = (((size_t)(m * 2u + 1u) * 64u + c16) * 32u + ks) * 512u + lane * 8u;
    *(bf16x8*)&WF[bh_] = H;
    *(bf16x8*)&WF[bl_] = L;
}

// ---------------- pre1 = x*Wi1^T + (bi1+bh1), frag-major into d_out (round 7) -------
__global__ __launch_bounds__(256) void pre1_gemm(
    const float* __restrict__ x, const float* __restrict__ bi, const float* __restrict__ bh,
    const unsigned short* __restrict__ WF, float* __restrict__ preO)
{
    __shared__ float xs[64 * 36];
    const unsigned t = blockIdx.x >> 3, cg = blockIdx.x & 7u;
    const unsigned tid = threadIdx.x, w = tid >> 6, lane = tid & 63u;
    const unsigned ct32 = cg * 4u + w;

    float b0 = bi[ct32 * 32u + (lane & 15u)]        + bh[ct32 * 32u + (lane & 15u)];
    float b1 = bi[ct32 * 32u + 16u + (lane & 15u)]  + bh[ct32 * 32u + 16u + (lane & 15u)];
    f32x4 acc[4][2];
#pragma unroll
    for (unsigned rt = 0; rt < 4; ++rt) {
        acc[rt][0] = (f32x4){b0, b0, b0, b0};
        acc[rt][1] = (f32x4){b1, b1, b1, b1};
    }
    const float* xt = x + (size_t)t * BH;

    for (unsigned ks = 0; ks < 32; ++ks) {
        {
            unsigned row = tid >> 2, c8 = (tid & 3u) * 8u;
            const float* sp = xt + (size_t)row * HCC + ks * 32u + c8;
            *(f32x4*)&xs[row * 36u + c8]      = *(const f32x4*)&sp[0];
            *(f32x4*)&xs[row * 36u + c8 + 4u] = *(const f32x4*)&sp[4];
        }
        __syncthreads();
        bf16x8 bhv[2], blv[2];
#pragma unroll
        for (unsigned c16 = 0; c16 < 2; ++c16) {
            size_t base = (((size_t)(0u) * 64u + (ct32 * 2u + c16)) * 32u + ks) * 512u + lane * 8u;
            bhv[c16] = *(const bf16x8*)&WF[base];
            blv[c16] = *(const bf16x8*)&WF[base + (size_t)64u * 32u * 512u];
        }
#pragma unroll
        for (unsigned rt = 0; rt < 4; ++rt) {
            unsigned row = rt * 16u + (lane & 15u);
            unsigned k0 = (lane >> 4) * 8u;
            float f[8];
            *(f32x4*)&f[0] = *(const f32x4*)&xs[row * 36u + k0];
            *(f32x4*)&f[4] = *(const f32x4*)&xs[row * 36u + k0 + 4u];
            bf16x8 ah, al; split8(f, ah, al);
#pragma unroll
            for (unsigned c16 = 0; c16 < 2; ++c16) {
                acc[rt][c16] = __builtin_amdgcn_mfma_f32_16x16x32_bf16(ah, bhv[c16], acc[rt][c16], 0, 0, 0);
                acc[rt][c16] = __builtin_amdgcn_mfma_f32_16x16x32_bf16(al, bhv[c16], acc[rt][c16], 0, 0, 0);
                acc[rt][c16] = __builtin_amdgcn_mfma_f32_16x16x32_bf16(ah, blv[c16], acc[rt][c16], 0, 0, 0);
            }
        }
        __syncthreads();
    }
#pragma unroll
    for (unsigned rt = 0; rt < 4; ++rt)
#pragma unroll
        for (unsigned c16 = 0; c16 < 2; ++c16) {
            unsigned rh = rt >> 1, fi = (rt & 1u) * 2u + c16;
            size_t off = ((((size_t)t * 2u + rh) * 32u + ct32) * 4u + fi) * 256u + lane * 4u;
            *(f32x4*)&preO[off] = acc[rt][c16];
        }
}

// ---------------- persistent 3-group pipeline ----------------
__global__ __launch_bounds__(512, 1) void rnn_persist(
    const float* __restrict__ bi, const float* __restrict__ bh,
    const unsigned short* __restrict__ WF,
    unsigned short* __restrict__ h1F, unsigned short* __restrict__ h2F,
    float* __restrict__ pre2F, unsigned* __restrict__ flg,
    float* __restrict__ seqO, float* __restrict__ hsO)
{
    __shared__ short WlS[65536];       // 128 KiB weights (hi+lo, 32 cols)
    __shared__ float redS[7168];       // 28 KiB: 7 bufs x [frag(4)][lane][4]
    float* const epS = &redS[4096];    // aliases bufs 4-6 (safe: data-dep ordered)

    const unsigned wg  = blockIdx.x;
    const unsigned grp = wg >> 6;                // 0,1,2
    const unsigned sub = wg & 63u;
    const unsigned rh  = sub >> 5, ct = sub & 31u;
    const unsigned tid = threadIdx.x;
    const unsigned w   = tid >> 6, lane = tid & 63u;  // w = K-eighth

    // persistent weight LDS (mat block = grp+1: Wh1/Wi2/Wh2)
    const unsigned mat = grp + 1u;
#pragma unroll
    for (unsigned prec = 0; prec < 2; ++prec)
#pragma unroll
        for (unsigned c16l = 0; c16l < 2; ++c16l) {
            const unsigned short* sp = WF + (((size_t)(mat * 2u + prec) * 64u + (ct * 2u + c16l)) * 32u) * 512u;
            short* dp = &WlS[(prec * 2u + c16l) * 16384u];
            for (unsigned o = tid * 8u; o < 16384u; o += 4096u)
                *(bf16x8*)&dp[o] = *(const bf16x8*)&sp[o];
        }
    // staged cross-wave; first post-poll __syncthreads below is the barrier

    float binit0 = 0.f, binit1 = 0.f;
    if (grp == 1u) {
        unsigned c = HCC + ct * 32u + (lane & 15u);
        binit0 = bi[c] + bh[c];
        binit1 = bi[c + 16u] + bh[c + 16u];
    }

    const int s0_ = (grp == 0u) ? 0 : (grp == 1u) ? 1 : 2;
    const int s1_ = s0_ + 511;

#define POLL(G, TGT) do {                                                             \
        const unsigned* fp_ = flg + fidx((G), lane);                                  \
        while (!__all((int)(__hip_atomic_load(fp_, __ATOMIC_RELAXED,                  \
                                              __HIP_MEMORY_SCOPE_AGENT) >= (unsigned)(TGT)))) \
            __builtin_amdgcn_s_sleep(1);                                              \
    } while (0)

    for (int s = s0_; s <= s1_; ++s) {
        // ---- dependency waits (round 7): w0 main, w1 anti, then barrier ----
        bool needA, needB; unsigned srcA = 0u, srcB = 0u, tA = 0u, tB = 0u;
        if (grp == 0u) {
            needA = (s >= 1); srcA = 0u; tA = (unsigned)s;
            needB = (s >= 4); srcB = 1u; tB = (unsigned)(s - 2);
        } else if (grp == 1u) {
            needA = true;     srcA = 0u; tA = (unsigned)s;
            needB = (s >= 5); srcB = 2u; tB = (unsigned)(s - 2);
        } else {
            needA = true;     srcA = 1u; tA = (unsigned)s;
            needB = (s >= 3); srcB = 2u; tB = (unsigned)s;
        }
        if (w == 0u && needA) POLL(srcA, tA);
        if (w == 1u && needB) POLL(srcB, tB);
        __syncthreads();

        const bool do_h   = (grp == 0u) ? (s > 0) : (grp == 1u) ? true : (s > 2);
        const bool has_ld = (w == 0u && grp != 1u);

        // ---- A loads: Ah (8), Al (8), then wave0 acc loads (newest) ----
        bf16x8 Ah0[4], Ah1[4], Al0[4], Al1[4];
        if (do_h) {
            const unsigned aslot = (grp == 2u) ? ((unsigned)(s - 3) & 3u)
                                               : ((unsigned)(s - 1) & 3u);
            const unsigned short* Aslab = (grp <= 1u ? h1F : h2F)
                                        + (size_t)aslot * SLAB_SHORTS;
            const unsigned b00 = ((rh * 2u + 0u) * 2u + 0u) * 16384u;
            const unsigned b01 = ((rh * 2u + 0u) * 2u + 1u) * 16384u;
            const unsigned b10 = ((rh * 2u + 1u) * 2u + 0u) * 16384u;
            const unsigned b11 = ((rh * 2u + 1u) * 2u + 1u) * 16384u;
#pragma unroll
            for (unsigned i = 0; i < 4; ++i) {
                const unsigned ao = (w * 4u + i) * 512u + lane * 8u;
                gload_b128_cc(Ah0[i], Aslab + b00 + ao);
                gload_b128_cc(Ah1[i], Aslab + b01 + ao);
            }
#pragma unroll
            for (unsigned i = 0; i < 4; ++i) {
                const unsigned ao = (w * 4u + i) * 512u + lane * 8u;
                gload_b128_cc(Al0[i], Aslab + b10 + ao);
                gload_b128_cc(Al1[i], Aslab + b11 + ao);
            }
        }
        f32x4 ld0 = {0,0,0,0}, ld1 = {0,0,0,0}, ld2 = {0,0,0,0}, ld3 = {0,0,0,0};
        if (has_ld) {
            if (grp == 0u) {
                const float* pp = seqO + (((size_t)s * 2u + rh) * 32u + ct) * 1024u;
                gload_f128_nc(ld0, pp + 0u * 256u + lane * 4u);
                gload_f128_nc(ld1, pp + 1u * 256u + lane * 4u);
                gload_f128_nc(ld2, pp + 2u * 256u + lane * 4u);
                gload_f128_nc(ld3, pp + 3u * 256u + lane * 4u);
            } else {
                const float* pp = pre2F + (size_t)((s - 2) & 3) * PRE2_FLOATS
                                + ((size_t)rh * 32u + ct) * 1024u;
                gload_f128_cc(ld0, pp + 0u * 256u + lane * 4u);
                gload_f128_cc(ld1, pp + 1u * 256u + lane * 4u);
                gload_f128_cc(ld2, pp + 2u * 256u + lane * 4u);
                gload_f128_cc(ld3, pp + 3u * 256u + lane * 4u);
            }
        }

        f32x4 a00 = {0,0,0,0}, a01 = {0,0,0,0}, a10 = {0,0,0,0}, a11 = {0,0,0,0};
        if (do_h) {
            // phase 1: Ah terms (oldest 8 loads) while Al (+acc) stream
            if (has_ld) vm_wait12(); else vm_wait8();
            SBAR();
#pragma unroll
            for (unsigned i = 0; i < 4; ++i) {
                const unsigned ao = (w * 4u + i) * 512u + lane * 8u;
                bf16x8 bh0 = *(const bf16x8*)&WlS[ao];
                bf16x8 bh1 = *(const bf16x8*)&WlS[16384u + ao];
                bf16x8 bl0 = *(const bf16x8*)&WlS[32768u + ao];
                bf16x8 bl1 = *(const bf16x8*)&WlS[49152u + ao];
                a00 = __builtin_amdgcn_mfma_f32_16x16x32_bf16(Ah0[i], bh0, a00, 0, 0, 0);
                a01 = __builtin_amdgcn_mfma_f32_16x16x32_bf16(Ah0[i], bh1, a01, 0, 0, 0);
                a10 = __builtin_amdgcn_mfma_f32_16x16x32_bf16(Ah1[i], bh0, a10, 0, 0, 0);
                a11 = __builtin_amdgcn_mfma_f32_16x16x32_bf16(Ah1[i], bh1, a11, 0, 0, 0);
                a00 = __builtin_amdgcn_mfma_f32_16x16x32_bf16(Ah0[i], bl0, a00, 0, 0, 0);
                a01 = __builtin_amdgcn_mfma_f32_16x16x32_bf16(Ah0[i], bl1, a01, 0, 0, 0);
                a10 = __builtin_amdgcn_mfma_f32_16x16x32_bf16(Ah1[i], bl0, a10, 0, 0, 0);
                a11 = __builtin_amdgcn_mfma_f32_16x16x32_bf16(Ah1[i], bl1, a11, 0, 0, 0);
            }
            // phase 2: Al x W_hi (acc loads may stay in flight on wave0)
            if (has_ld) vm_wait4(); else vm_drain();
            SBAR();
#pragma unroll
            for (unsigned i = 0; i < 4; ++i) {
                const unsigned ao = (w * 4u + i) * 512u + lane * 8u;
                bf16x8 bh0 = *(const bf16x8*)&WlS[ao];
                bf16x8 bh1 = *(const bf16x8*)&WlS[16384u + ao];
                a00 = __builtin_amdgcn_mfma_f32_16x16x32_bf16(Al0[i], bh0, a00, 0, 0, 0);
                a01 = __builtin_amdgcn_mfma_f32_16x16x32_bf16(Al0[i], bh1, a01, 0, 0, 0);
                a10 = __builtin_amdgcn_mfma_f32_16x16x32_bf16(Al1[i], bh0, a10, 0, 0, 0);
                a11 = __builtin_amdgcn_mfma_f32_16x16x32_bf16(Al1[i], bh1, a11, 0, 0, 0);
            }
        } else {
            vm_drain(); SBAR();
        }

        // ---- single-barrier 8-way reduction (7 buffers) ----
        if (w) {
            *(f32x4*)&redS[((w - 1u) * 4u + 0u) * 256u + lane * 4u] = a00;
            *(f32x4*)&redS[((w - 1u) * 4u + 1u) * 256u + lane * 4u] = a01;
            *(f32x4*)&redS[((w - 1u) * 4u + 2u) * 256u + lane * 4u] = a10;
            *(f32x4*)&redS[((w - 1u) * 4u + 3u) * 256u + lane * 4u] = a11;
        }
        __syncthreads();                                   // barrier 1
        if (w == 0u) {
#pragma unroll
            for (unsigned b = 0; b < 7; ++b) {
                a00 += *(const f32x4*)&redS[(b * 4u + 0u) * 256u + lane * 4u];
                a01 += *(const f32x4*)&redS[(b * 4u + 1u) * 256u + lane * 4u];
                a10 += *(const f32x4*)&redS[(b * 4u + 2u) * 256u + lane * 4u];
                a11 += *(const f32x4*)&redS[(b * 4u + 3u) * 256u + lane * 4u];
            }
            vm_drain(); SBAR();     // acc-init loads retired
            if (grp == 1u) {
                a00 += (f32x4){binit0, binit0, binit0, binit0};
                a01 += (f32x4){binit1, binit1, binit1, binit1};
                a10 += (f32x4){binit0, binit0, binit0, binit0};
                a11 += (f32x4){binit1, binit1, binit1, binit1};
                float* pp = pre2F + (size_t)((s - 1) & 3) * PRE2_FLOATS
                          + ((size_t)rh * 32u + ct) * 1024u;
                gstore_f128_cc(a00, pp + 0u * 256u + lane * 4u);
                gstore_f128_cc(a01, pp + 1u * 256u + lane * 4u);
                gstore_f128_cc(a10, pp + 2u * 256u + lane * 4u);
                gstore_f128_cc(a11, pp + 3u * 256u + lane * 4u);
            } else {
                a00 += ld0; a01 += ld1; a10 += ld2; a11 += ld3;
                // tanh -> epS [32 rows][36 cols] (depends on sums: ordered after redS reads)
#pragma unroll
                for (unsigned rr = 0; rr < 4; ++rr) {
                    unsigned rbase = ((lane >> 4) * 4u + rr) * 36u;
                    epS[rbase + (lane & 15u)]                 = tanh_fast(a00[rr]);
                    epS[rbase + 16u + (lane & 15u)]           = tanh_fast(a01[rr]);
                    epS[576u + rbase + (lane & 15u)]          = tanh_fast(a10[rr]);
                    epS[576u + rbase + 16u + (lane & 15u)]    = tanh_fast(a11[rr]);
                }
            }
        }
        if (grp != 1u) {
            __syncthreads();                               // barrier 2: epS ready
            // h-slab store (hi+lo) from epS, waves 0..3 (round 7 verbatim)
            if (w < 4u) {
                const unsigned r16l = w >> 1, prec = w & 1u;
                const unsigned row = r16l * 16u + (lane & 15u);
                const unsigned c0 = (lane >> 4) * 8u;
                float f[8];
                *(f32x4*)&f[0] = *(const f32x4*)&epS[row * 36u + c0];
                *(f32x4*)&f[4] = *(const f32x4*)&epS[row * 36u + c0 + 4u];
                bf16x8 H, L; split8(f, H, L);
                unsigned short* hdst = (grp == 0u ? h1F : h2F)
                    + (size_t)((unsigned)(grp == 0u ? s : s - 2) & 3u) * SLAB_SHORTS;
                gstore_b128_cc(prec ? L : H,
                    hdst + ((rh * 2u + prec) * 2u + r16l) * 16384u + ct * 512u + lane * 8u);
            }
            // coalesced fp32 outputs from epS (round 7 verbatim)
            if (grp == 2u) {
                const int t2 = s - 2;
#pragma unroll
                for (unsigned pass = 0; pass < 2; ++pass) {
                    const unsigned r = w * 4u + pass * 2u + (lane >> 5);
                    const unsigned c = lane & 31u;
                    const float v = epS[r * 36u + c];
                    seqO[((size_t)t2 * 64u + rh * 32u + r) * 1024u + ct * 32u + c] = v;
                    if (s == 513) hsO[BH + (size_t)(rh * 32u + r) * 1024u + ct * 32u + c] = v;
                }
            }
            if (grp == 0u && s == 511) {
#pragma unroll
                for (unsigned pass = 0; pass < 2; ++pass) {
                    const unsigned r = w * 4u + pass * 2u + (lane >> 5);
                    const unsigned c = lane & 31u;
                    hsO[(size_t)(rh * 32u + r) * 1024u + ct * 32u + c] = epS[r * 36u + c];
                }
            }
        }
        // ---- stage end (round 7 verbatim): drain stores, barrier, flag ----
        vm_drain();
        __syncthreads();
        if (tid == 0u)
            __hip_atomic_store(flg + fidx(grp, sub), (unsigned)s + 1u,
                               __ATOMIC_RELAXED, __HIP_MEMORY_SCOPE_AGENT);
    }
#undef POLL
}

extern "C" void kernel_launch(void* const* d_in, const int* in_sizes, int n_in,
                              void* d_out, int out_size, void* d_ws, size_t ws_size,
                              hipStream_t stream) {
    const float* x  = (const float*)d_in[0];
    const float* Wi = (const float*)d_in[1];
    const float* bi = (const float*)d_in[2];
    const float* Wh = (const float*)d_in[3];
    const float* bh = (const float*)d_in[4];

    float* seqO = (float*)d_out;
    float* hsO  = seqO + (size_t)T_STEPS * BH;

    unsigned short* wsS = (unsigned short*)d_ws;
    unsigned short* WF  = wsS;
    unsigned short* h1F = wsS + OFF_H1F;
    unsigned short* h2F = wsS + OFF_H2F;
    float* pre2F = (float*)((char*)d_ws + OFF_PRE2_BYTES);
    unsigned* flg = (unsigned*)((char*)d_ws + FLG_BYTE_OFF);

    zero_cnt_kernel<<<(FLG_UINTS + 255u) / 256u, 256, 0, stream>>>(flg, FLG_UINTS);
    wsplit_kernel<<<2048, 256, 0, stream>>>(Wi, Wh, WF);
    pre1_gemm<<<4096, 256, 0, stream>>>(x, bi, bh, WF, seqO);
    rnn_persist<<<NWG, 512, 0, stream>>>(bi, bh, WF, h1F, h2F, pre2F, flg, seqO, hsO);
}

// Round 12
// 2840.990 us; speedup vs baseline: 7.4747x; 1.1070x over previous
//
#include <hip/hip_runtime.h>

// 2-layer tanh RNN, T=512, B=64, IC=HC=1024, fp32 in/out.
// pre1 = x*Wi1+b precomputed (parallel MFMA GEMM, frag-major into d_out).
// Persistent kernel, 3 groups of 64 WGs x 512 threads (waves = K-eighths).
// Cross-WG data: sc0/sc1 write-through stores + sc0/sc1 coherent loads.
// ROUND-12: fine-grained per-wave producer polls (4 flags instead of 64);
// no post-poll barrier; explicit WlS staging barrier; all-64 polls remain
// only as 2-stage-slack anti-dep polls on w1/w2 (ordered by barrier 1
// before slab writes). Producer epilogue/flag protocol = round 11 verbatim.
//   G0 (wg 0..63):    h1[s]   = tanh(pre1[s] + h1[s-1]*Wh1^T)        s=0..511
//   G1 (wg 64..127):  pre2[s-1] = h1[s-1]*Wi2^T + b2                 s=1..512
//   G2 (wg 128..191): h2[s-2] = tanh(pre2[s-2] + h2[s-3]*Wh2^T)      s=2..513
// Split-bf16 (hi+lo, drop lo*lo) MFMA 16x16x32, fp32 accumulate.

#define T_STEPS 512
#define HCC     1024
#define BH      65536
#define NWG     192

typedef __attribute__((ext_vector_type(8))) short  bf16x8;
typedef __attribute__((ext_vector_type(4))) float  f32x4;

// ws layout: WF 16 MiB | h1F 4 slabs | h2F 4 slabs | pre2 4 slots | flags
#define WF_SHORTS   8388608u
#define SLAB_SHORTS 131072u
#define OFF_H1F     WF_SHORTS
#define OFF_H2F     (OFF_H1F + 4u*SLAB_SHORTS)
#define OFF_PRE2_BYTES ((size_t)(OFF_H2F + 4u*SLAB_SHORTS) * 2u)   /* 18,874,368 */
#define PRE2_FLOATS 65536u
#define FLG_BYTE_OFF (OFF_PRE2_BYTES + 4u*(size_t)PRE2_FLOATS*4u)  /* 19,922,944 */
#define FLG_UINTS   (3u*64u*4u)

__device__ __forceinline__ unsigned fidx(unsigned g, unsigned i) {
    return (g * 64u + i) * 4u;
}

// ---- raw 16B loads/stores; VMEM ordering handled manually ----
__device__ __forceinline__ void gload_b128_cc(bf16x8& d, const unsigned short* p) {
    asm volatile("global_load_dwordx4 %0, %1, off sc0 sc1" : "=v"(d) : "v"(p));
}
__device__ __forceinline__ void gload_f128_cc(f32x4& d, const float* p) {
    asm volatile("global_load_dwordx4 %0, %1, off sc0 sc1" : "=v"(d) : "v"(p));
}
__device__ __forceinline__ void gload_f128_nc(f32x4& d, const float* p) {
    asm volatile("global_load_dwordx4 %0, %1, off" : "=v"(d) : "v"(p));
}
__device__ __forceinline__ void gstore_b128_cc(bf16x8 v, unsigned short* p) {
    asm volatile("global_store_dwordx4 %0, %1, off sc0 sc1" :: "v"(p), "v"(v) : "memory");
}
__device__ __forceinline__ void gstore_f128_cc(f32x4 v, float* p) {
    asm volatile("global_store_dwordx4 %0, %1, off sc0 sc1" :: "v"(p), "v"(v) : "memory");
}
__device__ __forceinline__ void vm_drain()  { asm volatile("s_waitcnt vmcnt(0)"  ::: "memory"); }
__device__ __forceinline__ void vm_wait4()  { asm volatile("s_waitcnt vmcnt(4)"  ::: "memory"); }
__device__ __forceinline__ void vm_wait8()  { asm volatile("s_waitcnt vmcnt(8)"  ::: "memory"); }
__device__ __forceinline__ void vm_wait12() { asm volatile("s_waitcnt vmcnt(12)" ::: "memory"); }
#define SBAR() __builtin_amdgcn_sched_barrier(0)

__device__ __forceinline__ unsigned short bf16_rne_bits(float f) {
    unsigned u = __builtin_bit_cast(unsigned, f);
    unsigned r = u + 0x7fffu + ((u >> 16) & 1u);
    return (unsigned short)(r >> 16);
}
__device__ __forceinline__ void split1(float f, unsigned short& hi, unsigned short& lo) {
    unsigned u = __builtin_bit_cast(unsigned, f);
    unsigned r = (u + 0x7fffu + ((u >> 16) & 1u)) & 0xffff0000u;
    hi = (unsigned short)(r >> 16);
    float res = f - __builtin_bit_cast(float, r);
    lo = bf16_rne_bits(res);
}
__device__ __forceinline__ void split8(const float* f, bf16x8& H, bf16x8& L) {
#pragma unroll
    for (int e = 0; e < 8; ++e) {
        unsigned short hi, lo; split1(f[e], hi, lo);
        H[e] = (short)hi; L[e] = (short)lo;
    }
}
__device__ __forceinline__ float tanh_fast(float v) {
    float e = __expf(2.0f * v);
    return 1.0f - 2.0f * __builtin_amdgcn_rcpf(e + 1.0f);
}

__global__ __launch_bounds__(256) void zero_cnt_kernel(unsigned* cnt, unsigned n) {
    unsigned i = blockIdx.x * 256u + threadIdx.x;
    if (i < n) cnt[i] = 0u;
}

// ---------------- weight split to fragment-major ----------------
// WF[mat][prec][c16][ks][lane*8+e]; mat: 0=Wi1 1=Wh1 2=Wi2 3=Wh2
__global__ __launch_bounds__(256) void wsplit_kernel(
    const float* __restrict__ Wi, const float* __restrict__ Wh,
    unsigned short* __restrict__ WF)
{
    unsigned id  = blockIdx.x * 256u + threadIdx.x;   // < 524288
    unsigned kc  = id & 127u;
    unsigned row = (id >> 7) & 1023u;
    unsigned m   = id >> 17;                           // 0..3

    const float* src = ((m & 1u) ? Wh : Wi) + (size_t)(m >> 1) * HCC * HCC
                     + (size_t)row * HCC + kc * 8u;
    float f[8];
    *(f32x4*)&f[0] = *(const f32x4*)&src[0];
    *(f32x4*)&f[4] = *(const f32x4*)&src[4];
    bf16x8 H, L; split8(f, H, L);

    unsigned c16 = row >> 4, ks = kc >> 2;
    unsigned lane = (row & 15u) + 16u * (kc & 3u);
    size_t bh_ = (((size_t)(m * 2u + 0u) * 64u + c16) * 32u + ks) * 512u + lane * 8u;
    size_t bl_ = (((size_t)(m * 2u + 1u) * 64u + c16) * 32u + ks) * 512u + lane * 8u;
    *(bf16x8*)&WF[bh_] = H;
    *(bf16x8*)&WF[bl_] = L;
}

// ---------------- pre1 = x*Wi1^T + (bi1+bh1), frag-major into d_out ----------------
__global__ __launch_bounds__(256) void pre1_gemm(
    const float* __restrict__ x, const float* __restrict__ bi, const float* __restrict__ bh,
    const unsigned short* __restrict__ WF, float* __restrict__ preO)
{
    __shared__ float xs[64 * 36];
    const unsigned t = blockIdx.x >> 3, cg = blockIdx.x & 7u;
    const unsigned tid = threadIdx.x, w = tid >> 6, lane = tid & 63u;
    const unsigned ct32 = cg * 4u + w;

    float b0 = bi[ct32 * 32u + (lane & 15u)]        + bh[ct32 * 32u + (lane & 15u)];
    float b1 = bi[ct32 * 32u + 16u + (lane & 15u)]  + bh[ct32 * 32u + 16u + (lane & 15u)];
    f32x4 acc[4][2];
#pragma unroll
    for (unsigned rt = 0; rt < 4; ++rt) {
        acc[rt][0] = (f32x4){b0, b0, b0, b0};
        acc[rt][1] = (f32x4){b1, b1, b1, b1};
    }
    const float* xt = x + (size_t)t * BH;

    for (unsigned ks = 0; ks < 32; ++ks) {
        {
            unsigned row = tid >> 2, c8 = (tid & 3u) * 8u;
            const float* sp = xt + (size_t)row * HCC + ks * 32u + c8;
            *(f32x4*)&xs[row * 36u + c8]      = *(const f32x4*)&sp[0];
            *(f32x4*)&xs[row * 36u + c8 + 4u] = *(const f32x4*)&sp[4];
        }
        __syncthreads();
        bf16x8 bhv[2], blv[2];
#pragma unroll
        for (unsigned c16 = 0; c16 < 2; ++c16) {
            size_t base = (((size_t)(0u) * 64u + (ct32 * 2u + c16)) * 32u + ks) * 512u + lane * 8u;
            bhv[c16] = *(const bf16x8*)&WF[base];
            blv[c16] = *(const bf16x8*)&WF[base + (size_t)64u * 32u * 512u];
        }
#pragma unroll
        for (unsigned rt = 0; rt < 4; ++rt) {
            unsigned row = rt * 16u + (lane & 15u);
            unsigned k0 = (lane >> 4) * 8u;
            float f[8];
            *(f32x4*)&f[0] = *(const f32x4*)&xs[row * 36u + k0];
            *(f32x4*)&f[4] = *(const f32x4*)&xs[row * 36u + k0 + 4u];
            bf16x8 ah, al; split8(f, ah, al);
#pragma unroll
            for (unsigned c16 = 0; c16 < 2; ++c16) {
                acc[rt][c16] = __builtin_amdgcn_mfma_f32_16x16x32_bf16(ah, bhv[c16], acc[rt][c16], 0, 0, 0);
                acc[rt][c16] = __builtin_amdgcn_mfma_f32_16x16x32_bf16(al, bhv[c16], acc[rt][c16], 0, 0, 0);
                acc[rt][c16] = __builtin_amdgcn_mfma_f32_16x16x32_bf16(ah, blv[c16], acc[rt][c16], 0, 0, 0);
            }
        }
        __syncthreads();
    }
#pragma unroll
    for (unsigned rt = 0; rt < 4; ++rt)
#pragma unroll
        for (unsigned c16 = 0; c16 < 2; ++c16) {
            unsigned rh = rt >> 1, fi = (rt & 1u) * 2u + c16;
            size_t off = ((((size_t)t * 2u + rh) * 32u + ct32) * 4u + fi) * 256u + lane * 4u;
            *(f32x4*)&preO[off] = acc[rt][c16];
        }
}

// ---------------- persistent 3-group pipeline ----------------
__global__ __launch_bounds__(512, 1) void rnn_persist(
    const float* __restrict__ bi, const float* __restrict__ bh,
    const unsigned short* __restrict__ WF,
    unsigned short* __restrict__ h1F, unsigned short* __restrict__ h2F,
    float* __restrict__ pre2F, unsigned* __restrict__ flg,
    float* __restrict__ seqO, float* __restrict__ hsO)
{
    __shared__ short WlS[65536];       // 128 KiB weights (hi+lo, 32 cols)
    __shared__ float redS[7168];       // 28 KiB: 7 bufs x [frag(4)][lane][4]
    float* const epS = &redS[4096];    // aliases bufs 4-6 (stage-end barrier ordered)

    const unsigned wg  = blockIdx.x;
    const unsigned grp = wg >> 6;                // 0,1,2
    const unsigned sub = wg & 63u;
    const unsigned rh  = sub >> 5, ct = sub & 31u;
    const unsigned tid = threadIdx.x;
    const unsigned w   = tid >> 6, lane = tid & 63u;  // w = K-eighth

    // persistent weight LDS (mat block = grp+1: Wh1/Wi2/Wh2)
    const unsigned mat = grp + 1u;
#pragma unroll
    for (unsigned prec = 0; prec < 2; ++prec)
#pragma unroll
        for (unsigned c16l = 0; c16l < 2; ++c16l) {
            const unsigned short* sp = WF + (((size_t)(mat * 2u + prec) * 64u + (ct * 2u + c16l)) * 32u) * 512u;
            short* dp = &WlS[(prec * 2u + c16l) * 16384u];
            for (unsigned o = tid * 8u; o < 16384u; o += 4096u)
                *(bf16x8*)&dp[o] = *(const bf16x8*)&sp[o];
        }
    __syncthreads();   // WlS staged cross-wave; explicit barrier (round-10 lesson)

    float binit0 = 0.f, binit1 = 0.f;
    if (grp == 1u) {
        unsigned c = HCC + ct * 32u + (lane & 15u);
        binit0 = bi[c] + bh[c];
        binit1 = bi[c + 16u] + bh[c + 16u];
    }

    const int s0_ = (grp == 0u) ? 0 : (grp == 1u) ? 1 : 2;
    const int s1_ = s0_ + 511;

#define POLL(G, TGT) do {                                                             \
        const unsigned* fp_ = flg + fidx((G), lane);                                  \
        while (!__all((int)(__hip_atomic_load(fp_, __ATOMIC_RELAXED,                  \
                                              __HIP_MEMORY_SCOPE_AGENT) >= (unsigned)(TGT)))) \
            __builtin_amdgcn_s_sleep(1);                                              \
    } while (0)
// fine poll: this wave's 4 producers (same rh, ct' = 4w..4w+3)
#define POLL4(G, TGT) do {                                                            \
        const unsigned* fp_ = flg + fidx((G), rh * 32u + w * 4u + (lane & 3u));       \
        while (!__all((int)(__hip_atomic_load(fp_, __ATOMIC_RELAXED,                  \
                                              __HIP_MEMORY_SCOPE_AGENT) >= (unsigned)(TGT)))) \
            __builtin_amdgcn_s_sleep(1);                                              \
    } while (0)
// single flag (uniform across lanes)
#define POLL1(G, IDX, TGT) do {                                                       \
        const unsigned* fp_ = flg + fidx((G), (IDX));                                 \
        while (__hip_atomic_load(fp_, __ATOMIC_RELAXED,                               \
                                 __HIP_MEMORY_SCOPE_AGENT) < (unsigned)(TGT))         \
            __builtin_amdgcn_s_sleep(1);                                              \
    } while (0)

    for (int s = s0_; s <= s1_; ++s) {
        // ---- fine-grained A-gate polls (per wave, no barrier) ----
        if (grp == 0u)      { if (s >= 1) POLL4(0u, s); }
        else if (grp == 1u) { POLL4(0u, s); }
        else {
            if (s >= 3) POLL4(2u, s);                 // own h2 K-eighth
            if (w == 0u) POLL1(1u, sub, s);           // pre2 tile (G1 same sub)
        }
        // ---- anti-dep polls, 2-stage slack (ordered before writes by barrier 1) ----
        if (w == 1u) {
            if (grp == 0u && s >= 4) POLL(1u, s - 2); // G1 done reading h1[s-4]
            if (grp == 1u && s >= 5) POLL(2u, s - 2); // G2 done reading pre2[s-5]
        }
        if (w == 2u) {
            if (grp == 0u && s >= 4) POLL(0u, s - 2); // G0 done reading h1[s-4]
            if (grp == 2u && s >= 6) POLL(2u, s - 2); // G2 done reading h2[s-6]
        }

        const bool do_h   = (grp == 0u) ? (s > 0) : (grp == 1u) ? true : (s > 2);
        const bool has_ld = (w == 0u && grp != 1u);

        // ---- A loads: Ah (8), Al (8), then wave0 acc loads (newest) ----
        bf16x8 Ah0[4], Ah1[4], Al0[4], Al1[4];
        if (do_h) {
            const unsigned aslot = (grp == 2u) ? ((unsigned)(s - 3) & 3u)
                                               : ((unsigned)(s - 1) & 3u);
            const unsigned short* Aslab = (grp <= 1u ? h1F : h2F)
                                        + (size_t)aslot * SLAB_SHORTS;
            const unsigned b00 = ((rh * 2u + 0u) * 2u + 0u) * 16384u;
            const unsigned b01 = ((rh * 2u + 0u) * 2u + 1u) * 16384u;
            const unsigned b10 = ((rh * 2u + 1u) * 2u + 0u) * 16384u;
            const unsigned b11 = ((rh * 2u + 1u) * 2u + 1u) * 16384u;
#pragma unroll
            for (unsigned i = 0; i < 4; ++i) {
                const unsigned ao = (w * 4u + i) * 512u + lane * 8u;
                gload_b128_cc(Ah0[i], Aslab + b00 + ao);
                gload_b128_cc(Ah1[i], Aslab + b01 + ao);
            }
#pragma unroll
            for (unsigned i = 0; i < 4; ++i) {
                const unsigned ao = (w * 4u + i) * 512u + lane * 8u;
                gload_b128_cc(Al0[i], Aslab + b10 + ao);
                gload_b128_cc(Al1[i], Aslab + b11 + ao);
            }
        }
        f32x4 ld0 = {0,0,0,0}, ld1 = {0,0,0,0}, ld2 = {0,0,0,0}, ld3 = {0,0,0,0};
        if (has_ld) {
            if (grp == 0u) {
                const float* pp = seqO + (((size_t)s * 2u + rh) * 32u + ct) * 1024u;
                gload_f128_nc(ld0, pp + 0u * 256u + lane * 4u);
                gload_f128_nc(ld1, pp + 1u * 256u + lane * 4u);
                gload_f128_nc(ld2, pp + 2u * 256u + lane * 4u);
                gload_f128_nc(ld3, pp + 3u * 256u + lane * 4u);
            } else {
                const float* pp = pre2F + (size_t)((s - 2) & 3) * PRE2_FLOATS
                                + ((size_t)rh * 32u + ct) * 1024u;
                gload_f128_cc(ld0, pp + 0u * 256u + lane * 4u);
                gload_f128_cc(ld1, pp + 1u * 256u + lane * 4u);
                gload_f128_cc(ld2, pp + 2u * 256u + lane * 4u);
                gload_f128_cc(ld3, pp + 3u * 256u + lane * 4u);
            }
        }

        f32x4 a00 = {0,0,0,0}, a01 = {0,0,0,0}, a10 = {0,0,0,0}, a11 = {0,0,0,0};
        if (do_h) {
            // phase 1: Ah terms (oldest 8 loads) while Al (+acc) stream
            if (has_ld) vm_wait12(); else vm_wait8();
            SBAR();
#pragma unroll
            for (unsigned i = 0; i < 4; ++i) {
                const unsigned ao = (w * 4u + i) * 512u + lane * 8u;
                bf16x8 bh0 = *(const bf16x8*)&WlS[ao];
                bf16x8 bh1 = *(const bf16x8*)&WlS[16384u + ao];
                bf16x8 bl0 = *(const bf16x8*)&WlS[32768u + ao];
                bf16x8 bl1 = *(const bf16x8*)&WlS[49152u + ao];
                a00 = __builtin_amdgcn_mfma_f32_16x16x32_bf16(Ah0[i], bh0, a00, 0, 0, 0);
                a01 = __builtin_amdgcn_mfma_f32_16x16x32_bf16(Ah0[i], bh1, a01, 0, 0, 0);
                a10 = __builtin_amdgcn_mfma_f32_16x16x32_bf16(Ah1[i], bh0, a10, 0, 0, 0);
                a11 = __builtin_amdgcn_mfma_f32_16x16x32_bf16(Ah1[i], bh1, a11, 0, 0, 0);
                a00 = __builtin_amdgcn_mfma_f32_16x16x32_bf16(Ah0[i], bl0, a00, 0, 0, 0);
                a01 = __builtin_amdgcn_mfma_f32_16x16x32_bf16(Ah0[i], bl1, a01, 0, 0, 0);
                a10 = __builtin_amdgcn_mfma_f32_16x16x32_bf16(Ah1[i], bl0, a10, 0, 0, 0);
                a11 = __builtin_amdgcn_mfma_f32_16x16x32_bf16(Ah1[i], bl1, a11, 0, 0, 0);
            }
            // phase 2: Al x W_hi (acc loads may stay in flight on wave0)
            if (has_ld) vm_wait4(); else vm_drain();
            SBAR();
#pragma unroll
            for (unsigned i = 0; i < 4; ++i) {
                const unsigned ao = (w * 4u + i) * 512u + lane * 8u;
                bf16x8 bh0 = *(const bf16x8*)&WlS[ao];
                bf16x8 bh1 = *(const bf16x8*)&WlS[16384u + ao];
                a00 = __builtin_amdgcn_mfma_f32_16x16x32_bf16(Al0[i], bh0, a00, 0, 0, 0);
                a01 = __builtin_amdgcn_mfma_f32_16x16x32_bf16(Al0[i], bh1, a01, 0, 0, 0);
                a10 = __builtin_amdgcn_mfma_f32_16x16x32_bf16(Al1[i], bh0, a10, 0, 0, 0);
                a11 = __builtin_amdgcn_mfma_f32_16x16x32_bf16(Al1[i], bh1, a11, 0, 0, 0);
            }
        } else {
            vm_drain(); SBAR();
        }

        // ---- single-barrier 8-way reduction (7 buffers) ----
        if (w) {
            *(f32x4*)&redS[((w - 1u) * 4u + 0u) * 256u + lane * 4u] = a00;
            *(f32x4*)&redS[((w - 1u) * 4u + 1u) * 256u + lane * 4u] = a01;
            *(f32x4*)&redS[((w - 1u) * 4u + 2u) * 256u + lane * 4u] = a10;
            *(f32x4*)&redS[((w - 1u) * 4u + 3u) * 256u + lane * 4u] = a11;
        }
        __syncthreads();                                   // barrier 1
        if (w == 0u) {
#pragma unroll
            for (unsigned b = 0; b < 7; ++b) {
                a00 += *(const f32x4*)&redS[(b * 4u + 0u) * 256u + lane * 4u];
                a01 += *(const f32x4*)&redS[(b * 4u + 1u) * 256u + lane * 4u];
                a10 += *(const f32x4*)&redS[(b * 4u + 2u) * 256u + lane * 4u];
                a11 += *(const f32x4*)&redS[(b * 4u + 3u) * 256u + lane * 4u];
            }
            vm_drain(); SBAR();     // acc-init loads retired
            if (grp == 1u) {
                a00 += (f32x4){binit0, binit0, binit0, binit0};
                a01 += (f32x4){binit1, binit1, binit1, binit1};
                a10 += (f32x4){binit0, binit0, binit0, binit0};
                a11 += (f32x4){binit1, binit1, binit1, binit1};
                float* pp = pre2F + (size_t)((s - 1) & 3) * PRE2_FLOATS
                          + ((size_t)rh * 32u + ct) * 1024u;
                gstore_f128_cc(a00, pp + 0u * 256u + lane * 4u);
                gstore_f128_cc(a01, pp + 1u * 256u + lane * 4u);
                gstore_f128_cc(a10, pp + 2u * 256u + lane * 4u);
                gstore_f128_cc(a11, pp + 3u * 256u + lane * 4u);
            } else {
                a00 += ld0; a01 += ld1; a10 += ld2; a11 += ld3;
                // tanh -> epS [32 rows][36 cols]
#pragma unroll
                for (unsigned rr = 0; rr < 4; ++rr) {
                    unsigned rbase = ((lane >> 4) * 4u + rr) * 36u;
                    epS[rbase + (lane & 15u)]                 = tanh_fast(a00[rr]);
                    epS[rbase + 16u + (lane & 15u)]           = tanh_fast(a01[rr]);
                    epS[576u + rbase + (lane & 15u)]          = tanh_fast(a10[rr]);
                    epS[576u + rbase + 16u + (lane & 15u)]    = tanh_fast(a11[rr]);
                }
            }
        }
        if (grp != 1u) {
            __syncthreads();                               // barrier 2: epS ready
            // h-slab store (hi+lo) from epS, waves 0..3
            if (w < 4u) {
                const unsigned r16l = w >> 1, prec = w & 1u;
                const unsigned row = r16l * 16u + (lane & 15u);
                const unsigned c0 = (lane >> 4) * 8u;
                float f[8];
                *(f32x4*)&f[0] = *(const f32x4*)&epS[row * 36u + c0];
                *(f32x4*)&f[4] = *(const f32x4*)&epS[row * 36u + c0 + 4u];
                bf16x8 H, L; split8(f, H, L);
                unsigned short* hdst = (grp == 0u ? h1F : h2F)
                    + (size_t)((unsigned)(grp == 0u ? s : s - 2) & 3u) * SLAB_SHORTS;
                gstore_b128_cc(prec ? L : H,
                    hdst + ((rh * 2u + prec) * 2u + r16l) * 16384u + ct * 512u + lane * 8u);
            }
            // coalesced fp32 outputs from epS
            if (grp == 2u) {
                const int t2 = s - 2;
#pragma unroll
                for (unsigned pass = 0; pass < 2; ++pass) {
                    const unsigned r = w * 4u + pass * 2u + (lane >> 5);
                    const unsigned c = lane & 31u;
                    const float v = epS[r * 36u + c];
                    seqO[((size_t)t2 * 64u + rh * 32u + r) * 1024u + ct * 32u + c] = v;
                    if (s == 513) hsO[BH + (size_t)(rh * 32u + r) * 1024u + ct * 32u + c] = v;
                }
            }
            if (grp == 0u && s == 511) {
#pragma unroll
                for (unsigned pass = 0; pass < 2; ++pass) {
                    const unsigned r = w * 4u + pass * 2u + (lane >> 5);
                    const unsigned c = lane & 31u;
                    hsO[(size_t)(rh * 32u + r) * 1024u + ct * 32u + c] = epS[r * 36u + c];
                }
            }
        }
        // ---- stage end: drain stores (all waves), barrier, tid0 flag ----
        vm_drain();
        __syncthreads();
        if (tid == 0u)
            __hip_atomic_store(flg + fidx(grp, sub), (unsigned)s + 1u,
                               __ATOMIC_RELAXED, __HIP_MEMORY_SCOPE_AGENT);
    }
#undef POLL
#undef POLL4
#undef POLL1
}

extern "C" void kernel_launch(void* const* d_in, const int* in_sizes, int n_in,
                              void* d_out, int out_size, void* d_ws, size_t ws_size,
                              hipStream_t stream) {
    const float* x  = (const float*)d_in[0];
    const float* Wi = (const float*)d_in[1];
    const float* bi = (const float*)d_in[2];
    const float* Wh = (const float*)d_in[3];
    const float* bh = (const float*)d_in[4];

    float* seqO = (float*)d_out;
    float* hsO  = seqO + (size_t)T_STEPS * BH;

    unsigned short* wsS = (unsigned short*)d_ws;
    unsigned short* WF  = wsS;
    unsigned short* h1F = wsS + OFF_H1F;
    unsigned short* h2F = wsS + OFF_H2F;
    float* pre2F = (float*)((char*)d_ws + OFF_PRE2_BYTES);
    unsigned* flg = (unsigned*)((char*)d_ws + FLG_BYTE_OFF);

    zero_cnt_kernel<<<(FLG_UINTS + 255u) / 256u, 256, 0, stream>>>(flg, FLG_UINTS);
    wsplit_kernel<<<2048, 256, 0, stream>>>(Wi, Wh, WF);
    pre1_gemm<<<4096, 256, 0, stream>>>(x, bi, bh, WF, seqO);
    rnn_persist<<<NWG, 512, 0, stream>>>(bi, bh, WF, h1F, h2F, pre2F, flg, seqO, hsO);
}

// Round 13
// 2788.094 us; speedup vs baseline: 7.6165x; 1.0190x over previous
//
#include <hip/hip_runtime.h>

// 2-layer tanh RNN, T=512, B=64, IC=HC=1024, fp32 in/out.
// pre1 = x*Wi1+b precomputed (parallel MFMA GEMM, frag-major into d_out).
// Persistent kernel, 3 groups of 64 WGs x 512 threads (waves = K-eighths).
// Cross-WG data: sc0/sc1 write-through stores + sc0/sc1 coherent loads.
// ROUND-13: per-store-wave flags signaled BEFORE the stage-end barrier;
// consumers A-gate on 16 flags (4 producers x 4 store-waves); anti-deps on
// w'=0 flags (wave0 flag => barrier1 passed => all waves' loads retired);
// G2 uses counted vmcnt(2) so seqO HBM stores don't gate the flag.
//   G0 (wg 0..63):    h1[s]   = tanh(pre1[s] + h1[s-1]*Wh1^T)        s=0..511
//   G1 (wg 64..127):  pre2[s-1] = h1[s-1]*Wi2^T + b2                 s=1..512
//   G2 (wg 128..191): h2[s-2] = tanh(pre2[s-2] + h2[s-3]*Wh2^T)      s=2..513
// Split-bf16 (hi+lo, drop lo*lo) MFMA 16x16x32, fp32 accumulate.

#define T_STEPS 512
#define HCC     1024
#define BH      65536
#define NWG     192

typedef __attribute__((ext_vector_type(8))) short  bf16x8;
typedef __attribute__((ext_vector_type(4))) float  f32x4;

// ws layout: WF 16 MiB | h1F 4 slabs | h2F 4 slabs | pre2 4 slots | flags
#define WF_SHORTS   8388608u
#define SLAB_SHORTS 131072u
#define OFF_H1F     WF_SHORTS
#define OFF_H2F     (OFF_H1F + 4u*SLAB_SHORTS)
#define OFF_PRE2_BYTES ((size_t)(OFF_H2F + 4u*SLAB_SHORTS) * 2u)   /* 18,874,368 */
#define PRE2_FLOATS 65536u
#define FLG_BYTE_OFF (OFF_PRE2_BYTES + 4u*(size_t)PRE2_FLOATS*4u)  /* 19,922,944 */
#define FLG_UINTS   (3u*64u*4u*4u)           /* [g][sub][wp], 16B-strided */

__device__ __forceinline__ unsigned fidx(unsigned g, unsigned i, unsigned wp) {
    return ((g * 64u + i) * 4u + wp) * 4u;
}

// ---- raw 16B loads/stores; VMEM ordering handled manually ----
__device__ __forceinline__ void gload_b128_cc(bf16x8& d, const unsigned short* p) {
    asm volatile("global_load_dwordx4 %0, %1, off sc0 sc1" : "=v"(d) : "v"(p));
}
__device__ __forceinline__ void gload_f128_cc(f32x4& d, const float* p) {
    asm volatile("global_load_dwordx4 %0, %1, off sc0 sc1" : "=v"(d) : "v"(p));
}
__device__ __forceinline__ void gload_f128_nc(f32x4& d, const float* p) {
    asm volatile("global_load_dwordx4 %0, %1, off" : "=v"(d) : "v"(p));
}
__device__ __forceinline__ void gstore_b128_cc(bf16x8 v, unsigned short* p) {
    asm volatile("global_store_dwordx4 %0, %1, off sc0 sc1" :: "v"(p), "v"(v) : "memory");
}
__device__ __forceinline__ void gstore_f128_cc(f32x4 v, float* p) {
    asm volatile("global_store_dwordx4 %0, %1, off sc0 sc1" :: "v"(p), "v"(v) : "memory");
}
__device__ __forceinline__ void vm_drain()  { asm volatile("s_waitcnt vmcnt(0)"  ::: "memory"); }
__device__ __forceinline__ void vm_wait2()  { asm volatile("s_waitcnt vmcnt(2)"  ::: "memory"); }
__device__ __forceinline__ void vm_wait4()  { asm volatile("s_waitcnt vmcnt(4)"  ::: "memory"); }
__device__ __forceinline__ void vm_wait8()  { asm volatile("s_waitcnt vmcnt(8)"  ::: "memory"); }
__device__ __forceinline__ void vm_wait12() { asm volatile("s_waitcnt vmcnt(12)" ::: "memory"); }
#define SBAR() __builtin_amdgcn_sched_barrier(0)

__device__ __forceinline__ unsigned short bf16_rne_bits(float f) {
    unsigned u = __builtin_bit_cast(unsigned, f);
    unsigned r = u + 0x7fffu + ((u >> 16) & 1u);
    return (unsigned short)(r >> 16);
}
__device__ __forceinline__ void split1(float f, unsigned short& hi, unsigned short& lo) {
    unsigned u = __builtin_bit_cast(unsigned, f);
    unsigned r = (u + 0x7fffu + ((u >> 16) & 1u)) & 0xffff0000u;
    hi = (unsigned short)(r >> 16);
    float res = f - __builtin_bit_cast(float, r);
    lo = bf16_rne_bits(res);
}
__device__ __forceinline__ void split8(const float* f, bf16x8& H, bf16x8& L) {
#pragma unroll
    for (int e = 0; e < 8; ++e) {
        unsigned short hi, lo; split1(f[e], hi, lo);
        H[e] = (short)hi; L[e] = (short)lo;
    }
}
__device__ __forceinline__ float tanh_fast(float v) {
    float e = __expf(2.0f * v);
    return 1.0f - 2.0f * __builtin_amdgcn_rcpf(e + 1.0f);
}

__global__ __launch_bounds__(256) void zero_cnt_kernel(unsigned* cnt, unsigned n) {
    unsigned i = blockIdx.x * 256u + threadIdx.x;
    if (i < n) cnt[i] = 0u;
}

// ---------------- weight split to fragment-major ----------------
// WF[mat][prec][c16][ks][lane*8+e]; mat: 0=Wi1 1=Wh1 2=Wi2 3=Wh2
__global__ __launch_bounds__(256) void wsplit_kernel(
    const float* __restrict__ Wi, const float* __restrict__ Wh,
    unsigned short* __restrict__ WF)
{
    unsigned id  = blockIdx.x * 256u + threadIdx.x;   // < 524288
    unsigned kc  = id & 127u;
    unsigned row = (id >> 7) & 1023u;
    unsigned m   = id >> 17;                           // 0..3

    const float* src = ((m & 1u) ? Wh : Wi) + (size_t)(m >> 1) * HCC * HCC
                     + (size_t)row * HCC + kc * 8u;
    float f[8];
    *(f32x4*)&f[0] = *(const f32x4*)&src[0];
    *(f32x4*)&f[4] = *(const f32x4*)&src[4];
    bf16x8 H, L; split8(f, H, L);

    unsigned c16 = row >> 4, ks = kc >> 2;
    unsigned lane = (row & 15u) + 16u * (kc & 3u);
    size_t bh_ = (((size_t)(m * 2u + 0u) * 64u + c16) * 32u + ks) * 512u + lane * 8u;
    size_t bl_ = (((size_t)(m * 2u + 1u) * 64u + c16) * 32u + ks) * 512u + lane * 8u;
    *(bf16x8*)&WF[bh_] = H;
    *(bf16x8*)&WF[bl_] = L;
}

// ---------------- pre1 = x*Wi1^T + (bi1+bh1), frag-major into d_out ----------------
__global__ __launch_bounds__(256) void pre1_gemm(
    const float* __restrict__ x, const float* __restrict__ bi, const float* __restrict__ bh,
    const unsigned short* __restrict__ WF, float* __restrict__ preO)
{
    __shared__ float xs[64 * 36];
    const unsigned t = blockIdx.x >> 3, cg = blockIdx.x & 7u;
    const unsigned tid = threadIdx.x, w = tid >> 6, lane = tid & 63u;
    const unsigned ct32 = cg * 4u + w;

    float b0 = bi[ct32 * 32u + (lane & 15u)]        + bh[ct32 * 32u + (lane & 15u)];
    float b1 = bi[ct32 * 32u + 16u + (lane & 15u)]  + bh[ct32 * 32u + 16u + (lane & 15u)];
    f32x4 acc[4][2];
#pragma unroll
    for (unsigned rt = 0; rt < 4; ++rt) {
        acc[rt][0] = (f32x4){b0, b0, b0, b0};
        acc[rt][1] = (f32x4){b1, b1, b1, b1};
    }
    const float* xt = x + (size_t)t * BH;

    for (unsigned ks = 0; ks < 32; ++ks) {
        {
            unsigned row = tid >> 2, c8 = (tid & 3u) * 8u;
            const float* sp = xt + (size_t)row * HCC + ks * 32u + c8;
            *(f32x4*)&xs[row * 36u + c8]      = *(const f32x4*)&sp[0];
            *(f32x4*)&xs[row * 36u + c8 + 4u] = *(const f32x4*)&sp[4];
        }
        __syncthreads();
        bf16x8 bhv[2], blv[2];
#pragma unroll
        for (unsigned c16 = 0; c16 < 2; ++c16) {
            size_t base = (((size_t)(0u) * 64u + (ct32 * 2u + c16)) * 32u + ks) * 512u + lane * 8u;
            bhv[c16] = *(const bf16x8*)&WF[base];
            blv[c16] = *(const bf16x8*)&WF[base + (size_t)64u * 32u * 512u];
        }
#pragma unroll
        for (unsigned rt = 0; rt < 4; ++rt) {
            unsigned row = rt * 16u + (lane & 15u);
            unsigned k0 = (lane >> 4) * 8u;
            float f[8];
            *(f32x4*)&f[0] = *(const f32x4*)&xs[row * 36u + k0];
            *(f32x4*)&f[4] = *(const f32x4*)&xs[row * 36u + k0 + 4u];
            bf16x8 ah, al; split8(f, ah, al);
#pragma unroll
            for (unsigned c16 = 0; c16 < 2; ++c16) {
                acc[rt][c16] = __builtin_amdgcn_mfma_f32_16x16x32_bf16(ah, bhv[c16], acc[rt][c16], 0, 0, 0);
                acc[rt][c16] = __builtin_amdgcn_mfma_f32_16x16x32_bf16(al, bhv[c16], acc[rt][c16], 0, 0, 0);
                acc[rt][c16] = __builtin_amdgcn_mfma_f32_16x16x32_bf16(ah, blv[c16], acc[rt][c16], 0, 0, 0);
            }
        }
        __syncthreads();
    }
#pragma unroll
    for (unsigned rt = 0; rt < 4; ++rt)
#pragma unroll
        for (unsigned c16 = 0; c16 < 2; ++c16) {
            unsigned rh = rt >> 1, fi = (rt & 1u) * 2u + c16;
            size_t off = ((((size_t)t * 2u + rh) * 32u + ct32) * 4u + fi) * 256u + lane * 4u;
            *(f32x4*)&preO[off] = acc[rt][c16];
        }
}

// ---------------- persistent 3-group pipeline ----------------
__global__ __launch_bounds__(512, 1) void rnn_persist(
    const float* __restrict__ bi, const float* __restrict__ bh,
    const unsigned short* __restrict__ WF,
    unsigned short* __restrict__ h1F, unsigned short* __restrict__ h2F,
    float* __restrict__ pre2F, unsigned* __restrict__ flg,
    float* __restrict__ seqO, float* __restrict__ hsO)
{
    __shared__ short WlS[65536];       // 128 KiB weights (hi+lo, 32 cols)
    __shared__ float redS[7168];       // 28 KiB: 7 bufs x [frag(4)][lane][4]
    float* const epS = &redS[4096];    // aliases bufs 4-6 (stage-end barrier ordered)

    const unsigned wg  = blockIdx.x;
    const unsigned grp = wg >> 6;                // 0,1,2
    const unsigned sub = wg & 63u;
    const unsigned rh  = sub >> 5, ct = sub & 31u;
    const unsigned tid = threadIdx.x;
    const unsigned w   = tid >> 6, lane = tid & 63u;  // w = K-eighth

    // persistent weight LDS (mat block = grp+1: Wh1/Wi2/Wh2)
    const unsigned mat = grp + 1u;
#pragma unroll
    for (unsigned prec = 0; prec < 2; ++prec)
#pragma unroll
        for (unsigned c16l = 0; c16l < 2; ++c16l) {
            const unsigned short* sp = WF + (((size_t)(mat * 2u + prec) * 64u + (ct * 2u + c16l)) * 32u) * 512u;
            short* dp = &WlS[(prec * 2u + c16l) * 16384u];
            for (unsigned o = tid * 8u; o < 16384u; o += 4096u)
                *(bf16x8*)&dp[o] = *(const bf16x8*)&sp[o];
        }
    __syncthreads();   // WlS staged cross-wave; explicit barrier

    float binit0 = 0.f, binit1 = 0.f;
    if (grp == 1u) {
        unsigned c = HCC + ct * 32u + (lane & 15u);
        binit0 = bi[c] + bh[c];
        binit1 = bi[c + 16u] + bh[c + 16u];
    }

    const int s0_ = (grp == 0u) ? 0 : (grp == 1u) ? 1 : 2;
    const int s1_ = s0_ + 511;

// A-gate: this wave's 4 producers x 4 store-waves (16 flags, one vector load)
#define POLL16(G, TGT) do {                                                           \
        const unsigned* fp_ = flg + fidx((G), rh * 32u + w * 4u + ((lane >> 2) & 3u), \
                                         lane & 3u);                                  \
        while (!__all((int)(__hip_atomic_load(fp_, __ATOMIC_RELAXED,                  \
                                              __HIP_MEMORY_SCOPE_AGENT) >= (unsigned)(TGT)))) \
            __builtin_amdgcn_s_sleep(1);                                              \
    } while (0)
// anti-dep: all 64 WGs' wave0 flags (wave0 flag => barrier1 passed => loads retired)
#define POLLW0(G, TGT) do {                                                           \
        const unsigned* fp_ = flg + fidx((G), lane, 0u);                              \
        while (!__all((int)(__hip_atomic_load(fp_, __ATOMIC_RELAXED,                  \
                                              __HIP_MEMORY_SCOPE_AGENT) >= (unsigned)(TGT)))) \
            __builtin_amdgcn_s_sleep(1);                                              \
    } while (0)
// single flag (uniform across lanes)
#define POLL1(G, IDX, TGT) do {                                                       \
        const unsigned* fp_ = flg + fidx((G), (IDX), 0u);                             \
        while (__hip_atomic_load(fp_, __ATOMIC_RELAXED,                               \
                                 __HIP_MEMORY_SCOPE_AGENT) < (unsigned)(TGT))         \
            __builtin_amdgcn_s_sleep(1);                                              \
    } while (0)

    for (int s = s0_; s <= s1_; ++s) {
        // ---- fine-grained A-gate polls (per wave, no barrier) ----
        if (grp == 0u)      { if (s >= 1) POLL16(0u, s); }
        else if (grp == 1u) { POLL16(0u, s); }
        else {
            if (s >= 3) POLL16(2u, s);                // own h2 K-eighth
            if (w == 0u) POLL1(1u, sub, s);           // pre2 tile (G1 wave0 flag)
        }
        // ---- anti-dep polls, 2-stage slack ----
        if (w == 1u) {
            if (grp == 0u && s >= 4) POLLW0(1u, s - 2); // G1 done reading h1[s-4]
            if (grp == 1u && s >= 5) POLLW0(2u, s - 2); // G2 done reading pre2[s-5]
        }
        if (w == 2u) {
            if (grp == 0u && s >= 4) POLLW0(0u, s - 2); // G0 done reading h1[s-4]
            if (grp == 2u && s >= 6) POLLW0(2u, s - 2); // G2 done reading h2[s-6]
        }

        const bool do_h   = (grp == 0u) ? (s > 0) : (grp == 1u) ? true : (s > 2);
        const bool has_ld = (w == 0u && grp != 1u);

        // ---- A loads: Ah (8), Al (8), then wave0 acc loads (newest) ----
        // NOTE: up to 2 stale seqO stores may be outstanding from the previous
        // stage (G2 w<8). vmcnt waits are oldest-first, so the counted waits
        // below still cover exactly {stale stores + Ah} / {+Al} as intended.
        bf16x8 Ah0[4], Ah1[4], Al0[4], Al1[4];
        if (do_h) {
            const unsigned aslot = (grp == 2u) ? ((unsigned)(s - 3) & 3u)
                                               : ((unsigned)(s - 1) & 3u);
            const unsigned short* Aslab = (grp <= 1u ? h1F : h2F)
                                        + (size_t)aslot * SLAB_SHORTS;
            const unsigned b00 = ((rh * 2u + 0u) * 2u + 0u) * 16384u;
            const unsigned b01 = ((rh * 2u + 0u) * 2u + 1u) * 16384u;
            const unsigned b10 = ((rh * 2u + 1u) * 2u + 0u) * 16384u;
            const unsigned b11 = ((rh * 2u + 1u) * 2u + 1u) * 16384u;
#pragma unroll
            for (unsigned i = 0; i < 4; ++i) {
                const unsigned ao = (w * 4u + i) * 512u + lane * 8u;
                gload_b128_cc(Ah0[i], Aslab + b00 + ao);
                gload_b128_cc(Ah1[i], Aslab + b01 + ao);
            }
#pragma unroll
            for (unsigned i = 0; i < 4; ++i) {
                const unsigned ao = (w * 4u + i) * 512u + lane * 8u;
                gload_b128_cc(Al0[i], Aslab + b10 + ao);
                gload_b128_cc(Al1[i], Aslab + b11 + ao);
            }
        }
        f32x4 ld0 = {0,0,0,0}, ld1 = {0,0,0,0}, ld2 = {0,0,0,0}, ld3 = {0,0,0,0};
        if (has_ld) {
            if (grp == 0u) {
                const float* pp = seqO + (((size_t)s * 2u + rh) * 32u + ct) * 1024u;
                gload_f128_nc(ld0, pp + 0u * 256u + lane * 4u);
                gload_f128_nc(ld1, pp + 1u * 256u + lane * 4u);
                gload_f128_nc(ld2, pp + 2u * 256u + lane * 4u);
                gload_f128_nc(ld3, pp + 3u * 256u + lane * 4u);
            } else {
                const float* pp = pre2F + (size_t)((s - 2) & 3) * PRE2_FLOATS
                                + ((size_t)rh * 32u + ct) * 1024u;
                gload_f128_cc(ld0, pp + 0u * 256u + lane * 4u);
                gload_f128_cc(ld1, pp + 1u * 256u + lane * 4u);
                gload_f128_cc(ld2, pp + 2u * 256u + lane * 4u);
                gload_f128_cc(ld3, pp + 3u * 256u + lane * 4u);
            }
        }

        f32x4 a00 = {0,0,0,0}, a01 = {0,0,0,0}, a10 = {0,0,0,0}, a11 = {0,0,0,0};
        if (do_h) {
            // phase 1: Ah terms while Al (+acc) stream
            if (has_ld) vm_wait12(); else vm_wait8();
            SBAR();
#pragma unroll
            for (unsigned i = 0; i < 4; ++i) {
                const unsigned ao = (w * 4u + i) * 512u + lane * 8u;
                bf16x8 bh0 = *(const bf16x8*)&WlS[ao];
                bf16x8 bh1 = *(const bf16x8*)&WlS[16384u + ao];
                bf16x8 bl0 = *(const bf16x8*)&WlS[32768u + ao];
                bf16x8 bl1 = *(const bf16x8*)&WlS[49152u + ao];
                a00 = __builtin_amdgcn_mfma_f32_16x16x32_bf16(Ah0[i], bh0, a00, 0, 0, 0);
                a01 = __builtin_amdgcn_mfma_f32_16x16x32_bf16(Ah0[i], bh1, a01, 0, 0, 0);
                a10 = __builtin_amdgcn_mfma_f32_16x16x32_bf16(Ah1[i], bh0, a10, 0, 0, 0);
                a11 = __builtin_amdgcn_mfma_f32_16x16x32_bf16(Ah1[i], bh1, a11, 0, 0, 0);
                a00 = __builtin_amdgcn_mfma_f32_16x16x32_bf16(Ah0[i], bl0, a00, 0, 0, 0);
                a01 = __builtin_amdgcn_mfma_f32_16x16x32_bf16(Ah0[i], bl1, a01, 0, 0, 0);
                a10 = __builtin_amdgcn_mfma_f32_16x16x32_bf16(Ah1[i], bl0, a10, 0, 0, 0);
                a11 = __builtin_amdgcn_mfma_f32_16x16x32_bf16(Ah1[i], bl1, a11, 0, 0, 0);
            }
            // phase 2: Al x W_hi (acc loads may stay in flight on wave0)
            if (has_ld) vm_wait4(); else vm_drain();
            SBAR();
#pragma unroll
            for (unsigned i = 0; i < 4; ++i) {
                const unsigned ao = (w * 4u + i) * 512u + lane * 8u;
                bf16x8 bh0 = *(const bf16x8*)&WlS[ao];
                bf16x8 bh1 = *(const bf16x8*)&WlS[16384u + ao];
                a00 = __builtin_amdgcn_mfma_f32_16x16x32_bf16(Al0[i], bh0, a00, 0, 0, 0);
                a01 = __builtin_amdgcn_mfma_f32_16x16x32_bf16(Al0[i], bh1, a01, 0, 0, 0);
                a10 = __builtin_amdgcn_mfma_f32_16x16x32_bf16(Al1[i], bh0, a10, 0, 0, 0);
                a11 = __builtin_amdgcn_mfma_f32_16x16x32_bf16(Al1[i], bh1, a11, 0, 0, 0);
            }
        } else {
            vm_drain(); SBAR();
        }

        // ---- single-barrier 8-way reduction (7 buffers) ----
        if (w) {
            *(f32x4*)&redS[((w - 1u) * 4u + 0u) * 256u + lane * 4u] = a00;
            *(f32x4*)&redS[((w - 1u) * 4u + 1u) * 256u + lane * 4u] = a01;
            *(f32x4*)&redS[((w - 1u) * 4u + 2u) * 256u + lane * 4u] = a10;
            *(f32x4*)&redS[((w - 1u) * 4u + 3u) * 256u + lane * 4u] = a11;
        }
        __syncthreads();                                   // barrier 1
        if (w == 0u) {
#pragma unroll
            for (unsigned b = 0; b < 7; ++b) {
                a00 += *(const f32x4*)&redS[(b * 4u + 0u) * 256u + lane * 4u];
                a01 += *(const f32x4*)&redS[(b * 4u + 1u) * 256u + lane * 4u];
                a10 += *(const f32x4*)&redS[(b * 4u + 2u) * 256u + lane * 4u];
                a11 += *(const f32x4*)&redS[(b * 4u + 3u) * 256u + lane * 4u];
            }
            vm_drain(); SBAR();     // acc-init loads retired
            if (grp == 1u) {
                a00 += (f32x4){binit0, binit0, binit0, binit0};
                a01 += (f32x4){binit1, binit1, binit1, binit1};
                a10 += (f32x4){binit0, binit0, binit0, binit0};
                a11 += (f32x4){binit1, binit1, binit1, binit1};
                float* pp = pre2F + (size_t)((s - 1) & 3) * PRE2_FLOATS
                          + ((size_t)rh * 32u + ct) * 1024u;
                gstore_f128_cc(a00, pp + 0u * 256u + lane * 4u);
                gstore_f128_cc(a01, pp + 1u * 256u + lane * 4u);
                gstore_f128_cc(a10, pp + 2u * 256u + lane * 4u);
                gstore_f128_cc(a11, pp + 3u * 256u + lane * 4u);
                vm_drain();
                if (lane == 0u)
                    __hip_atomic_store(flg + fidx(1u, sub, 0u), (unsigned)s + 1u,
                                       __ATOMIC_RELAXED, __HIP_MEMORY_SCOPE_AGENT);
            } else {
                a00 += ld0; a01 += ld1; a10 += ld2; a11 += ld3;
                // tanh -> epS [32 rows][36 cols]
#pragma unroll
                for (unsigned rr = 0; rr < 4; ++rr) {
                    unsigned rbase = ((lane >> 4) * 4u + rr) * 36u;
                    epS[rbase + (lane & 15u)]                 = tanh_fast(a00[rr]);
                    epS[rbase + 16u + (lane & 15u)]           = tanh_fast(a01[rr]);
                    epS[576u + rbase + (lane & 15u)]          = tanh_fast(a10[rr]);
                    epS[576u + rbase + 16u + (lane & 15u)]    = tanh_fast(a11[rr]);
                }
            }
        }
        if (grp != 1u) {
            __syncthreads();                               // barrier 2: epS ready
            // h-slab store FIRST (it gates the flag), waves 0..3
            if (w < 4u) {
                const unsigned r16l = w >> 1, prec = w & 1u;
                const unsigned row = r16l * 16u + (lane & 15u);
                const unsigned c0 = (lane >> 4) * 8u;
                float f[8];
                *(f32x4*)&f[0] = *(const f32x4*)&epS[row * 36u + c0];
                *(f32x4*)&f[4] = *(const f32x4*)&epS[row * 36u + c0 + 4u];
                bf16x8 H, L; split8(f, H, L);
                unsigned short* hdst = (grp == 0u ? h1F : h2F)
                    + (size_t)((unsigned)(grp == 0u ? s : s - 2) & 3u) * SLAB_SHORTS;
                gstore_b128_cc(prec ? L : H,
                    hdst + ((rh * 2u + prec) * 2u + r16l) * 16384u + ct * 512u + lane * 8u);
            }
            // seqO outputs AFTER h-store (excluded from pre-flag wait via vmcnt(2))
            if (grp == 2u) {
                const int t2 = s - 2;
#pragma unroll
                for (unsigned pass = 0; pass < 2; ++pass) {
                    const unsigned r = w * 4u + pass * 2u + (lane >> 5);
                    const unsigned c = lane & 31u;
                    const float v = epS[r * 36u + c];
                    seqO[((size_t)t2 * 64u + rh * 32u + r) * 1024u + ct * 32u + c] = v;
                    if (s == 513) hsO[BH + (size_t)(rh * 32u + r) * 1024u + ct * 32u + c] = v;
                }
            }
            if (grp == 0u && s == 511) {
#pragma unroll
                for (unsigned pass = 0; pass < 2; ++pass) {
                    const unsigned r = w * 4u + pass * 2u + (lane >> 5);
                    const unsigned c = lane & 31u;
                    hsO[(size_t)(rh * 32u + r) * 1024u + ct * 32u + c] = epS[r * 36u + c];
                }
            }
            // per-store-wave counted wait + flag (BEFORE stage-end barrier)
            if (w < 4u) {
                if (grp == 2u && s < 513) vm_wait2(); else vm_drain();
                if (lane == 0u)
                    __hip_atomic_store(flg + fidx(grp, sub, w), (unsigned)s + 1u,
                                       __ATOMIC_RELAXED, __HIP_MEMORY_SCOPE_AGENT);
            }
        }
        // ---- stage-end barrier: redS/epS WAR protection only ----
        __syncthreads();
    }
    vm_drain();   // retire any straggler seqO stores before kernel end
#undef POLL16
#undef POLLW0
#undef POLL1
}

extern "C" void kernel_launch(void* const* d_in, const int* in_sizes, int n_in,
                              void* d_out, int out_size, void* d_ws, size_t ws_size,
                              hipStream_t stream) {
    const float* x  = (const float*)d_in[0];
    const float* Wi = (const float*)d_in[1];
    const float* bi = (const float*)d_in[2];
    const float* Wh = (const float*)d_in[3];
    const float* bh = (const float*)d_in[4];

    float* seqO = (float*)d_out;
    float* hsO  = seqO + (size_t)T_STEPS * BH;

    unsigned short* wsS = (unsigned short*)d_ws;
    unsigned short* WF  = wsS;
    unsigned short* h1F = wsS + OFF_H1F;
    unsigned short* h2F = wsS + OFF_H2F;
    float* pre2F = (float*)((char*)d_ws + OFF_PRE2_BYTES);
    unsigned* flg = (unsigned*)((char*)d_ws + FLG_BYTE_OFF);

    zero_cnt_kernel<<<(FLG_UINTS + 255u) / 256u, 256, 0, stream>>>(flg, FLG_UINTS);
    wsplit_kernel<<<2048, 256, 0, stream>>>(Wi, Wh, WF);
    pre1_gemm<<<4096, 256, 0, stream>>>(x, bi, bh, WF, seqO);
    rnn_persist<<<NWG, 512, 0, stream>>>(bi, bh, WF, h1F, h2F, pre2F, flg, seqO, hsO);
}

// Round 14
// 2509.679 us; speedup vs baseline: 8.4614x; 1.1109x over previous
//
#include <hip/hip_runtime.h>

// 2-layer tanh RNN, T=512, B=64, IC=HC=1024, fp32 in/out.
// pre1 = x*Wi1+b precomputed (parallel MFMA GEMM, frag-major into d_out).
// Persistent kernel, 3 groups of 64 WGs x 512 threads (waves = K-eighths).
// Cross-WG data: sc0/sc1 write-through stores + sc0/sc1 coherent loads.
// ROUND-14: frag-parallel epilogue. Wave j<4 owns output frag j
// (rows (j>>1)*16.., cols (j&1)*16..): waves write 3 non-owned partials to
// redS (28-slot bijective map), wave j sums + tanh + writes its 16x16
// quadrant at slot j*7 (read-then-overwrite, barrier-ordered). G1 frag-waves
// store pre2 frag + drain + flag[1][sub][j] (G2 polls 4 G1 flags).
// Acc-init loads hoisted pre-poll; anti-dep polls moved after phase 2.
//   G0 (wg 0..63):    h1[s]   = tanh(pre1[s] + h1[s-1]*Wh1^T)        s=0..511
//   G1 (wg 64..127):  pre2[s-1] = h1[s-1]*Wi2^T + b2                 s=1..512
//   G2 (wg 128..191): h2[s-2] = tanh(pre2[s-2] + h2[s-3]*Wh2^T)      s=2..513
// Split-bf16 (hi+lo, drop lo*lo) MFMA 16x16x32, fp32 accumulate.

#define T_STEPS 512
#define HCC     1024
#define BH      65536
#define NWG     192

typedef __attribute__((ext_vector_type(8))) short  bf16x8;
typedef __attribute__((ext_vector_type(4))) float  f32x4;

// ws layout: WF 16 MiB | h1F 4 slabs | h2F 4 slabs | pre2 4 slots | flags
#define WF_SHORTS   8388608u
#define SLAB_SHORTS 131072u
#define OFF_H1F     WF_SHORTS
#define OFF_H2F     (OFF_H1F + 4u*SLAB_SHORTS)
#define OFF_PRE2_BYTES ((size_t)(OFF_H2F + 4u*SLAB_SHORTS) * 2u)   /* 18,874,368 */
#define PRE2_FLOATS 65536u
#define FLG_BYTE_OFF (OFF_PRE2_BYTES + 4u*(size_t)PRE2_FLOATS*4u)  /* 19,922,944 */
#define FLG_UINTS   (3u*64u*4u*4u)           /* [g][sub][wp], 16B-strided */

__device__ __forceinline__ unsigned fidx(unsigned g, unsigned i, unsigned wp) {
    return ((g * 64u + i) * 4u + wp) * 4u;
}

// ---- raw 16B loads/stores; VMEM ordering handled manually ----
__device__ __forceinline__ void gload_b128_cc(bf16x8& d, const unsigned short* p) {
    asm volatile("global_load_dwordx4 %0, %1, off sc0 sc1" : "=v"(d) : "v"(p));
}
__device__ __forceinline__ void gload_f128_cc(f32x4& d, const float* p) {
    asm volatile("global_load_dwordx4 %0, %1, off sc0 sc1" : "=v"(d) : "v"(p));
}
__device__ __forceinline__ void gload_f128_nc(f32x4& d, const float* p) {
    asm volatile("global_load_dwordx4 %0, %1, off" : "=v"(d) : "v"(p));
}
__device__ __forceinline__ void gstore_b128_cc(bf16x8 v, unsigned short* p) {
    asm volatile("global_store_dwordx4 %0, %1, off sc0 sc1" :: "v"(p), "v"(v) : "memory");
}
__device__ __forceinline__ void gstore_f128_cc(f32x4 v, float* p) {
    asm volatile("global_store_dwordx4 %0, %1, off sc0 sc1" :: "v"(p), "v"(v) : "memory");
}
__device__ __forceinline__ void vm_drain()  { asm volatile("s_waitcnt vmcnt(0)"  ::: "memory"); }
__device__ __forceinline__ void vm_wait8()  { asm volatile("s_waitcnt vmcnt(8)"  ::: "memory"); }
#define SBAR() __builtin_amdgcn_sched_barrier(0)

__device__ __forceinline__ unsigned short bf16_rne_bits(float f) {
    unsigned u = __builtin_bit_cast(unsigned, f);
    unsigned r = u + 0x7fffu + ((u >> 16) & 1u);
    return (unsigned short)(r >> 16);
}
__device__ __forceinline__ void split1(float f, unsigned short& hi, unsigned short& lo) {
    unsigned u = __builtin_bit_cast(unsigned, f);
    unsigned r = (u + 0x7fffu + ((u >> 16) & 1u)) & 0xffff0000u;
    hi = (unsigned short)(r >> 16);
    float res = f - __builtin_bit_cast(float, r);
    lo = bf16_rne_bits(res);
}
__device__ __forceinline__ void split8(const float* f, bf16x8& H, bf16x8& L) {
#pragma unroll
    for (int e = 0; e < 8; ++e) {
        unsigned short hi, lo; split1(f[e], hi, lo);
        H[e] = (short)hi; L[e] = (short)lo;
    }
}
__device__ __forceinline__ float tanh_fast(float v) {
    float e = __expf(2.0f * v);
    return 1.0f - 2.0f * __builtin_amdgcn_rcpf(e + 1.0f);
}

__global__ __launch_bounds__(256) void zero_cnt_kernel(unsigned* cnt, unsigned n) {
    unsigned i = blockIdx.x * 256u + threadIdx.x;
    if (i < n) cnt[i] = 0u;
}

// ---------------- weight split to fragment-major ----------------
// WF[mat][prec][c16][ks][lane*8+e]; mat: 0=Wi1 1=Wh1 2=Wi2 3=Wh2
__global__ __launch_bounds__(256) void wsplit_kernel(
    const float* __restrict__ Wi, const float* __restrict__ Wh,
    unsigned short* __restrict__ WF)
{
    unsigned id  = blockIdx.x * 256u + threadIdx.x;   // < 524288
    unsigned kc  = id & 127u;
    unsigned row = (id >> 7) & 1023u;
    unsigned m   = id >> 17;                           // 0..3

    const float* src = ((m & 1u) ? Wh : Wi) + (size_t)(m >> 1) * HCC * HCC
                     + (size_t)row * HCC + kc * 8u;
    float f[8];
    *(f32x4*)&f[0] = *(const f32x4*)&src[0];
    *(f32x4*)&f[4] = *(const f32x4*)&src[4];
    bf16x8 H, L; split8(f, H, L);

    unsigned c16 = row >> 4, ks = kc >> 2;
    unsigned lane = (row & 15u) + 16u * (kc & 3u);
    size_t bh_ = (((size_t)(m * 2u + 0u) * 64u + c16) * 32u + ks) * 512u + lane * 8u;
    size_t bl_ = (((size_t)(m * 2u + 1u) * 64u + c16) * 32u + ks) * 512u + lane * 8u;
    *(bf16x8*)&WF[bh_] = H;
    *(bf16x8*)&WF[bl_] = L;
}

// ---------------- pre1 = x*Wi1^T + (bi1+bh1), frag-major into d_out ----------------
__global__ __launch_bounds__(256) void pre1_gemm(
    const float* __restrict__ x, const float* __restrict__ bi, const float* __restrict__ bh,
    const unsigned short* __restrict__ WF, float* __restrict__ preO)
{
    __shared__ float xs[64 * 36];
    const unsigned t = blockIdx.x >> 3, cg = blockIdx.x & 7u;
    const unsigned tid = threadIdx.x, w = tid >> 6, lane = tid & 63u;
    const unsigned ct32 = cg * 4u + w;

    float b0 = bi[ct32 * 32u + (lane & 15u)]        + bh[ct32 * 32u + (lane & 15u)];
    float b1 = bi[ct32 * 32u + 16u + (lane & 15u)]  + bh[ct32 * 32u + 16u + (lane & 15u)];
    f32x4 acc[4][2];
#pragma unroll
    for (unsigned rt = 0; rt < 4; ++rt) {
        acc[rt][0] = (f32x4){b0, b0, b0, b0};
        acc[rt][1] = (f32x4){b1, b1, b1, b1};
    }
    const float* xt = x + (size_t)t * BH;

    for (unsigned ks = 0; ks < 32; ++ks) {
        {
            unsigned row = tid >> 2, c8 = (tid & 3u) * 8u;
            const float* sp = xt + (size_t)row * HCC + ks * 32u + c8;
            *(f32x4*)&xs[row * 36u + c8]      = *(const f32x4*)&sp[0];
            *(f32x4*)&xs[row * 36u + c8 + 4u] = *(const f32x4*)&sp[4];
        }
        __syncthreads();
        bf16x8 bhv[2], blv[2];
#pragma unroll
        for (unsigned c16 = 0; c16 < 2; ++c16) {
            size_t base = (((size_t)(0u) * 64u + (ct32 * 2u + c16)) * 32u + ks) * 512u + lane * 8u;
            bhv[c16] = *(const bf16x8*)&WF[base];
            blv[c16] = *(const bf16x8*)&WF[base + (size_t)64u * 32u * 512u];
        }
#pragma unroll
        for (unsigned rt = 0; rt < 4; ++rt) {
            unsigned row = rt * 16u + (lane & 15u);
            unsigned k0 = (lane >> 4) * 8u;
            float f[8];
            *(f32x4*)&f[0] = *(const f32x4*)&xs[row * 36u + k0];
            *(f32x4*)&f[4] = *(const f32x4*)&xs[row * 36u + k0 + 4u];
            bf16x8 ah, al; split8(f, ah, al);
#pragma unroll
            for (unsigned c16 = 0; c16 < 2; ++c16) {
                acc[rt][c16] = __builtin_amdgcn_mfma_f32_16x16x32_bf16(ah, bhv[c16], acc[rt][c16], 0, 0, 0);
                acc[rt][c16] = __builtin_amdgcn_mfma_f32_16x16x32_bf16(al, bhv[c16], acc[rt][c16], 0, 0, 0);
                acc[rt][c16] = __builtin_amdgcn_mfma_f32_16x16x32_bf16(ah, blv[c16], acc[rt][c16], 0, 0, 0);
            }
        }
        __syncthreads();
    }
#pragma unroll
    for (unsigned rt = 0; rt < 4; ++rt)
#pragma unroll
        for (unsigned c16 = 0; c16 < 2; ++c16) {
            unsigned rh = rt >> 1, fi = (rt & 1u) * 2u + c16;
            size_t off = ((((size_t)t * 2u + rh) * 32u + ct32) * 4u + fi) * 256u + lane * 4u;
            *(f32x4*)&preO[off] = acc[rt][c16];
        }
}

// ---------------- persistent 3-group pipeline ----------------
__global__ __launch_bounds__(512, 1) void rnn_persist(
    const float* __restrict__ bi, const float* __restrict__ bh,
    const unsigned short* __restrict__ WF,
    unsigned short* __restrict__ h1F, unsigned short* __restrict__ h2F,
    float* __restrict__ pre2F, unsigned* __restrict__ flg,
    float* __restrict__ seqO, float* __restrict__ hsO)
{
    __shared__ short WlS[65536];       // 128 KiB weights (hi+lo, 32 cols)
    __shared__ float redS[7168];       // 28 KiB: slot(f,wi)=f*7+wi, 1 KiB each.
                                       // Quadrant f (16x16 tanh out) parks at slot f*7.

    const unsigned wg  = blockIdx.x;
    const unsigned grp = wg >> 6;                // 0,1,2
    const unsigned sub = wg & 63u;
    const unsigned rh  = sub >> 5, ct = sub & 31u;
    const unsigned tid = threadIdx.x;
    const unsigned w   = tid >> 6, lane = tid & 63u;  // w = K-eighth; w<4 = frag-wave

    const unsigned mat = grp + 1u;               // Wh1/Wi2/Wh2
#pragma unroll
    for (unsigned prec = 0; prec < 2; ++prec)
#pragma unroll
        for (unsigned c16l = 0; c16l < 2; ++c16l) {
            const unsigned short* sp = WF + (((size_t)(mat * 2u + prec) * 64u + (ct * 2u + c16l)) * 32u) * 512u;
            short* dp = &WlS[(prec * 2u + c16l) * 16384u];
            for (unsigned o = tid * 8u; o < 16384u; o += 4096u)
                *(bf16x8*)&dp[o] = *(const bf16x8*)&sp[o];
        }
    __syncthreads();   // WlS staged cross-wave

    float bsel = 0.f;
    if (grp == 1u && w < 4u) {
        unsigned c = HCC + ct * 32u + (w & 1u) * 16u + (lane & 15u);
        bsel = bi[c] + bh[c];
    }

    const int s0_ = (grp == 0u) ? 0 : (grp == 1u) ? 1 : 2;
    const int s1_ = s0_ + 511;

#define POLL16(G, TGT) do {                                                           \
        const unsigned* fp_ = flg + fidx((G), rh * 32u + w * 4u + ((lane >> 2) & 3u), \
                                         lane & 3u);                                  \
        while (!__all((int)(__hip_atomic_load(fp_, __ATOMIC_RELAXED,                  \
                                              __HIP_MEMORY_SCOPE_AGENT) >= (unsigned)(TGT)))) \
            __builtin_amdgcn_s_sleep(1);                                              \
    } while (0)
#define POLLW0(G, TGT) do {                                                           \
        const unsigned* fp_ = flg + fidx((G), lane, 0u);                              \
        while (!__all((int)(__hip_atomic_load(fp_, __ATOMIC_RELAXED,                  \
                                              __HIP_MEMORY_SCOPE_AGENT) >= (unsigned)(TGT)))) \
            __builtin_amdgcn_s_sleep(1);                                              \
    } while (0)
#define POLLG1(TGT) do {                                                              \
        const unsigned* fp_ = flg + fidx(1u, sub, lane & 3u);                         \
        while (!__all((int)(__hip_atomic_load(fp_, __ATOMIC_RELAXED,                  \
                                              __HIP_MEMORY_SCOPE_AGENT) >= (unsigned)(TGT)))) \
            __builtin_amdgcn_s_sleep(1);                                              \
    } while (0)

    for (int s = s0_; s <= s1_; ++s) {
        const bool do_h   = (grp == 0u) ? (s > 0) : (grp == 1u) ? true : (s > 2);

        // ---- acc-init issue + A-gate polls ----
        f32x4 ldq = {0, 0, 0, 0};
        if (grp == 0u) {
            if (w < 4u) {   // pre1[s] stable until G2 stage s+2 (>= G0 flag s+1)
                const float* pp = seqO + (((size_t)s * 2u + rh) * 32u + ct) * 1024u;
                gload_f128_nc(ldq, pp + w * 256u + lane * 4u);
            }
            if (s >= 1) POLL16(0u, s);
        } else if (grp == 1u) {
            POLL16(0u, s);
        } else {
            if (w < 4u) {
                POLLG1(s);   // G1 frag flags >= s  =>  pre2[s-2] complete
                const float* pp = pre2F + (size_t)((s - 2) & 3) * PRE2_FLOATS
                                + ((size_t)rh * 32u + ct) * 1024u;
                gload_f128_cc(ldq, pp + w * 256u + lane * 4u);
            }
            if (s >= 3) POLL16(2u, s);
        }

        // ---- A loads: Ah (8) then Al (8) ----
        bf16x8 Ah0[4], Ah1[4], Al0[4], Al1[4];
        if (do_h) {
            const unsigned aslot = (grp == 2u) ? ((unsigned)(s - 3) & 3u)
                                               : ((unsigned)(s - 1) & 3u);
            const unsigned short* Aslab = (grp <= 1u ? h1F : h2F)
                                        + (size_t)aslot * SLAB_SHORTS;
            const unsigned b00 = ((rh * 2u + 0u) * 2u + 0u) * 16384u;
            const unsigned b01 = ((rh * 2u + 0u) * 2u + 1u) * 16384u;
            const unsigned b10 = ((rh * 2u + 1u) * 2u + 0u) * 16384u;
            const unsigned b11 = ((rh * 2u + 1u) * 2u + 1u) * 16384u;
#pragma unroll
            for (unsigned i = 0; i < 4; ++i) {
                const unsigned ao = (w * 4u + i) * 512u + lane * 8u;
                gload_b128_cc(Ah0[i], Aslab + b00 + ao);
                gload_b128_cc(Ah1[i], Aslab + b01 + ao);
            }
#pragma unroll
            for (unsigned i = 0; i < 4; ++i) {
                const unsigned ao = (w * 4u + i) * 512u + lane * 8u;
                gload_b128_cc(Al0[i], Aslab + b10 + ao);
                gload_b128_cc(Al1[i], Aslab + b11 + ao);
            }
        }

        f32x4 a00 = {0,0,0,0}, a01 = {0,0,0,0}, a10 = {0,0,0,0}, a11 = {0,0,0,0};
        if (do_h) {
            // phase 1: Ah x {Bh, Bl} while Al streams
            vm_wait8(); SBAR();
#pragma unroll
            for (unsigned i = 0; i < 4; ++i) {
                const unsigned ao = (w * 4u + i) * 512u + lane * 8u;
                bf16x8 bh0 = *(const bf16x8*)&WlS[ao];
                bf16x8 bh1 = *(const bf16x8*)&WlS[16384u + ao];
                bf16x8 bl0 = *(const bf16x8*)&WlS[32768u + ao];
                bf16x8 bl1 = *(const bf16x8*)&WlS[49152u + ao];
                a00 = __builtin_amdgcn_mfma_f32_16x16x32_bf16(Ah0[i], bh0, a00, 0, 0, 0);
                a01 = __builtin_amdgcn_mfma_f32_16x16x32_bf16(Ah0[i], bh1, a01, 0, 0, 0);
                a10 = __builtin_amdgcn_mfma_f32_16x16x32_bf16(Ah1[i], bh0, a10, 0, 0, 0);
                a11 = __builtin_amdgcn_mfma_f32_16x16x32_bf16(Ah1[i], bh1, a11, 0, 0, 0);
                a00 = __builtin_amdgcn_mfma_f32_16x16x32_bf16(Ah0[i], bl0, a00, 0, 0, 0);
                a01 = __builtin_amdgcn_mfma_f32_16x16x32_bf16(Ah0[i], bl1, a01, 0, 0, 0);
                a10 = __builtin_amdgcn_mfma_f32_16x16x32_bf16(Ah1[i], bl0, a10, 0, 0, 0);
                a11 = __builtin_amdgcn_mfma_f32_16x16x32_bf16(Ah1[i], bl1, a11, 0, 0, 0);
            }
            // phase 2: Al x Bh
            vm_drain(); SBAR();
#pragma unroll
            for (unsigned i = 0; i < 4; ++i) {
                const unsigned ao = (w * 4u + i) * 512u + lane * 8u;
                bf16x8 bh0 = *(const bf16x8*)&WlS[ao];
                bf16x8 bh1 = *(const bf16x8*)&WlS[16384u + ao];
                a00 = __builtin_amdgcn_mfma_f32_16x16x32_bf16(Al0[i], bh0, a00, 0, 0, 0);
                a01 = __builtin_amdgcn_mfma_f32_16x16x32_bf16(Al0[i], bh1, a01, 0, 0, 0);
                a10 = __builtin_amdgcn_mfma_f32_16x16x32_bf16(Al1[i], bh0, a10, 0, 0, 0);
                a11 = __builtin_amdgcn_mfma_f32_16x16x32_bf16(Al1[i], bh1, a11, 0, 0, 0);
            }
        } else {
            vm_drain(); SBAR();
        }

        // ---- anti-dep polls (gate only the post-barrier-2 stores) ----
        if (w == 1u) {
            if (grp == 0u && s >= 4) POLLW0(1u, s - 2); // G1 done reading h1[s-4]
            if (grp == 1u && s >= 5) POLLW0(2u, s - 2); // G2 done reading pre2[s-5]
        }
        if (w == 2u) {
            if (grp == 0u && s >= 4) POLLW0(0u, s - 2); // G0 done reading h1[s-4]
            if (grp == 2u && s >= 6) POLLW0(2u, s - 2); // G2 done reading h2[s-6]
        }

        // ---- partials to redS: wave w writes frags f != w (w<4) / all (w>=4) ----
        {
            f32x4 av[4] = {a00, a01, a10, a11};
#pragma unroll
            for (unsigned f = 0; f < 4; ++f) {
                const bool skip = (w < 4u) && (f == w);
                const unsigned wi = w - ((w > f) ? 1u : 0u);
                if (!skip)
                    *(f32x4*)&redS[(f * 7u + wi) * 256u + lane * 4u] = av[f];
            }
        }
        __syncthreads();                                   // barrier 1

        // ---- frag-parallel reduce + epilogue (waves 0..3) ----
        if (w < 4u) {
            f32x4 acc = (w == 0u) ? a00 : (w == 1u) ? a01 : (w == 2u) ? a10 : a11;
#pragma unroll
            for (unsigned b = 0; b < 7; ++b)
                acc += *(const f32x4*)&redS[(w * 7u + b) * 256u + lane * 4u];
            if (grp == 1u) {
                acc += (f32x4){bsel, bsel, bsel, bsel};
                float* pp = pre2F + (size_t)((s - 1) & 3) * PRE2_FLOATS
                          + ((size_t)rh * 32u + ct) * 1024u;
                gstore_f128_cc(acc, pp + w * 256u + lane * 4u);
                vm_drain();
                if (lane == 0u)
                    __hip_atomic_store(flg + fidx(1u, sub, w), (unsigned)s + 1u,
                                       __ATOMIC_RELAXED, __HIP_MEMORY_SCOPE_AGENT);
            } else {
                acc += ldq;
                // tanh -> quadrant w (16x16) parked at slot w*7 (own slots read above)
                const unsigned qb = w * 1792u;
                const unsigned rb = (lane >> 4) * 4u;
#pragma unroll
                for (unsigned rr = 0; rr < 4; ++rr)
                    redS[qb + (rb + rr) * 16u + (lane & 15u)] = tanh_fast(acc[rr]);
            }
        }
        if (grp != 1u) {
            __syncthreads();                               // barrier 2: quadrants ready
            // h-slab store (waves 0..3): block (prec=w&1, r16l=w>>1)
            if (w < 4u) {
                const unsigned r16l = w >> 1, prec = w & 1u;
                const unsigned c0 = (lane >> 4) * 8u;
                const unsigned q  = r16l * 2u + (c0 >> 4);
                const unsigned qa = q * 1792u + (lane & 15u) * 16u + (c0 & 15u);
                float f[8];
                *(f32x4*)&f[0] = *(const f32x4*)&redS[qa];
                *(f32x4*)&f[4] = *(const f32x4*)&redS[qa + 4u];
                bf16x8 H, L; split8(f, H, L);
                unsigned short* hdst = (grp == 0u ? h1F : h2F)
                    + (size_t)((unsigned)(grp == 0u ? s : s - 2) & 3u) * SLAB_SHORTS;
                gstore_b128_cc(prec ? L : H,
                    hdst + ((rh * 2u + prec) * 2u + r16l) * 16384u + ct * 512u + lane * 8u);
                vm_drain();    // stale seqO stores long retired; waits only h-store
                if (lane == 0u)
                    __hip_atomic_store(flg + fidx(grp, sub, w), (unsigned)s + 1u,
                                       __ATOMIC_RELAXED, __HIP_MEMORY_SCOPE_AGENT);
            }
            // seqO / hsO outputs from quadrants (off the flag path)
            if (grp == 2u) {
                const int t2 = s - 2;
#pragma unroll
                for (unsigned pass = 0; pass < 2; ++pass) {
                    const unsigned r = w * 4u + pass * 2u + (lane >> 5);
                    const unsigned c = lane & 31u;
                    const float v = redS[((r >> 4) * 2u + (c >> 4)) * 1792u
                                         + (r & 15u) * 16u + (c & 15u)];
                    seqO[((size_t)t2 * 64u + rh * 32u + r) * 1024u + ct * 32u + c] = v;
                    if (s == 513) hsO[BH + (size_t)(rh * 32u + r) * 1024u + ct * 32u + c] = v;
                }
            }
            if (grp == 0u && s == 511) {
#pragma unroll
                for (unsigned pass = 0; pass < 2; ++pass) {
                    const unsigned r = w * 4u + pass * 2u + (lane >> 5);
                    const unsigned c = lane & 31u;
                    hsO[(size_t)(rh * 32u + r) * 1024u + ct * 32u + c]
                        = redS[((r >> 4) * 2u + (c >> 4)) * 1792u
                               + (r & 15u) * 16u + (c & 15u)];
                }
            }
        }
        // ---- stage-end barrier: redS/quadrant WAR protection ----
        __syncthreads();
    }
    vm_drain();   // retire straggler seqO stores
#undef POLL16
#undef POLLW0
#undef POLLG1
}

extern "C" void kernel_launch(void* const* d_in, const int* in_sizes, int n_in,
                              void* d_out, int out_size, void* d_ws, size_t ws_size,
                              hipStream_t stream) {
    const float* x  = (const float*)d_in[0];
    const float* Wi = (const float*)d_in[1];
    const float* bi = (const float*)d_in[2];
    const float* Wh = (const float*)d_in[3];
    const float* bh = (const float*)d_in[4];

    float* seqO = (float*)d_out;
    float* hsO  = seqO + (size_t)T_STEPS * BH;

    unsigned short* wsS = (unsigned short*)d_ws;
    unsigned short* WF  = wsS;
    unsigned short* h1F = wsS + OFF_H1F;
    unsigned short* h2F = wsS + OFF_H2F;
    float* pre2F = (float*)((char*)d_ws + OFF_PRE2_BYTES);
    unsigned* flg = (unsigned*)((char*)d_ws + FLG_BYTE_OFF);

    zero_cnt_kernel<<<(FLG_UINTS + 255u) / 256u, 256, 0, stream>>>(flg, FLG_UINTS);
    wsplit_kernel<<<2048, 256, 0, stream>>>(Wi, Wh, WF);
    pre1_gemm<<<4096, 256, 0, stream>>>(x, bi, bh, WF, seqO);
    rnn_persist<<<NWG, 512, 0, stream>>>(bi, bh, WF, h1F, h2F, pre2F, flg, seqO, hsO);
}